// Round 8
// baseline (8649.997 us; speedup 1.0000x reference)
//
#include <hip/hip_runtime.h>
#include <math.h>

#define Bz 16
#define Sz 900
#define Vz 16
#define Dz 256
#define DCz 128
#define Hz 4
#define Nz 6300
#define TSz 5400
#define DSLOTz 145
#define NSLOTz 48
#define GXA 99    // ceil(6300/64) row-blocks
#define GXB 197   // ceil(6300/32) row-blocks for k_kv

typedef unsigned short u16;
typedef unsigned int u32;

typedef __bf16 bf16x8 __attribute__((ext_vector_type(8)));
typedef float floatx4 __attribute__((ext_vector_type(4)));
union U8 { bf16x8 v; uint4 q; };

static __device__ __forceinline__ float sigm(float x){ return 1.0f/(1.0f+__expf(-x)); }
static __device__ __forceinline__ void fma4(float4& a, float s, float4 b){ a.x+=s*b.x; a.y+=s*b.y; a.z+=s*b.z; a.w+=s*b.w; }
static __device__ __forceinline__ float dot4(float4 a, float4 b){ return a.x*b.x + a.y*b.y + a.z*b.z + a.w*b.w; }
static __device__ __forceinline__ float4 f4z(){ float4 z; z.x=0.f; z.y=0.f; z.z=0.f; z.w=0.f; return z; }
static __device__ __forceinline__ float elu1(float x){ return x>0.f ? x+1.f : __expf(x); }
static __device__ __forceinline__ float fcomp(float4 v, int i){ return (i==0)?v.x:(i==1)?v.y:(i==2)?v.z:v.w; }

// round-to-nearest-even bf16 (top 16 bits) of f32
static __device__ __forceinline__ uint hi16(float x){
  uint u = __float_as_uint(x);
  return (u + 0x7fffu + ((u>>16)&1u)) >> 16;
}

typedef const void GV __attribute__((address_space(1)));
typedef void LV __attribute__((address_space(3)));
static __device__ __forceinline__ void gl16(const float* g, float* l){
  __builtin_amdgcn_global_load_lds((GV*)g, (LV*)l, 16, 0, 0);
}
static __device__ __forceinline__ void gl16b(const void* g, void* l){
  __builtin_amdgcn_global_load_lds((GV*)g, (LV*)l, 16, 0, 0);
}

__global__ void k_sentinel(float* out, int nelem){
  int i = blockIdx.x*256 + threadIdx.x;
  if (i < nelem) out[i] = 12345.0f;
}

__global__ void k_zero(float* p, int n){
  int i = blockIdx.x*256 + threadIdx.x;
  if (i < n) p[i] = 0.f;
}

__global__ void k_rope(float* cost, float* sint){
  int i = blockIdx.x*256 + threadIdx.x;
  if (i >= Nz*32) return;
  int n = i>>5, f = i&31;
  double invd = pow(10000.0, -(double)f/32.0);
  double fr = (double)n * invd;
  cost[i] = (float)cos(fr);
  sint[i] = (float)sin(fr);
}

__global__ void k_embed(const int* __restrict__ di, const int* __restrict__ dq,
                        const int* __restrict__ ti, const float* __restrict__ temb,
                        const float* __restrict__ semb, float* __restrict__ h){
  int i = blockIdx.x*256 + threadIdx.x;   // over B*N*64 float4s
  if (i >= Bz*Nz*64) return;
  int dv = i & 63; int bn = i >> 6; int n = bn % Nz; int b = bn / Nz;
  int tok;
  if (n < TSz){
    int nd = n/1800; int r = n - nd*1800;
    tok = (r < Sz) ? di[(b*3+nd)*Sz + r] : dq[(b*3+nd)*Sz + (r-Sz)];
  } else {
    tok = ti[b*Sz + (n-TSz)];
  }
  const float4* e4 = (const float4*)(temb + (size_t)tok*Dz);
  const float4* s4 = (const float4*)semb;
  float4 v = e4[dv]; float4 s = s4[dv];
  v.x += s.x; v.y += s.y; v.z += s.z; v.w += s.w;
  ((float4*)h)[(size_t)bn*64 + dv] = v;
}

__global__ void k_cache_init(const float* __restrict__ slot_emb, const float* __restrict__ lid,
                             float* __restrict__ cache){
  int i = blockIdx.x*256 + threadIdx.x;
  if (i >= Bz*NSLOTz*DSLOTz) return;
  int c = i % DSLOTz; int sc = (i / DSLOTz) % NSLOTz; int l = sc >> 4;
  float v = 0.f;
  if (c < DCz) v = slot_emb[sc*DCz + c];
  else if (c >= 129 && c < 137) v = lid[l*8 + (c-129)];
  cache[i] = v;
}

// pack Wq^T (cols 0..256 of Wqkv) into MFMA A-fragment order, bf16 hi/lo.
__global__ void k_pack_w(const float* __restrict__ Wqkv,
                         u16* __restrict__ wh, u16* __restrict__ wl){
  int i = blockIdx.x*256 + threadIdx.x;
  if (i >= 3*65536) return;
  int l = i >> 16; int r = i & 65535;
  int ks = r >> 13; int ct = (r>>9)&15; int lane = (r>>3)&63; int e = r&7;
  int k = ks*32 + ((lane>>4)<<3) + e;
  int c = ct*16 + (lane&15);
  float x = Wqkv[(size_t)l*196608 + (size_t)k*768 + c];
  uint hb = hi16(x);
  uint lb = hi16(x - __uint_as_float(hb<<16));
  wh[i] = (u16)hb; wl[i] = (u16)lb;
}

// pack Wkv^T (cols 256..768 of Wqkv) into MFMA A-fragment order, bf16 hi/lo.
__global__ void k_pack_wkv(const float* __restrict__ Wqkv,
                           u16* __restrict__ wh, u16* __restrict__ wl){
  int i = blockIdx.x*256 + threadIdx.x;
  if (i >= 3*131072) return;
  int l = i / 131072; int r = i % 131072;
  int ks = r >> 14; int ct = (r>>9)&31; int lane = (r>>3)&63; int e = r&7;
  int k = ks*32 + ((lane>>4)<<3) + e;
  int c = ct*16 + (lane&15);
  float x = Wqkv[(size_t)l*196608 + (size_t)k*768 + 256 + c];
  uint hb = hi16(x);
  uint lb = hi16(x - __uint_as_float(hb<<16));
  wh[i] = (u16)hb; wl[i] = (u16)lb;
}

// pack Wq_read^T into MFMA A-fragment order, bf16 hi/lo.
__global__ void k_pack_wr(const float* __restrict__ Wqr,
                          u16* __restrict__ wh, u16* __restrict__ wl){
  int i = blockIdx.x*256 + threadIdx.x;
  if (i >= 3*32768) return;
  int l = i >> 15; int r = i & 32767;
  int ks = r >> 12; int ct = (r>>9)&7; int lane = (r>>3)&63; int e = r&7;
  int k = ks*32 + ((lane>>4)<<3) + e;
  int c = ct*16 + (lane&15);
  float x = Wqr[(size_t)l*32768 + (size_t)k*DCz + c];
  uint hb = hi16(x);
  uint lb = hi16(x - __uint_as_float(hb<<16));
  wh[i] = (u16)hb; wl[i] = (u16)lb;
}

// cache->kread/vread projections, emitted directly in bf16 hi/lo MFMA A-frag order.
__global__ __launch_bounds__(384) void k_proj_cache(const float* __restrict__ cache,
    const float* __restrict__ Wk, const float* __restrict__ Wv,
    u16* __restrict__ krh, u16* __restrict__ krl,
    u16* __restrict__ vrh, u16* __restrict__ vrl){
  __shared__ float crow[DSLOTz];
  int b = blockIdx.x / NSLOTz, sc = blockIdx.x % NSLOTz;
  int t = threadIdx.x;
  const float* cp = cache + (size_t)(b*NSLOTz+sc)*DSLOTz;
  if (t < DSLOTz) crow[t] = cp[t];
  __syncthreads();
  if (t < DCz){
    float a = 0.f;
    for (int r2=0;r2<DSLOTz;r2++) a += crow[r2]*Wk[r2*DCz + t];
    uint hb = hi16(a);
    uint lb = hi16(a - __uint_as_float(hb<<16));
    int ks = t>>5, st = sc>>4, lane = (sc&15) | (((t>>3)&3)<<4), e = t&7;
    size_t idx = (size_t)b*6144 + (size_t)(((ks*3+st)*64 + lane)*8 + e);
    krh[idx] = (u16)hb; krl[idx] = (u16)lb;
  } else {
    int d = t - DCz;
    float a = 0.f;
    for (int r2=0;r2<DSLOTz;r2++) a += crow[r2]*Wv[r2*Dz + d];
    uint hb = hi16(a);
    uint lb = hi16(a - __uint_as_float(hb<<16));
    int ot = d>>4, ks2 = sc>>5, lane = (d&15) | (((sc>>3)&3)<<4), e = sc&7;
    size_t idx = (size_t)b*16384 + (size_t)(((ks2*16+ot)*64 + lane)*8 + e);
    vrh[idx] = (u16)hb; vrl[idx] = (u16)lb;
  }
}

// ---------------- MFMA k_read_attn ----------------
#define RA2_BH 0
#define RA2_BL 5120
#define RA2_QBH 10240
#define RA2_QBL 30720
#define RA2_ABH 10240
#define RA2_ABL 20480
#define RA2_G  51200
#define RA2_WG 51456
__global__ __launch_bounds__(256) void k_read_attn(
    float* __restrict__ h,
    const u16* __restrict__ wqh, const u16* __restrict__ wql,
    const u16* __restrict__ krh, const u16* __restrict__ krl,
    const u16* __restrict__ vrh, const u16* __restrict__ vrl,
    const float* __restrict__ Wg, const float* __restrict__ bg){
  __shared__ float smem[13120];
  char* sb = (char*)smem;
  const int t = threadIdx.x;
  const int b = blockIdx.y;
  const int n0 = blockIdx.x*64;
  const int w = t>>6, lane = t&63, ln = t&15, lq = (t>>4)&3;
  float* hb = h + (size_t)b*Nz*Dz;
  ((float*)(sb+RA2_WG))[t] = Wg[t];
  floatx4 acc[2][4];
  #pragma unroll
  for (int i=0;i<2;i++)
    #pragma unroll
    for (int j=0;j<4;j++){ acc[i][j][0]=0.f; acc[i][j][1]=0.f; acc[i][j][2]=0.f; acc[i][j][3]=0.f; }
  for (int ks=0; ks<8; ks++){
    __syncthreads();
    {
      int n = n0 + (t>>2);
      const float* hp = hb + (size_t)n*Dz + ks*32 + (t&3)*8;
      float x[8];
      if (n < Nz){
        float4 v0 = *(const float4*)(hp);
        float4 v1 = *(const float4*)(hp+4);
        x[0]=v0.x; x[1]=v0.y; x[2]=v0.z; x[3]=v0.w;
        x[4]=v1.x; x[5]=v1.y; x[6]=v1.z; x[7]=v1.w;
      } else {
        #pragma unroll
        for (int e=0;e<8;e++) x[e]=0.f;
      }
      uint hw[4], lw[4];
      #pragma unroll
      for (int e=0;e<4;e++){
        uint h0=hi16(x[2*e]), h1=hi16(x[2*e+1]);
        uint l0=hi16(x[2*e]-__uint_as_float(h0<<16));
        uint l1=hi16(x[2*e+1]-__uint_as_float(h1<<16));
        hw[e]=h0|(h1<<16); lw[e]=l0|(l1<<16);
      }
      int a16 = (((t>>2)*5 + (t&3))<<4);
      *(uint4*)(sb + RA2_BH + a16) = make_uint4(hw[0],hw[1],hw[2],hw[3]);
      *(uint4*)(sb + RA2_BL + a16) = make_uint4(lw[0],lw[1],lw[2],lw[3]);
    }
    __syncthreads();
    U8 bh[4], bl[4];
    #pragma unroll
    for (int nt=0; nt<4; nt++){
      int a16 = (((nt*16+ln)*5 + lq)<<4);
      bh[nt].q = *(const uint4*)(sb + RA2_BH + a16);
      bl[nt].q = *(const uint4*)(sb + RA2_BL + a16);
    }
    #pragma unroll
    for (int mf=0; mf<2; mf++){
      U8 ah, al;
      size_t ai = ((size_t)(ks*8 + w*2 + mf))*512 + lane*8;
      ah.q = *(const uint4*)(wqh + ai);
      al.q = *(const uint4*)(wql + ai);
      #pragma unroll
      for (int nt=0; nt<4; nt++){
        acc[mf][nt] = __builtin_amdgcn_mfma_f32_16x16x32_bf16(ah.v, bh[nt].v, acc[mf][nt], 0,0,0);
        acc[mf][nt] = __builtin_amdgcn_mfma_f32_16x16x32_bf16(ah.v, bl[nt].v, acc[mf][nt], 0,0,0);
        acc[mf][nt] = __builtin_amdgcn_mfma_f32_16x16x32_bf16(al.v, bh[nt].v, acc[mf][nt], 0,0,0);
      }
    }
  }
  {
    int n = t>>2, kq = t&3;
    int nn = n0+n; int nc = (nn < Nz) ? nn : (Nz-1);
    const float* hp = hb + (size_t)nc*Dz + kq*64;
    const float* wgp = (const float*)(sb+RA2_WG) + kq*64;
    float a = 0.f;
    for (int k=0;k<64;k+=4){
      float4 hv = *(const float4*)(hp+k);
      float4 wv = *(const float4*)(wgp+k);
      a += dot4(hv,wv);
    }
    a += __shfl_xor(a,1,64);
    a += __shfl_xor(a,2,64);
    if (kq==0) ((float*)(sb+RA2_G))[n] = a;
  }
  {
    #pragma unroll
    for (int mf=0; mf<2; mf++){
      #pragma unroll
      for (int nt=0; nt<4; nt++){
        float v0 = acc[mf][nt][0], v1 = acc[mf][nt][1];
        float v2 = acc[mf][nt][2], v3 = acc[mf][nt][3];
        uint h0=hi16(v0), h1=hi16(v1), h2=hi16(v2), h3=hi16(v3);
        uint l0=hi16(v0-__uint_as_float(h0<<16));
        uint l1=hi16(v1-__uint_as_float(h1<<16));
        uint l2=hi16(v2-__uint_as_float(h2<<16));
        uint l3=hi16(v3-__uint_as_float(h3<<16));
        int a16 = (((nt*16+ln)*5 + (mf*2 + (lq>>1)))<<4) + ((lq&1)<<3);
        *(uint2*)(sb + RA2_QBH + w*5120 + a16) = make_uint2(h0|(h1<<16), h2|(h3<<16));
        *(uint2*)(sb + RA2_QBL + w*5120 + a16) = make_uint2(l0|(l1<<16), l2|(l3<<16));
      }
    }
  }
  __syncthreads();
  floatx4 sacc[3];
  #pragma unroll
  for (int st=0; st<3; st++){ sacc[st][0]=0.f; sacc[st][1]=0.f; sacc[st][2]=0.f; sacc[st][3]=0.f; }
  for (int ks=0; ks<4; ks++){
    U8 bh, bl;
    int a16 = (((w*16+ln)*5 + lq)<<4);
    bh.q = *(const uint4*)(sb + RA2_QBH + ks*5120 + a16);
    bl.q = *(const uint4*)(sb + RA2_QBL + ks*5120 + a16);
    #pragma unroll
    for (int st=0; st<3; st++){
      U8 ah, al;
      size_t ai = (size_t)b*6144 + ((size_t)(ks*3+st))*512 + lane*8;
      ah.q = *(const uint4*)(krh + ai);
      al.q = *(const uint4*)(krl + ai);
      sacc[st] = __builtin_amdgcn_mfma_f32_16x16x32_bf16(ah.v, bh.v, sacc[st], 0,0,0);
      sacc[st] = __builtin_amdgcn_mfma_f32_16x16x32_bf16(ah.v, bl.v, sacc[st], 0,0,0);
      sacc[st] = __builtin_amdgcn_mfma_f32_16x16x32_bf16(al.v, bh.v, sacc[st], 0,0,0);
    }
  }
  {
    const float scl = 0.088388347648318447f;
    float mx = -1e30f;
    #pragma unroll
    for (int st=0; st<3; st++)
      #pragma unroll
      for (int r=0;r<4;r++){ sacc[st][r] *= scl; mx = fmaxf(mx, sacc[st][r]); }
    mx = fmaxf(mx, __shfl_xor(mx, 16, 64));
    mx = fmaxf(mx, __shfl_xor(mx, 32, 64));
    float su = 0.f;
    #pragma unroll
    for (int st=0; st<3; st++)
      #pragma unroll
      for (int r=0;r<4;r++){ float e = __expf(sacc[st][r]-mx); sacc[st][r]=e; su+=e; }
    su += __shfl_xor(su, 16, 64);
    su += __shfl_xor(su, 32, 64);
    float inv = 1.f/su;
    #pragma unroll
    for (int st=0; st<3; st++)
      #pragma unroll
      for (int r=0;r<4;r++) sacc[st][r] *= inv;
  }
  __syncthreads();
  {
    uint2 ah2[3], al2[3];
    #pragma unroll
    for (int st=0; st<3; st++){
      float v0=sacc[st][0], v1=sacc[st][1], v2=sacc[st][2], v3=sacc[st][3];
      uint h0=hi16(v0), h1=hi16(v1), h2=hi16(v2), h3=hi16(v3);
      uint l0=hi16(v0-__uint_as_float(h0<<16));
      uint l1=hi16(v1-__uint_as_float(h1<<16));
      uint l2=hi16(v2-__uint_as_float(h2<<16));
      uint l3=hi16(v3-__uint_as_float(h3<<16));
      ah2[st] = make_uint2(h0|(h1<<16), h2|(h3<<16));
      al2[st] = make_uint2(l0|(l1<<16), l2|(l3<<16));
    }
    int rb = (w*16+ln)*5;
    int sub = (lq&1)<<3;
    #pragma unroll
    for (int st=0; st<2; st++){
      int a16 = ((rb + st*2 + (lq>>1))<<4) + sub;
      *(uint2*)(sb + RA2_ABH + a16) = ah2[st];
      *(uint2*)(sb + RA2_ABL + a16) = al2[st];
    }
    {
      int a16 = ((rb + (lq>>1))<<4) + sub;
      *(uint2*)(sb + RA2_ABH + 5120 + a16) = ah2[2];
      *(uint2*)(sb + RA2_ABL + 5120 + a16) = al2[2];
      int z16 = ((rb + 2 + (lq>>1))<<4) + sub;
      *(uint2*)(sb + RA2_ABH + 5120 + z16) = make_uint2(0,0);
      *(uint2*)(sb + RA2_ABL + 5120 + z16) = make_uint2(0,0);
    }
  }
  __syncthreads();
  floatx4 o[4][4];
  #pragma unroll
  for (int i=0;i<4;i++)
    #pragma unroll
    for (int j=0;j<4;j++){ o[i][j][0]=0.f; o[i][j][1]=0.f; o[i][j][2]=0.f; o[i][j][3]=0.f; }
  #pragma unroll
  for (int ks2=0; ks2<2; ks2++){
    U8 bh[4], bl[4];
    #pragma unroll
    for (int nt=0; nt<4; nt++){
      int a16 = (((nt*16+ln)*5 + lq)<<4);
      bh[nt].q = *(const uint4*)(sb + RA2_ABH + ks2*5120 + a16);
      bl[nt].q = *(const uint4*)(sb + RA2_ABL + ks2*5120 + a16);
    }
    #pragma unroll
    for (int mf=0; mf<4; mf++){
      U8 ah, al;
      size_t ai = (size_t)b*16384 + ((size_t)(ks2*16 + w*4 + mf))*512 + lane*8;
      ah.q = *(const uint4*)(vrh + ai);
      al.q = *(const uint4*)(vrl + ai);
      #pragma unroll
      for (int nt=0; nt<4; nt++){
        o[mf][nt] = __builtin_amdgcn_mfma_f32_16x16x32_bf16(ah.v, bh[nt].v, o[mf][nt], 0,0,0);
        o[mf][nt] = __builtin_amdgcn_mfma_f32_16x16x32_bf16(ah.v, bl[nt].v, o[mf][nt], 0,0,0);
        o[mf][nt] = __builtin_amdgcn_mfma_f32_16x16x32_bf16(al.v, bh[nt].v, o[mf][nt], 0,0,0);
      }
    }
  }
  float bg0 = bg[0];
  #pragma unroll
  for (int nt=0; nt<4; nt++){
    int n = n0 + nt*16 + ln;
    if (n < Nz){
      float gv = sigm(((const float*)(sb+RA2_G))[nt*16+ln] + bg0);
      #pragma unroll
      for (int mf=0; mf<4; mf++){
        float* hp = hb + (size_t)n*Dz + w*64 + mf*16 + lq*4;
        float4 hv = *(const float4*)hp;
        hv.x += gv*o[mf][nt][0];
        hv.y += gv*o[mf][nt][1];
        hv.z += gv*o[mf][nt][2];
        hv.w += gv*o[mf][nt][3];
        *(float4*)hp = hv;
      }
    }
  }
}

// ---------------- MFMA k_kv: 32-row tiles for TLP ----------------
// GEMM (swapped): C[c][n] = Wkv^T . h^T, 512c x 32n, K=256. Grid 197x16 (12.3/CU).
// acc[2][4][2] = 64 VGPRs. B (h tile) double-buffered (10 KB), A direct->reg.
// One barrier per ks. Phase B: per head g, wave g hands kf/v (32x68) to LDS;
// outer product + atomics. LDS total 17408 B -> high co-residency.
#define KVB_BUF 5120   // one B dbuf slot: hi 2560 + lo 2560
__global__ __launch_bounds__(256) void k_kv(
    const float* __restrict__ h,
    const u16* __restrict__ wh, const u16* __restrict__ wl,
    const float* __restrict__ cost, const float* __restrict__ sint,
    float* __restrict__ kvbuf){
  __shared__ float smem[4352];   // 17408 B
  char* sb = (char*)smem;
  const int t = threadIdx.x;
  const int b = blockIdx.y;
  const int n0 = blockIdx.x*32;
  const int w = t>>6;
  const int lane = t&63;
  const int ln = t&15;
  const int lq = (t>>4)&3;
  const float* hb = h + (size_t)b*Nz*Dz;
  floatx4 acc[2][4][2];
  #pragma unroll
  for (int cp=0;cp<2;cp++)
    #pragma unroll
    for (int i=0;i<4;i++)
      #pragma unroll
      for (int j=0;j<2;j++){ acc[cp][i][j][0]=0.f; acc[cp][i][j][1]=0.f; acc[cp][i][j][2]=0.f; acc[cp][i][j][3]=0.f; }

  // staging: threads t<128 handle (n=t>>2 in [0,32), k-oct=t&3)
  const int hrow = t>>2, hcol = t&3;
  const int hact = (t < 128);
  const float* hbase = hb + (size_t)(n0+hrow)*Dz + hcol*8;
  const int hvalid = hact && ((n0+hrow) < Nz);
  const int a16w = ((hrow*5 + hcol)<<4);

  auto load_h = [&](int ks, float x[8]){
    if (hvalid){
      float4 v0 = *(const float4*)(hbase + ks*32);
      float4 v1 = *(const float4*)(hbase + ks*32 + 4);
      x[0]=v0.x; x[1]=v0.y; x[2]=v0.z; x[3]=v0.w;
      x[4]=v1.x; x[5]=v1.y; x[6]=v1.z; x[7]=v1.w;
    } else {
      #pragma unroll
      for (int e=0;e<8;e++) x[e]=0.f;
    }
  };
  auto cvt_write = [&](const float x[8], int buf){
    if (!hact) return;
    uint hw[4], lw[4];
    #pragma unroll
    for (int e=0;e<4;e++){
      uint h0=hi16(x[2*e]), h1=hi16(x[2*e+1]);
      uint l0=hi16(x[2*e]-__uint_as_float(h0<<16));
      uint l1=hi16(x[2*e+1]-__uint_as_float(h1<<16));
      hw[e]=h0|(h1<<16); lw[e]=l0|(l1<<16);
    }
    *(uint4*)(sb + buf*KVB_BUF + a16w) = make_uint4(hw[0],hw[1],hw[2],hw[3]);
    *(uint4*)(sb + buf*KVB_BUF + 2560 + a16w) = make_uint4(lw[0],lw[1],lw[2],lw[3]);
  };

  { float x0[8]; load_h(0, x0); cvt_write(x0, 0); }
  for (int ks=0; ks<8; ks++){
    __syncthreads();
    float xn[8];
    if (ks < 7) load_h(ks+1, xn);
    const int cb = ks&1;
    U8 bh[2], bl[2];
    #pragma unroll
    for (int nt=0; nt<2; nt++){
      int a16 = (((nt*16+ln)*5 + lq)<<4);
      bh[nt].q = *(const uint4*)(sb + cb*KVB_BUF + a16);
      bl[nt].q = *(const uint4*)(sb + cb*KVB_BUF + 2560 + a16);
    }
    #pragma unroll
    for (int cp=0; cp<2; cp++){
      #pragma unroll
      for (int mf=0; mf<4; mf++){
        U8 ah, al;
        size_t ai = ((size_t)(ks*32 + cp*16 + w*4 + mf))*512 + lane*8;
        ah.q = *(const uint4*)(wh + ai);
        al.q = *(const uint4*)(wl + ai);
        #pragma unroll
        for (int nt=0; nt<2; nt++){
          acc[cp][mf][nt] = __builtin_amdgcn_mfma_f32_16x16x32_bf16(ah.v, bh[nt].v, acc[cp][mf][nt], 0,0,0);
          acc[cp][mf][nt] = __builtin_amdgcn_mfma_f32_16x16x32_bf16(ah.v, bl[nt].v, acc[cp][mf][nt], 0,0,0);
          acc[cp][mf][nt] = __builtin_amdgcn_mfma_f32_16x16x32_bf16(al.v, bh[nt].v, acc[cp][mf][nt], 0,0,0);
        }
      }
    }
    if (ks < 7) cvt_write(xn, cb^1);
  }
  // epilogue: rope + elu on kf (cp0), zero invalid columns
  #pragma unroll
  for (int mf=0; mf<4; mf++){
    #pragma unroll
    for (int nt=0; nt<2; nt++){
      int n = n0 + nt*16 + ln;
      int valid = (n < Nz);
      int nc = valid ? n : (Nz-1);
      int pi = mf*8 + lq*2;
      float2 c2 = *(const float2*)(cost + (size_t)nc*32 + pi);
      float2 s2 = *(const float2*)(sint + (size_t)nc*32 + pi);
      float q0 = acc[0][mf][nt][0], q1 = acc[0][mf][nt][1];
      float q2 = acc[0][mf][nt][2], q3 = acc[0][mf][nt][3];
      float r0 = elu1(q0*c2.x - q1*s2.x);
      float r1 = elu1(q0*s2.x + q1*c2.x);
      float r2 = elu1(q2*c2.y - q3*s2.y);
      float r3 = elu1(q2*s2.y + q3*c2.y);
      acc[0][mf][nt][0] = valid ? r0 : 0.f;
      acc[0][mf][nt][1] = valid ? r1 : 0.f;
      acc[0][mf][nt][2] = valid ? r2 : 0.f;
      acc[0][mf][nt][3] = valid ? r3 : 0.f;
    }
  }
  // phase B: kv accumulation per head (atomic path)
  const int d = t&63, q4 = t>>6;
  float* kfL = smem;          // [32][68]
  float* vL  = smem + 2176;   // [32][68]
  for (int g=0; g<4; g++){
    __syncthreads();
    if (w == g){
      #pragma unroll
      for (int mf=0; mf<4; mf++){
        #pragma unroll
        for (int nt=0; nt<2; nt++){
          int n = nt*16 + ln;
          int cc = mf*16 + lq*4;
          *(float4*)(kfL + n*68 + cc) = make_float4(acc[0][mf][nt][0],acc[0][mf][nt][1],acc[0][mf][nt][2],acc[0][mf][nt][3]);
          *(float4*)(vL  + n*68 + cc) = make_float4(acc[1][mf][nt][0],acc[1][mf][nt][1],acc[1][mf][nt][2],acc[1][mf][nt][3]);
        }
      }
    }
    __syncthreads();
    float4 kvacc[4];
    #pragma unroll
    for (int u=0;u<4;u++) kvacc[u]=f4z();
    float ksl = 0.f;
    for (int row=0; row<32; row++){
      float kd = kfL[row*68 + d];
      ksl += kd;
      const float4* vp = (const float4*)(vL + row*68);
      #pragma unroll
      for (int u=0;u<4;u++) fma4(kvacc[u], kd, vp[q4*4+u]);
    }
    float* kq = kvbuf + ((size_t)(b*Hz + g))*4160;
    #pragma unroll
    for (int u=0;u<4;u++){
      int e = q4*16 + 4*u;
      atomicAdd(&kq[(e+0)*64+d], kvacc[u].x);
      atomicAdd(&kq[(e+1)*64+d], kvacc[u].y);
      atomicAdd(&kq[(e+2)*64+d], kvacc[u].z);
      atomicAdd(&kq[(e+3)*64+d], kvacc[u].w);
    }
    if (q4==0) atomicAdd(&kq[4096+d], ksl);
  }
}

// P[b][h] = kv_h @ Wo_h (64 x 256, K=64), packed bf16 hi/lo output (fused pack_p).
__global__ __launch_bounds__(256) void k_pmat(
    const float* __restrict__ kvbuf, const float* __restrict__ Wo,
    u16* __restrict__ ph, u16* __restrict__ pl){
  __shared__ float smem[8448];
  const int t = threadIdx.x;
  const int bh = blockIdx.x;
  const int hh = bh & 3;
  const int bb = bh >> 2;
  const int c0 = t&15, rr = t>>4;
  const float* kvp = kvbuf + (size_t)bh*4160;
  for (int id=t; id<4096; id+=256){
    int e=id>>6, d=id&63;
    smem[e*68+d] = kvp[id];
  }
  float4 acc[4][4];
  #pragma unroll
  for (int i=0;i<4;i++){
    #pragma unroll
    for (int j=0;j<4;j++) acc[i][j]=f4z();
  }
  for (int kt=0; kt<64; kt+=16){
    __syncthreads();
    for (int id=t; id<1024; id+=256){
      int wr=id>>6, cf=id&63;
      ((float4*)(smem+4352))[wr*64+cf] = ((const float4*)(Wo + (size_t)(hh*64+kt+wr)*256))[cf];
    }
    __syncthreads();
    for (int kk=0; kk<16; kk++){
      float4 a4 = *(const float4*)(smem + (kt+kk)*68 + 4*rr);
      const float4* wrow = (const float4*)(smem+4352) + kk*64;
      float4 w0=wrow[c0], w1=wrow[c0+16], w2=wrow[c0+32], w3=wrow[c0+48];
      #pragma unroll
      for (int i=0;i<4;i++){
        float ac = fcomp(a4,i);
        fma4(acc[i][0],ac,w0); fma4(acc[i][1],ac,w1); fma4(acc[i][2],ac,w2); fma4(acc[i][3],ac,w3);
      }
    }
  }
  // fused pack: P[hd=4rr+i][oc=4c0+64j+q2] -> A-frag bf16 hi/lo
  #pragma unroll
  for (int i=0;i<4;i++){
    int hd = 4*rr + i;
    int e = hd & 7;
    int ln4 = (hd>>3) & 3;
    int ks2 = (hh*64 + hd) >> 5;
    #pragma unroll
    for (int j=0;j<4;j++){
      float4 v = acc[i][j];
      #pragma unroll
      for (int q2=0;q2<4;q2++){
        int oc = 4*c0 + 64*j + q2;
        int ct = oc>>4, l15 = oc&15;
        size_t idx = (size_t)bb*65536 + (((size_t)((ks2*16+ct)*64) + (l15 | (ln4<<4)))*8) + e;
        float val = fcomp(v, q2);
        uint hbt = hi16(val);
        uint lbt = hi16(val - __uint_as_float(hbt<<16));
        ph[idx] = (u16)hbt; pl[idx] = (u16)lbt;
      }
    }
  }
}

// ---------------- MFMA k_att ----------------
#define AH_OFF 0
#define AL_OFF 16384
#define BH_OFF 32768
#define BL_OFF 37888
#define KS_OFF 43008
__global__ __launch_bounds__(256) void k_att(
    float* __restrict__ h,
    const u16* __restrict__ wqh, const u16* __restrict__ wql,
    const u16* __restrict__ pth, const u16* __restrict__ ptl,
    const float* __restrict__ kvbuf,
    const float* __restrict__ cost, const float* __restrict__ sint){
  __shared__ float smem[11008];
  char* sb = (char*)smem;
  const int t = threadIdx.x;
  const int b = blockIdx.y;
  const int n0 = blockIdx.x*64;
  const int w = t>>6;
  const int lane = t&63;
  const int ln = t&15;
  const int lq = (t>>4)&3;
  float* hb = h + (size_t)b*Nz*Dz;
  ((float*)(sb+KS_OFF))[t] = kvbuf[(size_t)(b*Hz + w)*4160 + 4096 + lane];
  floatx4 acc[4][4];
  #pragma unroll
  for (int i=0;i<4;i++)
    #pragma unroll
    for (int j=0;j<4;j++){ acc[i][j][0]=0.f; acc[i][j][1]=0.f; acc[i][j][2]=0.f; acc[i][j][3]=0.f; }

  for (int ks=0; ks<8; ks++){
    __syncthreads();
    const u16* sh = wqh + (size_t)ks*8192;
    const u16* sl = wql + (size_t)ks*8192;
    #pragma unroll
    for (int j=0;j<4;j++){
      int c = w*4 + j;
      gl16b(sh + c*512 + lane*8, sb + AH_OFF + c*1024);
      gl16b(sl + c*512 + lane*8, sb + AL_OFF + c*1024);
    }
    {
      int n = n0 + (t>>2);
      const float* hp = hb + (size_t)n*Dz + ks*32 + (t&3)*8;
      float x[8];
      if (n < Nz){
        float4 v0 = *(const float4*)(hp);
        float4 v1 = *(const float4*)(hp+4);
        x[0]=v0.x; x[1]=v0.y; x[2]=v0.z; x[3]=v0.w;
        x[4]=v1.x; x[5]=v1.y; x[6]=v1.z; x[7]=v1.w;
      } else {
        #pragma unroll
        for (int e=0;e<8;e++) x[e]=0.f;
      }
      uint hw[4], lw[4];
      #pragma unroll
      for (int e=0;e<4;e++){
        uint h0=hi16(x[2*e]), h1=hi16(x[2*e+1]);
        uint l0=hi16(x[2*e]-__uint_as_float(h0<<16));
        uint l1=hi16(x[2*e+1]-__uint_as_float(h1<<16));
        hw[e]=h0|(h1<<16); lw[e]=l0|(l1<<16);
      }
      int a16 = (((t>>2)*5 + (t&3))<<4);
      *(uint4*)(sb + BH_OFF + a16) = make_uint4(hw[0],hw[1],hw[2],hw[3]);
      *(uint4*)(sb + BL_OFF + a16) = make_uint4(lw[0],lw[1],lw[2],lw[3]);
    }
    __syncthreads();
    U8 bh[4], bl[4];
    #pragma unroll
    for (int nt=0; nt<4; nt++){
      int a16 = (((nt*16+ln)*5 + lq)<<4);
      bh[nt].q = *(const uint4*)(sb + BH_OFF + a16);
      bl[nt].q = *(const uint4*)(sb + BL_OFF + a16);
    }
    #pragma unroll
    for (int mf=0; mf<4; mf++){
      U8 ah, al;
      int a16 = (((w*4+mf)*64 + lane)<<4);
      ah.q = *(const uint4*)(sb + AH_OFF + a16);
      al.q = *(const uint4*)(sb + AL_OFF + a16);
      #pragma unroll
      for (int nt=0; nt<4; nt++){
        acc[mf][nt] = __builtin_amdgcn_mfma_f32_16x16x32_bf16(ah.v, bh[nt].v, acc[mf][nt], 0,0,0);
        acc[mf][nt] = __builtin_amdgcn_mfma_f32_16x16x32_bf16(ah.v, bl[nt].v, acc[mf][nt], 0,0,0);
        acc[mf][nt] = __builtin_amdgcn_mfma_f32_16x16x32_bf16(al.v, bh[nt].v, acc[mf][nt], 0,0,0);
      }
    }
  }
  uint2 qzh[4][4], qzl[4][4];
  {
    float4 ks4[4];
    #pragma unroll
    for (int mf=0; mf<4; mf++)
      ks4[mf] = *(const float4*)(sb + KS_OFF + ((w*64 + mf*16 + lq*4)<<2));
    float psum[4] = {0.f,0.f,0.f,0.f};
    #pragma unroll
    for (int mf=0; mf<4; mf++){
      #pragma unroll
      for (int nt=0; nt<4; nt++){
        int n = n0 + nt*16 + ln;
        int nc = (n < Nz) ? n : (Nz-1);
        int pi = mf*8 + lq*2;
        float2 c2 = *(const float2*)(cost + (size_t)nc*32 + pi);
        float2 s2 = *(const float2*)(sint + (size_t)nc*32 + pi);
        float q0 = acc[mf][nt][0], q1 = acc[mf][nt][1];
        float q2 = acc[mf][nt][2], q3 = acc[mf][nt][3];
        float r0 = elu1(q0*c2.x - q1*s2.x);
        float r1 = elu1(q0*s2.x + q1*c2.x);
        float r2 = elu1(q2*c2.y - q3*s2.y);
        float r3 = elu1(q2*s2.y + q3*c2.y);
        acc[mf][nt][0]=r0; acc[mf][nt][1]=r1; acc[mf][nt][2]=r2; acc[mf][nt][3]=r3;
        psum[nt] += r0*ks4[mf].x + r1*ks4[mf].y + r2*ks4[mf].z + r3*ks4[mf].w;
      }
    }
    float zt[4];
    #pragma unroll
    for (int nt=0; nt<4; nt++){
      float p = psum[nt];
      p += __shfl_xor(p, 16, 64);
      p += __shfl_xor(p, 32, 64);
      zt[nt] = 1.f/(p + 1e-6f);
    }
    #pragma unroll
    for (int mf=0; mf<4; mf++){
      #pragma unroll
      for (int nt=0; nt<4; nt++){
        float v0 = acc[mf][nt][0]*zt[nt];
        float v1 = acc[mf][nt][1]*zt[nt];
        float v2 = acc[mf][nt][2]*zt[nt];
        float v3 = acc[mf][nt][3]*zt[nt];
        uint h0=hi16(v0), h1=hi16(v1), h2=hi16(v2), h3=hi16(v3);
        qzh[mf][nt] = make_uint2(h0|(h1<<16), h2|(h3<<16));
        uint l0=hi16(v0-__uint_as_float(h0<<16));
        uint l1=hi16(v1-__uint_as_float(h1<<16));
        uint l2=hi16(v2-__uint_as_float(h2<<16));
        uint l3=hi16(v3-__uint_as_float(h3<<16));
        qzl[mf][nt] = make_uint2(l0|(l1<<16), l2|(l3<<16));
      }
    }
  }
  floatx4 acc2[4][4];
  #pragma unroll
  for (int i=0;i<4;i++)
    #pragma unroll
    for (int j=0;j<4;j++){ acc2[i][j][0]=0.f; acc2[i][j][1]=0.f; acc2[i][j][2]=0.f; acc2[i][j][3]=0.f; }
  for (int ks2=0; ks2<8; ks2++){
    __syncthreads();
    const u16* sh = pth + (size_t)(b*8 + ks2)*8192;
    const u16* sl = ptl + (size_t)(b*8 + ks2)*8192;
    #pragma unroll
    for (int j=0;j<4;j++){
      int c = w*4 + j;
      gl16b(sh + c*512 + lane*8, sb + AH_OFF + c*1024);
      gl16b(sl + c*512 + lane*8, sb + AL_OFF + c*1024);
    }
    if (w == (ks2>>1)){
      #pragma unroll
      for (int mm=0; mm<2; mm++){
        int mf = ((ks2&1)<<1) + mm;
        int g = (mm<<1) + (lq>>1);
        int sub = (lq&1)*8;
        #pragma unroll
        for (int nt=0; nt<4; nt++){
          int a16 = (((nt*16+ln)*5 + g)<<4) + sub;
          *(uint2*)(sb + BH_OFF + a16) = qzh[mf][nt];
          *(uint2*)(sb + BL_OFF + a16) = qzl[mf][nt];
        }
      }
    }
    __syncthreads();
    U8 bh[4], bl[4];
    #pragma unroll
    for (int nt=0; nt<4; nt++){
      int a16 = (((nt*16+ln)*5 + lq)<<4);
      bh[nt].q = *(const uint4*)(sb + BH_OFF + a16);
      bl[nt].q = *(const uint4*)(sb + BL_OFF + a16);
    }
    #pragma unroll
    for (int mf=0; mf<4; mf++){
      U8 ah, al;
      int a16 = (((w*4+mf)*64 + lane)<<4);
      ah.q = *(const uint4*)(sb + AH_OFF + a16);
      al.q = *(const uint4*)(sb + AL_OFF + a16);
      #pragma unroll
      for (int nt=0; nt<4; nt++){
        acc2[mf][nt] = __builtin_amdgcn_mfma_f32_16x16x32_bf16(ah.v, bh[nt].v, acc2[mf][nt], 0,0,0);
        acc2[mf][nt] = __builtin_amdgcn_mfma_f32_16x16x32_bf16(ah.v, bl[nt].v, acc2[mf][nt], 0,0,0);
        acc2[mf][nt] = __builtin_amdgcn_mfma_f32_16x16x32_bf16(al.v, bh[nt].v, acc2[mf][nt], 0,0,0);
      }
    }
  }
  #pragma unroll
  for (int mf=0; mf<4; mf++){
    #pragma unroll
    for (int nt=0; nt<4; nt++){
      int n = n0 + nt*16 + ln;
      if (n < Nz){
        float* hp = hb + (size_t)n*Dz + w*64 + mf*16 + lq*4;
        float4 hv = *(const float4*)hp;
        hv.x += acc2[mf][nt][0];
        hv.y += acc2[mf][nt][1];
        hv.z += acc2[mf][nt][2];
        hv.w += acc2[mf][nt][3];
        *(float4*)hp = hv;
      }
    }
  }
}

__global__ __launch_bounds__(256) void k_wkv(const float* __restrict__ h,
    const float* __restrict__ Wwk, const float* __restrict__ Wwv,
    float* __restrict__ wkbuf, float* __restrict__ wvbuf){
  __shared__ float wtL[16*257];
  int t = threadIdx.x;
  int b = blockIdx.y, m0 = blockIdx.x*16;
  const float* hb = h + ((size_t)b*Nz + (Nz-64))*Dz;
  for (int i=t;i<16*Dz;i+=256){ int r=i>>8,c=i&255; wtL[r*257+c] = hb[(size_t)(m0+r)*Dz + c]; }
  __syncthreads();
  int r=t>>4, c0=t&15;
  float4 ak0=f4z(),ak1=f4z(),av0=f4z(),av1=f4z();
  for (int kk=0;kk<Dz;kk++){
    float hv = wtL[r*257+kk];
    const float4* wk4 = (const float4*)(Wwk + (size_t)kk*DCz);
    const float4* wv4 = (const float4*)(Wwv + (size_t)kk*DCz);
    fma4(ak0,hv,wk4[c0]); fma4(ak1,hv,wk4[c0+16]);
    fma4(av0,hv,wv4[c0]); fma4(av1,hv,wv4[c0+16]);
  }
  float4* ok = (float4*)(wkbuf + (size_t)(b*64 + m0+r)*DCz);
  float4* ov = (float4*)(wvbuf + (size_t)(b*64 + m0+r)*DCz);
  ok[c0]=ak0; ok[c0+16]=ak1; ov[c0]=av0; ov[c0+16]=av1;
}

__global__ __launch_bounds__(256) void k_cache_upd(float* __restrict__ cache,
    const float* __restrict__ wkbuf, const float* __restrict__ wvbuf,
    const float* __restrict__ Wwg, const float* __restrict__ bwg,
    int s0, int it, int pas){
  __shared__ float sqL[16*132];
  __shared__ float wkL[64*132];
  __shared__ float wat[16*68];
  __shared__ float ncL[16*132];
  __shared__ float wg[16];
  int t = threadIdx.x; int b = blockIdx.x;
  for (int i=t;i<16*DCz;i+=256){ int k2=i>>7,c=i&127; sqL[k2*132+c] = cache[((size_t)(b*NSLOTz)+s0+k2)*DSLOTz + c]; }
  for (int i=t;i<64*DCz;i+=256){ int m=i>>7,c=i&127; wkL[m*132+c] = wkbuf[(size_t)(b*64+m)*DCz+c]; }
  __syncthreads();
  {
    int k2 = t>>4;
    const float4* s4 = (const float4*)(sqL) + k2*33;
    for (int mm=0;mm<4;mm++){
      int m = (t&15) + 16*mm;
      const float4* k4 = (const float4*)(wkL) + m*33;
      float a=0.f;
      for (int d4=0;d4<32;d4++) a += dot4(s4[d4], k4[d4]);
      wat[k2*68+m] = a * 0.088388347648318447f;
    }
  }
  __syncthreads();
  if (t<16){
    float mx=-1e30f;
    for (int m=0;m<64;m++) mx = fmaxf(mx, wat[t*68+m]);
    float su=0.f;
    for (int m=0;m<64;m++){ float e=__expf(wat[t*68+m]-mx); wat[t*68+m]=e; su+=e; }
    float inv=1.f/su;
    for (int m=0;m<64;m++) wat[t*68+m]*=inv;
  }
  __syncthreads();
  {
    int k2=t>>4, c0=t&15;
    float4 a0=f4z(), a1=f4z();
    const float4* wvg = (const float4*)(wvbuf + (size_t)b*64*DCz);
    for (int m=0;m<64;m++){
      float a = wat[k2*68+m];
      fma4(a0,a,wvg[m*32+c0]); fma4(a1,a,wvg[m*32+c0+16]);
    }
    ((float4*)ncL)[k2*33+c0]=a0; ((float4*)ncL)[k2*33+16+c0]=a1;
  }
  __syncthreads();
  if (t<16){
    float a = bwg[0];
    for (int d2=0; d2<DCz; d2++) a += sqL[t*132+d2]*Wwg[d2] + ncL[t*132+d2]*Wwg[DCz+d2];
    wg[t] = sigm(a);
  }
  __syncthreads();
  for (int i=t;i<16*DCz;i+=256){
    int k2=i>>7,c=i&127;
    cache[((size_t)(b*NSLOTz)+s0+k2)*DSLOTz + c] = sqL[k2*132+c] + wg[k2]*ncL[k2*132+c];
  }
  if (t<16){
    float* cp = cache + ((size_t)(b*NSLOTz)+s0+t)*DSLOTz;
    cp[128] = wg[t];
    cp[137] = (it==0)?1.f:0.f; cp[138] = (it==1)?1.f:0.f; cp[139]=0.f; cp[140]=0.f;
    cp[141] = (pas==0)?1.f:0.f; cp[142] = (pas==1)?1.f:0.f; cp[143]=0.f; cp[144]=0.f;
  }
}

__global__ __launch_bounds__(256) void k_logits(const float* __restrict__ h,
    const float* __restrict__ Wout, const float* __restrict__ bout, float* __restrict__ out){
  __shared__ float hl[16*257];
  int t = threadIdx.x; int row0 = blockIdx.x*16;
  for (int i=t;i<16*Dz;i+=256){
    int rr=i>>8,c=i&255; int row=row0+rr; int b=row/Sz, s=row-b*Sz;
    hl[rr*257+c] = h[((size_t)b*Nz + TSz + s)*Dz + c];
  }
  __syncthreads();
  int rr = t>>4, v = t&15;
  float a = bout[v];
  for (int c=0;c<Dz;c++) a += hl[rr*257+c]*Wout[c*Vz + v];
  out[(size_t)(row0+rr)*Vz + v] = a;
}

__global__ __launch_bounds__(256) void k_feedback(float* __restrict__ h,
    const float* __restrict__ logits0, const float* __restrict__ pae,
    const float* __restrict__ Wfb, const float* __restrict__ bfb){
  __shared__ float trL[16*257];
  __shared__ float paeL[16*257];
  __shared__ int amL[16];
  int t = threadIdx.x; int b = blockIdx.y; int s0 = blockIdx.x*16;
  if (t<16){
    int s = s0+t; int am=0;
    if (s < Sz){
      const float* lg = logits0 + (size_t)(b*Sz+s)*Vz;
      float best = lg[0];
      for (int v=1;v<16;v++){ if (lg[v] > best){ best=lg[v]; am=v; } }
    }
    amL[t]=am;
  }
  for (int i=t;i<16*Dz;i+=256){
    int rr=i>>8,c=i&255; int s=s0+rr;
    trL[rr*257+c] = (s<Sz)? h[((size_t)b*Nz + TSz + s)*Dz + c] : 0.f;
  }
  __syncthreads();
  for (int i=t;i<16*Dz;i+=256){ int rr=i>>8,c=i&255; paeL[rr*257+c] = pae[(size_t)amL[rr]*Dz + c]; }
  __syncthreads();
  int r=t>>4, c0=t&15;
  float4 acc[4]; acc[0]=f4z(); acc[1]=f4z(); acc[2]=f4z(); acc[3]=f4z();
  for (int kk=0;kk<Dz;kk++){
    float xv = trL[r*257+kk];
    const float4* wr = (const float4*)(Wfb + (size_t)kk*Dz);
    fma4(acc[0],xv,wr[c0]); fma4(acc[1],xv,wr[c0+16]); fma4(acc[2],xv,wr[c0+32]); fma4(acc[3],xv,wr[c0+48]);
  }
  for (int kk=0;kk<Dz;kk++){
    float xv = paeL[r*257+kk];
    const float4* wr = (const float4*)(Wfb + (size_t)(Dz+kk)*Dz);
    fma4(acc[0],xv,wr[c0]); fma4(acc[1],xv,wr[c0+16]); fma4(acc[2],xv,wr[c0+32]); fma4(acc[3],xv,wr[c0+48]);
  }
  int s = s0+r;
  if (s < Sz){
    float* cp = h + ((size_t)b*Nz + TSz + s)*Dz;
    #pragma unroll
    for (int j=0;j<4;j++){
      float vals[4] = {acc[j].x, acc[j].y, acc[j].z, acc[j].w};
      #pragma unroll
      for (int q2=0;q2<4;q2++){
        int c = (c0+16*j)*4 + q2;
        float g = sigm(vals[q2] + bfb[c]);
        cp[c] = trL[r*257+c] + g*paeL[r*257+c];
      }
    }
  }
}

extern "C" void kernel_launch(void* const* d_in, const int* in_sizes, int n_in,
                              void* d_out, int out_size, void* d_ws, size_t ws_size,
                              hipStream_t stream){
  (void)in_sizes; (void)n_in;
  const int*   demo_in   = (const int*)d_in[0];
  const int*   demo_out  = (const int*)d_in[1];
  const int*   test_in   = (const int*)d_in[2];
  const float* token_emb = (const float*)d_in[3];
  const float* seg_emb   = (const float*)d_in[4];
  const float* slot_emb  = (const float*)d_in[5];
  const float* lid_emb   = (const float*)d_in[6];
  const float* Wq_read   = (const float*)d_in[7];
  const float* Wk_read   = (const float*)d_in[8];
  const float* Wv_read   = (const float*)d_in[9];
  const float* Wg_read   = (const float*)d_in[10];
  const float* bg_read   = (const float*)d_in[11];
  const float* Wqkv      = (const float*)d_in[12];
  const float* Wo        = (const float*)d_in[13];
  const float* Wwk       = (const float*)d_in[14];
  const float* Wwv       = (const float*)d_in[15];
  const float* Wwg       = (const float*)d_in[16];
  const float* bwg       = (const float*)d_in[17];
  const float* Wout      = (const float*)d_in[18];
  const float* bout      = (const float*)d_in[19];
  const float* pae       = (const float*)d_in[20];
  const float* Wfb       = (const float*)d_in[21];
  const float* bfb       = (const float*)d_in[22];

  char* wsb = (char*)d_ws;
  size_t off = 0;
  auto alloc = [&](size_t bytes)->char*{
    char* p = wsb + off;
    off += (bytes + 255) & ~(size_t)255;
    return p;
  };
  float* hbuf   = (float*)alloc((size_t)Bz*Nz*Dz*4);
  float* cache  = (float*)alloc((size_t)Bz*NSLOTz*DSLOTz*4);
  float* kvbuf  = (float*)alloc((size_t)Bz*Hz*4160*4);
  float* wkbuf  = (float*)alloc((size_t)Bz*64*DCz*4);
  float* wvbuf  = (float*)alloc((size_t)Bz*64*DCz*4);
  float* logits0= (float*)alloc((size_t)Bz*Sz*Vz*4);
  float* cost   = (float*)alloc((size_t)Nz*32*4);
  float* sint   = (float*)alloc((size_t)Nz*32*4);
  u16*   wqth   = (u16*)alloc((size_t)3*65536*2);
  u16*   wqtl   = (u16*)alloc((size_t)3*65536*2);
  u16*   pth    = (u16*)alloc((size_t)16*65536*2);
  u16*   ptl    = (u16*)alloc((size_t)16*65536*2);
  u16*   wkvh   = (u16*)alloc((size_t)3*131072*2);
  u16*   wkvl   = (u16*)alloc((size_t)3*131072*2);
  u16*   wqrh   = (u16*)alloc((size_t)3*32768*2);
  u16*   wqrl   = (u16*)alloc((size_t)3*32768*2);
  u16*   krh    = (u16*)alloc((size_t)Bz*6144*2);
  u16*   krl    = (u16*)alloc((size_t)Bz*6144*2);
  u16*   vrh    = (u16*)alloc((size_t)Bz*16384*2);
  u16*   vrl    = (u16*)alloc((size_t)Bz*16384*2);

  if (off > ws_size){
    k_sentinel<<<(out_size+255)/256, 256, 0, stream>>>((float*)d_out, out_size);
    return;
  }

  k_rope<<<(Nz*32+255)/256, 256, 0, stream>>>(cost, sint);
  k_cache_init<<<(Bz*NSLOTz*DSLOTz+255)/256, 256, 0, stream>>>(slot_emb, lid_emb, cache);
  k_pack_w<<<768, 256, 0, stream>>>(Wqkv, wqth, wqtl);
  k_pack_wkv<<<1536, 256, 0, stream>>>(Wqkv, wkvh, wkvl);
  k_pack_wr<<<384, 256, 0, stream>>>(Wq_read, wqrh, wqrl);
  // zero vreadp once: pad rows s=48..63 must be 0 bf16 forever
  k_zero<<<512, 256, 0, stream>>>((float*)vrh, Bz*16384/2);
  k_zero<<<512, 256, 0, stream>>>((float*)vrl, Bz*16384/2);

  const int KVN = Bz*Hz*4160;
  for (int pas=0; pas<2; pas++){
    k_embed<<<(Bz*Nz*64+255)/256, 256, 0, stream>>>(demo_in, demo_out, test_in, token_emb, seg_emb, hbuf);
    if (pas==1)
      k_feedback<<<dim3(57,Bz), 256, 0, stream>>>(hbuf, logits0, pae, Wfb, bfb);
    for (int l=0; l<3; l++){
      for (int it=0; it<2; it++){
        k_proj_cache<<<Bz*NSLOTz, 384, 0, stream>>>(cache,
            Wk_read + (size_t)l*DSLOTz*DCz, Wv_read + (size_t)l*DSLOTz*Dz,
            krh, krl, vrh, vrl);
        k_read_attn<<<dim3(GXA,Bz), 256, 0, stream>>>(hbuf,
            wqrh + (size_t)l*32768, wqrl + (size_t)l*32768,
            krh, krl, vrh, vrl,
            Wg_read + (size_t)l*Dz, bg_read + l);
        k_zero<<<(KVN+255)/256, 256, 0, stream>>>(kvbuf, KVN);
        k_kv<<<dim3(GXB,Bz), 256, 0, stream>>>(hbuf,
            wkvh + (size_t)l*131072, wkvl + (size_t)l*131072, cost, sint, kvbuf);
        k_pmat<<<Bz*Hz, 256, 0, stream>>>(kvbuf, Wo + (size_t)l*Dz*Dz, pth, ptl);
        k_att<<<dim3(GXA,Bz), 256, 0, stream>>>(hbuf,
            wqth + (size_t)l*65536, wqtl + (size_t)l*65536, pth, ptl,
            kvbuf, cost, sint);
        k_wkv<<<dim3(4,Bz), 256, 0, stream>>>(hbuf,
            Wwk + (size_t)l*Dz*DCz, Wwv + (size_t)l*Dz*DCz, wkbuf, wvbuf);
        k_cache_upd<<<Bz, 256, 0, stream>>>(cache, wkbuf, wvbuf,
            Wwg + (size_t)l*2*DCz, bwg + l, l*16, it, pas);
      }
    }
    float* outp = (pas==0) ? logits0 : (float*)d_out;
    k_logits<<<900, 256, 0, stream>>>(hbuf, Wout, bout, outp);
  }
}

// Round 9
// 8164.043 us; speedup vs baseline: 1.0595x; 1.0595x over previous
//
#include <hip/hip_runtime.h>
#include <math.h>

#define Bz 16
#define Sz 900
#define Vz 16
#define Dz 256
#define DCz 128
#define Hz 4
#define Nz 6300
#define TSz 5400
#define DSLOTz 145
#define NSLOTz 48
#define GXA 99    // ceil(6300/64) row-blocks

typedef unsigned short u16;
typedef unsigned int u32;

typedef __bf16 bf16x8 __attribute__((ext_vector_type(8)));
typedef float floatx4 __attribute__((ext_vector_type(4)));
union U8 { bf16x8 v; uint4 q; };

static __device__ __forceinline__ float sigm(float x){ return 1.0f/(1.0f+__expf(-x)); }
static __device__ __forceinline__ void fma4(float4& a, float s, float4 b){ a.x+=s*b.x; a.y+=s*b.y; a.z+=s*b.z; a.w+=s*b.w; }
static __device__ __forceinline__ float dot4(float4 a, float4 b){ return a.x*b.x + a.y*b.y + a.z*b.z + a.w*b.w; }
static __device__ __forceinline__ float4 f4z(){ float4 z; z.x=0.f; z.y=0.f; z.z=0.f; z.w=0.f; return z; }
static __device__ __forceinline__ float elu1(float x){ return x>0.f ? x+1.f : __expf(x); }
static __device__ __forceinline__ float fcomp(float4 v, int i){ return (i==0)?v.x:(i==1)?v.y:(i==2)?v.z:v.w; }

// round-to-nearest-even bf16 (top 16 bits) of f32
static __device__ __forceinline__ uint hi16(float x){
  uint u = __float_as_uint(x);
  return (u + 0x7fffu + ((u>>16)&1u)) >> 16;
}

typedef const void GV __attribute__((address_space(1)));
typedef void LV __attribute__((address_space(3)));
static __device__ __forceinline__ void gl16(const float* g, float* l){
  __builtin_amdgcn_global_load_lds((GV*)g, (LV*)l, 16, 0, 0);
}
static __device__ __forceinline__ void gl16b(const void* g, void* l){
  __builtin_amdgcn_global_load_lds((GV*)g, (LV*)l, 16, 0, 0);
}

__global__ void k_sentinel(float* out, int nelem){
  int i = blockIdx.x*256 + threadIdx.x;
  if (i < nelem) out[i] = 12345.0f;
}

__global__ void k_zero(float* p, int n){
  int i = blockIdx.x*256 + threadIdx.x;
  if (i < n) p[i] = 0.f;
}

__global__ void k_rope(float* cost, float* sint){
  int i = blockIdx.x*256 + threadIdx.x;
  if (i >= Nz*32) return;
  int n = i>>5, f = i&31;
  double invd = pow(10000.0, -(double)f/32.0);
  double fr = (double)n * invd;
  cost[i] = (float)cos(fr);
  sint[i] = (float)sin(fr);
}

__global__ void k_embed(const int* __restrict__ di, const int* __restrict__ dq,
                        const int* __restrict__ ti, const float* __restrict__ temb,
                        const float* __restrict__ semb, float* __restrict__ h){
  int i = blockIdx.x*256 + threadIdx.x;   // over B*N*64 float4s
  if (i >= Bz*Nz*64) return;
  int dv = i & 63; int bn = i >> 6; int n = bn % Nz; int b = bn / Nz;
  int tok;
  if (n < TSz){
    int nd = n/1800; int r = n - nd*1800;
    tok = (r < Sz) ? di[(b*3+nd)*Sz + r] : dq[(b*3+nd)*Sz + (r-Sz)];
  } else {
    tok = ti[b*Sz + (n-TSz)];
  }
  const float4* e4 = (const float4*)(temb + (size_t)tok*Dz);
  const float4* s4 = (const float4*)semb;
  float4 v = e4[dv]; float4 s = s4[dv];
  v.x += s.x; v.y += s.y; v.z += s.z; v.w += s.w;
  ((float4*)h)[(size_t)bn*64 + dv] = v;
}

__global__ void k_cache_init(const float* __restrict__ slot_emb, const float* __restrict__ lid,
                             float* __restrict__ cache){
  int i = blockIdx.x*256 + threadIdx.x;
  if (i >= Bz*NSLOTz*DSLOTz) return;
  int c = i % DSLOTz; int sc = (i / DSLOTz) % NSLOTz; int l = sc >> 4;
  float v = 0.f;
  if (c < DCz) v = slot_emb[sc*DCz + c];
  else if (c >= 129 && c < 137) v = lid[l*8 + (c-129)];
  cache[i] = v;
}

// pack Wq^T (cols 0..256 of Wqkv) into MFMA A-fragment order, bf16 hi/lo.
__global__ void k_pack_w(const float* __restrict__ Wqkv,
                         u16* __restrict__ wh, u16* __restrict__ wl){
  int i = blockIdx.x*256 + threadIdx.x;
  if (i >= 3*65536) return;
  int l = i >> 16; int r = i & 65535;
  int ks = r >> 13; int ct = (r>>9)&15; int lane = (r>>3)&63; int e = r&7;
  int k = ks*32 + ((lane>>4)<<3) + e;
  int c = ct*16 + (lane&15);
  float x = Wqkv[(size_t)l*196608 + (size_t)k*768 + c];
  uint hb = hi16(x);
  uint lb = hi16(x - __uint_as_float(hb<<16));
  wh[i] = (u16)hb; wl[i] = (u16)lb;
}

// pack Wkv^T (cols 256..768 of Wqkv) into MFMA A-fragment order, bf16 hi/lo.
__global__ void k_pack_wkv(const float* __restrict__ Wqkv,
                           u16* __restrict__ wh, u16* __restrict__ wl){
  int i = blockIdx.x*256 + threadIdx.x;
  if (i >= 3*131072) return;
  int l = i / 131072; int r = i % 131072;
  int ks = r >> 14; int ct = (r>>9)&31; int lane = (r>>3)&63; int e = r&7;
  int k = ks*32 + ((lane>>4)<<3) + e;
  int c = ct*16 + (lane&15);
  float x = Wqkv[(size_t)l*196608 + (size_t)k*768 + 256 + c];
  uint hb = hi16(x);
  uint lb = hi16(x - __uint_as_float(hb<<16));
  wh[i] = (u16)hb; wl[i] = (u16)lb;
}

// pack Wq_read^T into MFMA A-fragment order, bf16 hi/lo.
__global__ void k_pack_wr(const float* __restrict__ Wqr,
                          u16* __restrict__ wh, u16* __restrict__ wl){
  int i = blockIdx.x*256 + threadIdx.x;
  if (i >= 3*32768) return;
  int l = i >> 15; int r = i & 32767;
  int ks = r >> 12; int ct = (r>>9)&7; int lane = (r>>3)&63; int e = r&7;
  int k = ks*32 + ((lane>>4)<<3) + e;
  int c = ct*16 + (lane&15);
  float x = Wqr[(size_t)l*32768 + (size_t)k*DCz + c];
  uint hb = hi16(x);
  uint lb = hi16(x - __uint_as_float(hb<<16));
  wh[i] = (u16)hb; wl[i] = (u16)lb;
}

// pack Pcat^T into MFMA A-fragment order, bf16 hi/lo (coalesced reads+writes).
__global__ void k_pack_p(const float* __restrict__ pmat,
                         u16* __restrict__ ph, u16* __restrict__ pl){
  int i = blockIdx.x*256 + threadIdx.x;
  if (i >= 16*65536) return;
  int b = i >> 16; int r = i & 65535;
  int ks2 = r >> 13; int ct = (r>>9)&15; int lane = (r>>3)&63; int e = r&7;
  int c = ks2*32 + ((lane>>4)<<3) + e;
  int oc = ct*16 + (lane&15);
  float x = pmat[(((size_t)(b*4 + (c>>6)))*64 + (c&63))*256 + oc];
  uint hb = hi16(x);
  uint lb = hi16(x - __uint_as_float(hb<<16));
  ph[i] = (u16)hb; pl[i] = (u16)lb;
}

// cache->kread/vread projections, emitted directly in bf16 hi/lo MFMA A-frag order.
__global__ __launch_bounds__(384) void k_proj_cache(const float* __restrict__ cache,
    const float* __restrict__ Wk, const float* __restrict__ Wv,
    u16* __restrict__ krh, u16* __restrict__ krl,
    u16* __restrict__ vrh, u16* __restrict__ vrl){
  __shared__ float crow[DSLOTz];
  int b = blockIdx.x / NSLOTz, sc = blockIdx.x % NSLOTz;
  int t = threadIdx.x;
  const float* cp = cache + (size_t)(b*NSLOTz+sc)*DSLOTz;
  if (t < DSLOTz) crow[t] = cp[t];
  __syncthreads();
  if (t < DCz){
    float a = 0.f;
    for (int r2=0;r2<DSLOTz;r2++) a += crow[r2]*Wk[r2*DCz + t];
    uint hb = hi16(a);
    uint lb = hi16(a - __uint_as_float(hb<<16));
    int ks = t>>5, st = sc>>4, lane = (sc&15) | (((t>>3)&3)<<4), e = t&7;
    size_t idx = (size_t)b*6144 + (size_t)(((ks*3+st)*64 + lane)*8 + e);
    krh[idx] = (u16)hb; krl[idx] = (u16)lb;
  } else {
    int d = t - DCz;
    float a = 0.f;
    for (int r2=0;r2<DSLOTz;r2++) a += crow[r2]*Wv[r2*Dz + d];
    uint hb = hi16(a);
    uint lb = hi16(a - __uint_as_float(hb<<16));
    int ot = d>>4, ks2 = sc>>5, lane = (d&15) | (((sc>>3)&3)<<4), e = sc&7;
    size_t idx = (size_t)b*16384 + (size_t)(((ks2*16+ot)*64 + lane)*8 + e);
    vrh[idx] = (u16)hb; vrl[idx] = (u16)lb;
  }
}

// ---------------- MFMA k_read_attn (also zeroes kvbuf for this iteration) ------
#define RA2_BH 0
#define RA2_BL 5120
#define RA2_QBH 10240
#define RA2_QBL 30720
#define RA2_ABH 10240
#define RA2_ABL 20480
#define RA2_G  51200
#define RA2_WG 51456
__global__ __launch_bounds__(256) void k_read_attn(
    float* __restrict__ h,
    const u16* __restrict__ wqh, const u16* __restrict__ wql,
    const u16* __restrict__ krh, const u16* __restrict__ krl,
    const u16* __restrict__ vrh, const u16* __restrict__ vrl,
    const float* __restrict__ Wg, const float* __restrict__ bg,
    float* __restrict__ kvbuf){
  __shared__ float smem[13120];
  char* sb = (char*)smem;
  const int t = threadIdx.x;
  const int b = blockIdx.y;
  const int n0 = blockIdx.x*64;
  const int w = t>>6, lane = t&63, ln = t&15, lq = (t>>4)&3;
  float* hb = h + (size_t)b*Nz*Dz;
  { // fold: zero kvbuf (stream order: previous k_att was the last reader)
    int gid = (b*GXA + blockIdx.x)*256 + t;
    if (gid < Bz*Hz*4160) kvbuf[gid] = 0.f;
  }
  ((float*)(sb+RA2_WG))[t] = Wg[t];
  floatx4 acc[2][4];
  #pragma unroll
  for (int i=0;i<2;i++)
    #pragma unroll
    for (int j=0;j<4;j++){ acc[i][j][0]=0.f; acc[i][j][1]=0.f; acc[i][j][2]=0.f; acc[i][j][3]=0.f; }
  for (int ks=0; ks<8; ks++){
    __syncthreads();
    {
      int n = n0 + (t>>2);
      const float* hp = hb + (size_t)n*Dz + ks*32 + (t&3)*8;
      float x[8];
      if (n < Nz){
        float4 v0 = *(const float4*)(hp);
        float4 v1 = *(const float4*)(hp+4);
        x[0]=v0.x; x[1]=v0.y; x[2]=v0.z; x[3]=v0.w;
        x[4]=v1.x; x[5]=v1.y; x[6]=v1.z; x[7]=v1.w;
      } else {
        #pragma unroll
        for (int e=0;e<8;e++) x[e]=0.f;
      }
      uint hw[4], lw[4];
      #pragma unroll
      for (int e=0;e<4;e++){
        uint h0=hi16(x[2*e]), h1=hi16(x[2*e+1]);
        uint l0=hi16(x[2*e]-__uint_as_float(h0<<16));
        uint l1=hi16(x[2*e+1]-__uint_as_float(h1<<16));
        hw[e]=h0|(h1<<16); lw[e]=l0|(l1<<16);
      }
      int a16 = (((t>>2)*5 + (t&3))<<4);
      *(uint4*)(sb + RA2_BH + a16) = make_uint4(hw[0],hw[1],hw[2],hw[3]);
      *(uint4*)(sb + RA2_BL + a16) = make_uint4(lw[0],lw[1],lw[2],lw[3]);
    }
    __syncthreads();
    U8 bh[4], bl[4];
    #pragma unroll
    for (int nt=0; nt<4; nt++){
      int a16 = (((nt*16+ln)*5 + lq)<<4);
      bh[nt].q = *(const uint4*)(sb + RA2_BH + a16);
      bl[nt].q = *(const uint4*)(sb + RA2_BL + a16);
    }
    #pragma unroll
    for (int mf=0; mf<2; mf++){
      U8 ah, al;
      size_t ai = ((size_t)(ks*8 + w*2 + mf))*512 + lane*8;
      ah.q = *(const uint4*)(wqh + ai);
      al.q = *(const uint4*)(wql + ai);
      #pragma unroll
      for (int nt=0; nt<4; nt++){
        acc[mf][nt] = __builtin_amdgcn_mfma_f32_16x16x32_bf16(ah.v, bh[nt].v, acc[mf][nt], 0,0,0);
        acc[mf][nt] = __builtin_amdgcn_mfma_f32_16x16x32_bf16(ah.v, bl[nt].v, acc[mf][nt], 0,0,0);
        acc[mf][nt] = __builtin_amdgcn_mfma_f32_16x16x32_bf16(al.v, bh[nt].v, acc[mf][nt], 0,0,0);
      }
    }
  }
  {
    int n = t>>2, kq = t&3;
    int nn = n0+n; int nc = (nn < Nz) ? nn : (Nz-1);
    const float* hp = hb + (size_t)nc*Dz + kq*64;
    const float* wgp = (const float*)(sb+RA2_WG) + kq*64;
    float a = 0.f;
    for (int k=0;k<64;k+=4){
      float4 hv = *(const float4*)(hp+k);
      float4 wv = *(const float4*)(wgp+k);
      a += dot4(hv,wv);
    }
    a += __shfl_xor(a,1,64);
    a += __shfl_xor(a,2,64);
    if (kq==0) ((float*)(sb+RA2_G))[n] = a;
  }
  {
    #pragma unroll
    for (int mf=0; mf<2; mf++){
      #pragma unroll
      for (int nt=0; nt<4; nt++){
        float v0 = acc[mf][nt][0], v1 = acc[mf][nt][1];
        float v2 = acc[mf][nt][2], v3 = acc[mf][nt][3];
        uint h0=hi16(v0), h1=hi16(v1), h2=hi16(v2), h3=hi16(v3);
        uint l0=hi16(v0-__uint_as_float(h0<<16));
        uint l1=hi16(v1-__uint_as_float(h1<<16));
        uint l2=hi16(v2-__uint_as_float(h2<<16));
        uint l3=hi16(v3-__uint_as_float(h3<<16));
        int a16 = (((nt*16+ln)*5 + (mf*2 + (lq>>1)))<<4) + ((lq&1)<<3);
        *(uint2*)(sb + RA2_QBH + w*5120 + a16) = make_uint2(h0|(h1<<16), h2|(h3<<16));
        *(uint2*)(sb + RA2_QBL + w*5120 + a16) = make_uint2(l0|(l1<<16), l2|(l3<<16));
      }
    }
  }
  __syncthreads();
  floatx4 sacc[3];
  #pragma unroll
  for (int st=0; st<3; st++){ sacc[st][0]=0.f; sacc[st][1]=0.f; sacc[st][2]=0.f; sacc[st][3]=0.f; }
  for (int ks=0; ks<4; ks++){
    U8 bh, bl;
    int a16 = (((w*16+ln)*5 + lq)<<4);
    bh.q = *(const uint4*)(sb + RA2_QBH + ks*5120 + a16);
    bl.q = *(const uint4*)(sb + RA2_QBL + ks*5120 + a16);
    #pragma unroll
    for (int st=0; st<3; st++){
      U8 ah, al;
      size_t ai = (size_t)b*6144 + ((size_t)(ks*3+st))*512 + lane*8;
      ah.q = *(const uint4*)(krh + ai);
      al.q = *(const uint4*)(krl + ai);
      sacc[st] = __builtin_amdgcn_mfma_f32_16x16x32_bf16(ah.v, bh.v, sacc[st], 0,0,0);
      sacc[st] = __builtin_amdgcn_mfma_f32_16x16x32_bf16(ah.v, bl.v, sacc[st], 0,0,0);
      sacc[st] = __builtin_amdgcn_mfma_f32_16x16x32_bf16(al.v, bh.v, sacc[st], 0,0,0);
    }
  }
  {
    const float scl = 0.088388347648318447f;
    float mx = -1e30f;
    #pragma unroll
    for (int st=0; st<3; st++)
      #pragma unroll
      for (int r=0;r<4;r++){ sacc[st][r] *= scl; mx = fmaxf(mx, sacc[st][r]); }
    mx = fmaxf(mx, __shfl_xor(mx, 16, 64));
    mx = fmaxf(mx, __shfl_xor(mx, 32, 64));
    float su = 0.f;
    #pragma unroll
    for (int st=0; st<3; st++)
      #pragma unroll
      for (int r=0;r<4;r++){ float e = __expf(sacc[st][r]-mx); sacc[st][r]=e; su+=e; }
    su += __shfl_xor(su, 16, 64);
    su += __shfl_xor(su, 32, 64);
    float inv = 1.f/su;
    #pragma unroll
    for (int st=0; st<3; st++)
      #pragma unroll
      for (int r=0;r<4;r++) sacc[st][r] *= inv;
  }
  __syncthreads();
  {
    uint2 ah2[3], al2[3];
    #pragma unroll
    for (int st=0; st<3; st++){
      float v0=sacc[st][0], v1=sacc[st][1], v2=sacc[st][2], v3=sacc[st][3];
      uint h0=hi16(v0), h1=hi16(v1), h2=hi16(v2), h3=hi16(v3);
      uint l0=hi16(v0-__uint_as_float(h0<<16));
      uint l1=hi16(v1-__uint_as_float(h1<<16));
      uint l2=hi16(v2-__uint_as_float(h2<<16));
      uint l3=hi16(v3-__uint_as_float(h3<<16));
      ah2[st] = make_uint2(h0|(h1<<16), h2|(h3<<16));
      al2[st] = make_uint2(l0|(l1<<16), l2|(l3<<16));
    }
    int rb = (w*16+ln)*5;
    int sub = (lq&1)<<3;
    #pragma unroll
    for (int st=0; st<2; st++){
      int a16 = ((rb + st*2 + (lq>>1))<<4) + sub;
      *(uint2*)(sb + RA2_ABH + a16) = ah2[st];
      *(uint2*)(sb + RA2_ABL + a16) = al2[st];
    }
    {
      int a16 = ((rb + (lq>>1))<<4) + sub;
      *(uint2*)(sb + RA2_ABH + 5120 + a16) = ah2[2];
      *(uint2*)(sb + RA2_ABL + 5120 + a16) = al2[2];
      int z16 = ((rb + 2 + (lq>>1))<<4) + sub;
      *(uint2*)(sb + RA2_ABH + 5120 + z16) = make_uint2(0,0);
      *(uint2*)(sb + RA2_ABL + 5120 + z16) = make_uint2(0,0);
    }
  }
  __syncthreads();
  floatx4 o[4][4];
  #pragma unroll
  for (int i=0;i<4;i++)
    #pragma unroll
    for (int j=0;j<4;j++){ o[i][j][0]=0.f; o[i][j][1]=0.f; o[i][j][2]=0.f; o[i][j][3]=0.f; }
  #pragma unroll
  for (int ks2=0; ks2<2; ks2++){
    U8 bh[4], bl[4];
    #pragma unroll
    for (int nt=0; nt<4; nt++){
      int a16 = (((nt*16+ln)*5 + lq)<<4);
      bh[nt].q = *(const uint4*)(sb + RA2_ABH + ks2*5120 + a16);
      bl[nt].q = *(const uint4*)(sb + RA2_ABL + ks2*5120 + a16);
    }
    #pragma unroll
    for (int mf=0; mf<4; mf++){
      U8 ah, al;
      size_t ai = (size_t)b*16384 + ((size_t)(ks2*16 + w*4 + mf))*512 + lane*8;
      ah.q = *(const uint4*)(vrh + ai);
      al.q = *(const uint4*)(vrl + ai);
      #pragma unroll
      for (int nt=0; nt<4; nt++){
        o[mf][nt] = __builtin_amdgcn_mfma_f32_16x16x32_bf16(ah.v, bh[nt].v, o[mf][nt], 0,0,0);
        o[mf][nt] = __builtin_amdgcn_mfma_f32_16x16x32_bf16(ah.v, bl[nt].v, o[mf][nt], 0,0,0);
        o[mf][nt] = __builtin_amdgcn_mfma_f32_16x16x32_bf16(al.v, bh[nt].v, o[mf][nt], 0,0,0);
      }
    }
  }
  float bg0 = bg[0];
  #pragma unroll
  for (int nt=0; nt<4; nt++){
    int n = n0 + nt*16 + ln;
    if (n < Nz){
      float gv = sigm(((const float*)(sb+RA2_G))[nt*16+ln] + bg0);
      #pragma unroll
      for (int mf=0; mf<4; mf++){
        float* hp = hb + (size_t)n*Dz + w*64 + mf*16 + lq*4;
        float4 hv = *(const float4*)hp;
        hv.x += gv*o[mf][nt][0];
        hv.y += gv*o[mf][nt][1];
        hv.z += gv*o[mf][nt][2];
        hv.w += gv*o[mf][nt][3];
        *(float4*)hp = hv;
      }
    }
  }
}

// ---------------- MFMA k_kv: A direct->reg, double-buffered B, 1 barrier/ks ----
// (R6 version — empirically best at ~283 µs.)
__global__ __launch_bounds__(256) void k_kv(
    const float* __restrict__ h,
    const u16* __restrict__ wh, const u16* __restrict__ wl,
    const float* __restrict__ cost, const float* __restrict__ sint,
    float* __restrict__ kvbuf){
  __shared__ float smem[8704];
  char* sb = (char*)smem;
  const int t = threadIdx.x;
  const int b = blockIdx.y;
  const int n0 = blockIdx.x*64;
  const int w = t>>6;
  const int lane = t&63;
  const int ln = t&15;
  const int lq = (t>>4)&3;
  const float* hb = h + (size_t)b*Nz*Dz;
  floatx4 acc[2][4][4];
  #pragma unroll
  for (int cp=0;cp<2;cp++)
    #pragma unroll
    for (int i=0;i<4;i++)
      #pragma unroll
      for (int j=0;j<4;j++){ acc[cp][i][j][0]=0.f; acc[cp][i][j][1]=0.f; acc[cp][i][j][2]=0.f; acc[cp][i][j][3]=0.f; }

  const int hrow = t>>2, hcol = t&3;
  const float* hbase = hb + (size_t)(n0+hrow)*Dz + hcol*8;
  const int hvalid = (n0+hrow) < Nz;
  const int a16w = ((hrow*5 + hcol)<<4);

  auto load_h = [&](int ks, float x[8]){
    if (hvalid){
      float4 v0 = *(const float4*)(hbase + ks*32);
      float4 v1 = *(const float4*)(hbase + ks*32 + 4);
      x[0]=v0.x; x[1]=v0.y; x[2]=v0.z; x[3]=v0.w;
      x[4]=v1.x; x[5]=v1.y; x[6]=v1.z; x[7]=v1.w;
    } else {
      #pragma unroll
      for (int e=0;e<8;e++) x[e]=0.f;
    }
  };
  auto cvt_write = [&](const float x[8], int buf){
    uint hw[4], lw[4];
    #pragma unroll
    for (int e=0;e<4;e++){
      uint h0=hi16(x[2*e]), h1=hi16(x[2*e+1]);
      uint l0=hi16(x[2*e]-__uint_as_float(h0<<16));
      uint l1=hi16(x[2*e+1]-__uint_as_float(h1<<16));
      hw[e]=h0|(h1<<16); lw[e]=l0|(l1<<16);
    }
    *(uint4*)(sb + buf*10240 + a16w) = make_uint4(hw[0],hw[1],hw[2],hw[3]);
    *(uint4*)(sb + buf*10240 + 5120 + a16w) = make_uint4(lw[0],lw[1],lw[2],lw[3]);
  };

  { float x0[8]; load_h(0, x0); cvt_write(x0, 0); }
  for (int ks=0; ks<8; ks++){
    __syncthreads();
    float xn[8];
    if (ks < 7) load_h(ks+1, xn);
    const int cb = ks&1;
    U8 bh[4], bl[4];
    #pragma unroll
    for (int nt=0; nt<4; nt++){
      int a16 = (((nt*16+ln)*5 + lq)<<4);
      bh[nt].q = *(const uint4*)(sb + cb*10240 + a16);
      bl[nt].q = *(const uint4*)(sb + cb*10240 + 5120 + a16);
    }
    #pragma unroll
    for (int cp=0; cp<2; cp++){
      #pragma unroll
      for (int mf=0; mf<4; mf++){
        U8 ah, al;
        size_t ai = ((size_t)(ks*32 + cp*16 + w*4 + mf))*512 + lane*8;
        ah.q = *(const uint4*)(wh + ai);
        al.q = *(const uint4*)(wl + ai);
        #pragma unroll
        for (int nt=0; nt<4; nt++){
          acc[cp][mf][nt] = __builtin_amdgcn_mfma_f32_16x16x32_bf16(ah.v, bh[nt].v, acc[cp][mf][nt], 0,0,0);
          acc[cp][mf][nt] = __builtin_amdgcn_mfma_f32_16x16x32_bf16(ah.v, bl[nt].v, acc[cp][mf][nt], 0,0,0);
          acc[cp][mf][nt] = __builtin_amdgcn_mfma_f32_16x16x32_bf16(al.v, bh[nt].v, acc[cp][mf][nt], 0,0,0);
        }
      }
    }
    if (ks < 7) cvt_write(xn, cb^1);
  }
  // epilogue: rope + elu on kf (cp0), zero invalid columns
  #pragma unroll
  for (int mf=0; mf<4; mf++){
    #pragma unroll
    for (int nt=0; nt<4; nt++){
      int n = n0 + nt*16 + ln;
      int valid = (n < Nz);
      int nc = valid ? n : (Nz-1);
      int pi = mf*8 + lq*2;
      float2 c2 = *(const float2*)(cost + (size_t)nc*32 + pi);
      float2 s2 = *(const float2*)(sint + (size_t)nc*32 + pi);
      float q0 = acc[0][mf][nt][0], q1 = acc[0][mf][nt][1];
      float q2 = acc[0][mf][nt][2], q3 = acc[0][mf][nt][3];
      float r0 = elu1(q0*c2.x - q1*s2.x);
      float r1 = elu1(q0*s2.x + q1*c2.x);
      float r2 = elu1(q2*c2.y - q3*s2.y);
      float r3 = elu1(q2*s2.y + q3*c2.y);
      acc[0][mf][nt][0] = valid ? r0 : 0.f;
      acc[0][mf][nt][1] = valid ? r1 : 0.f;
      acc[0][mf][nt][2] = valid ? r2 : 0.f;
      acc[0][mf][nt][3] = valid ? r3 : 0.f;
    }
  }
  // phase B: kv accumulation per head (atomic path)
  const int d = t&63, q4 = t>>6;
  float* kfL = smem;          // [n(64)][68]
  float* vL  = smem + 4352;   // [n(64)][68]
  for (int g=0; g<4; g++){
    __syncthreads();
    if (w == g){
      #pragma unroll
      for (int mf=0; mf<4; mf++){
        #pragma unroll
        for (int nt=0; nt<4; nt++){
          int n = nt*16 + ln;
          int cc = mf*16 + lq*4;
          *(float4*)(kfL + n*68 + cc) = make_float4(acc[0][mf][nt][0],acc[0][mf][nt][1],acc[0][mf][nt][2],acc[0][mf][nt][3]);
          *(float4*)(vL  + n*68 + cc) = make_float4(acc[1][mf][nt][0],acc[1][mf][nt][1],acc[1][mf][nt][2],acc[1][mf][nt][3]);
        }
      }
    }
    __syncthreads();
    float4 kvacc[4];
    #pragma unroll
    for (int u=0;u<4;u++) kvacc[u]=f4z();
    float ksl = 0.f;
    for (int row=0; row<64; row++){
      float kd = kfL[row*68 + d];
      ksl += kd;
      const float4* vp = (const float4*)(vL + row*68);
      #pragma unroll
      for (int u=0;u<4;u++) fma4(kvacc[u], kd, vp[q4*4+u]);
    }
    float* kq = kvbuf + ((size_t)(b*Hz + g))*4160;
    #pragma unroll
    for (int u=0;u<4;u++){
      int e = q4*16 + 4*u;
      atomicAdd(&kq[(e+0)*64+d], kvacc[u].x);
      atomicAdd(&kq[(e+1)*64+d], kvacc[u].y);
      atomicAdd(&kq[(e+2)*64+d], kvacc[u].z);
      atomicAdd(&kq[(e+3)*64+d], kvacc[u].w);
    }
    if (q4==0) atomicAdd(&kq[4096+d], ksl);
  }
}

// P[b][h] = kv_h @ Wo_h  (64 x 256, K=64). grid: Bz*Hz blocks. f32 output.
__global__ __launch_bounds__(256) void k_pmat(const float* __restrict__ kvbuf,
    const float* __restrict__ Wo, float* __restrict__ pmat){
  __shared__ float smem[8448];
  const int t = threadIdx.x;
  const int bh = blockIdx.x;
  const int hh = bh & 3;
  const int c0 = t&15, rr = t>>4;
  const float* kvp = kvbuf + (size_t)bh*4160;
  for (int id=t; id<4096; id+=256){
    int e=id>>6, d=id&63;
    smem[e*68+d] = kvp[id];
  }
  float4 acc[4][4];
  #pragma unroll
  for (int i=0;i<4;i++){
    #pragma unroll
    for (int j=0;j<4;j++) acc[i][j]=f4z();
  }
  for (int kt=0; kt<64; kt+=16){
    __syncthreads();
    for (int id=t; id<1024; id+=256){
      int wr=id>>6, cf=id&63;
      ((float4*)(smem+4352))[wr*64+cf] = ((const float4*)(Wo + (size_t)(hh*64+kt+wr)*256))[cf];
    }
    __syncthreads();
    for (int kk=0; kk<16; kk++){
      float4 a4 = *(const float4*)(smem + (kt+kk)*68 + 4*rr);
      const float4* wrow = (const float4*)(smem+4352) + kk*64;
      float4 w0=wrow[c0], w1=wrow[c0+16], w2=wrow[c0+32], w3=wrow[c0+48];
      #pragma unroll
      for (int i=0;i<4;i++){
        float ac = fcomp(a4,i);
        fma4(acc[i][0],ac,w0); fma4(acc[i][1],ac,w1); fma4(acc[i][2],ac,w2); fma4(acc[i][3],ac,w3);
      }
    }
  }
  float* Pp = pmat + (size_t)bh*16384;
  #pragma unroll
  for (int i=0;i<4;i++){
    #pragma unroll
    for (int j=0;j<4;j++) ((float4*)Pp)[(4*rr+i)*64 + c0 + 16*j] = acc[i][j];
  }
}

// ---------------- MFMA k_att ----------------
#define AH_OFF 0
#define AL_OFF 16384
#define BH_OFF 32768
#define BL_OFF 37888
#define KS_OFF 43008
__global__ __launch_bounds__(256) void k_att(
    float* __restrict__ h,
    const u16* __restrict__ wqh, const u16* __restrict__ wql,
    const u16* __restrict__ pth, const u16* __restrict__ ptl,
    const float* __restrict__ kvbuf,
    const float* __restrict__ cost, const float* __restrict__ sint){
  __shared__ float smem[11008];
  char* sb = (char*)smem;
  const int t = threadIdx.x;
  const int b = blockIdx.y;
  const int n0 = blockIdx.x*64;
  const int w = t>>6;
  const int lane = t&63;
  const int ln = t&15;
  const int lq = (t>>4)&3;
  float* hb = h + (size_t)b*Nz*Dz;
  ((float*)(sb+KS_OFF))[t] = kvbuf[(size_t)(b*Hz + w)*4160 + 4096 + lane];
  floatx4 acc[4][4];
  #pragma unroll
  for (int i=0;i<4;i++)
    #pragma unroll
    for (int j=0;j<4;j++){ acc[i][j][0]=0.f; acc[i][j][1]=0.f; acc[i][j][2]=0.f; acc[i][j][3]=0.f; }

  for (int ks=0; ks<8; ks++){
    __syncthreads();
    const u16* sh = wqh + (size_t)ks*8192;
    const u16* sl = wql + (size_t)ks*8192;
    #pragma unroll
    for (int j=0;j<4;j++){
      int c = w*4 + j;
      gl16b(sh + c*512 + lane*8, sb + AH_OFF + c*1024);
      gl16b(sl + c*512 + lane*8, sb + AL_OFF + c*1024);
    }
    {
      int n = n0 + (t>>2);
      const float* hp = hb + (size_t)n*Dz + ks*32 + (t&3)*8;
      float x[8];
      if (n < Nz){
        float4 v0 = *(const float4*)(hp);
        float4 v1 = *(const float4*)(hp+4);
        x[0]=v0.x; x[1]=v0.y; x[2]=v0.z; x[3]=v0.w;
        x[4]=v1.x; x[5]=v1.y; x[6]=v1.z; x[7]=v1.w;
      } else {
        #pragma unroll
        for (int e=0;e<8;e++) x[e]=0.f;
      }
      uint hw[4], lw[4];
      #pragma unroll
      for (int e=0;e<4;e++){
        uint h0=hi16(x[2*e]), h1=hi16(x[2*e+1]);
        uint l0=hi16(x[2*e]-__uint_as_float(h0<<16));
        uint l1=hi16(x[2*e+1]-__uint_as_float(h1<<16));
        hw[e]=h0|(h1<<16); lw[e]=l0|(l1<<16);
      }
      int a16 = (((t>>2)*5 + (t&3))<<4);
      *(uint4*)(sb + BH_OFF + a16) = make_uint4(hw[0],hw[1],hw[2],hw[3]);
      *(uint4*)(sb + BL_OFF + a16) = make_uint4(lw[0],lw[1],lw[2],lw[3]);
    }
    __syncthreads();
    U8 bh[4], bl[4];
    #pragma unroll
    for (int nt=0; nt<4; nt++){
      int a16 = (((nt*16+ln)*5 + lq)<<4);
      bh[nt].q = *(const uint4*)(sb + BH_OFF + a16);
      bl[nt].q = *(const uint4*)(sb + BL_OFF + a16);
    }
    #pragma unroll
    for (int mf=0; mf<4; mf++){
      U8 ah, al;
      int a16 = (((w*4+mf)*64 + lane)<<4);
      ah.q = *(const uint4*)(sb + AH_OFF + a16);
      al.q = *(const uint4*)(sb + AL_OFF + a16);
      #pragma unroll
      for (int nt=0; nt<4; nt++){
        acc[mf][nt] = __builtin_amdgcn_mfma_f32_16x16x32_bf16(ah.v, bh[nt].v, acc[mf][nt], 0,0,0);
        acc[mf][nt] = __builtin_amdgcn_mfma_f32_16x16x32_bf16(ah.v, bl[nt].v, acc[mf][nt], 0,0,0);
        acc[mf][nt] = __builtin_amdgcn_mfma_f32_16x16x32_bf16(al.v, bh[nt].v, acc[mf][nt], 0,0,0);
      }
    }
  }
  uint2 qzh[4][4], qzl[4][4];
  {
    float4 ks4[4];
    #pragma unroll
    for (int mf=0; mf<4; mf++)
      ks4[mf] = *(const float4*)(sb + KS_OFF + ((w*64 + mf*16 + lq*4)<<2));
    float psum[4] = {0.f,0.f,0.f,0.f};
    #pragma unroll
    for (int mf=0; mf<4; mf++){
      #pragma unroll
      for (int nt=0; nt<4; nt++){
        int n = n0 + nt*16 + ln;
        int nc = (n < Nz) ? n : (Nz-1);
        int pi = mf*8 + lq*2;
        float2 c2 = *(const float2*)(cost + (size_t)nc*32 + pi);
        float2 s2 = *(const float2*)(sint + (size_t)nc*32 + pi);
        float q0 = acc[mf][nt][0], q1 = acc[mf][nt][1];
        float q2 = acc[mf][nt][2], q3 = acc[mf][nt][3];
        float r0 = elu1(q0*c2.x - q1*s2.x);
        float r1 = elu1(q0*s2.x + q1*c2.x);
        float r2 = elu1(q2*c2.y - q3*s2.y);
        float r3 = elu1(q2*s2.y + q3*c2.y);
        acc[mf][nt][0]=r0; acc[mf][nt][1]=r1; acc[mf][nt][2]=r2; acc[mf][nt][3]=r3;
        psum[nt] += r0*ks4[mf].x + r1*ks4[mf].y + r2*ks4[mf].z + r3*ks4[mf].w;
      }
    }
    float zt[4];
    #pragma unroll
    for (int nt=0; nt<4; nt++){
      float p = psum[nt];
      p += __shfl_xor(p, 16, 64);
      p += __shfl_xor(p, 32, 64);
      zt[nt] = 1.f/(p + 1e-6f);
    }
    #pragma unroll
    for (int mf=0; mf<4; mf++){
      #pragma unroll
      for (int nt=0; nt<4; nt++){
        float v0 = acc[mf][nt][0]*zt[nt];
        float v1 = acc[mf][nt][1]*zt[nt];
        float v2 = acc[mf][nt][2]*zt[nt];
        float v3 = acc[mf][nt][3]*zt[nt];
        uint h0=hi16(v0), h1=hi16(v1), h2=hi16(v2), h3=hi16(v3);
        qzh[mf][nt] = make_uint2(h0|(h1<<16), h2|(h3<<16));
        uint l0=hi16(v0-__uint_as_float(h0<<16));
        uint l1=hi16(v1-__uint_as_float(h1<<16));
        uint l2=hi16(v2-__uint_as_float(h2<<16));
        uint l3=hi16(v3-__uint_as_float(h3<<16));
        qzl[mf][nt] = make_uint2(l0|(l1<<16), l2|(l3<<16));
      }
    }
  }
  floatx4 acc2[4][4];
  #pragma unroll
  for (int i=0;i<4;i++)
    #pragma unroll
    for (int j=0;j<4;j++){ acc2[i][j][0]=0.f; acc2[i][j][1]=0.f; acc2[i][j][2]=0.f; acc2[i][j][3]=0.f; }
  for (int ks2=0; ks2<8; ks2++){
    __syncthreads();
    const u16* sh = pth + (size_t)(b*8 + ks2)*8192;
    const u16* sl = ptl + (size_t)(b*8 + ks2)*8192;
    #pragma unroll
    for (int j=0;j<4;j++){
      int c = w*4 + j;
      gl16b(sh + c*512 + lane*8, sb + AH_OFF + c*1024);
      gl16b(sl + c*512 + lane*8, sb + AL_OFF + c*1024);
    }
    if (w == (ks2>>1)){
      #pragma unroll
      for (int mm=0; mm<2; mm++){
        int mf = ((ks2&1)<<1) + mm;
        int g = (mm<<1) + (lq>>1);
        int sub = (lq&1)*8;
        #pragma unroll
        for (int nt=0; nt<4; nt++){
          int a16 = (((nt*16+ln)*5 + g)<<4) + sub;
          *(uint2*)(sb + BH_OFF + a16) = qzh[mf][nt];
          *(uint2*)(sb + BL_OFF + a16) = qzl[mf][nt];
        }
      }
    }
    __syncthreads();
    U8 bh[4], bl[4];
    #pragma unroll
    for (int nt=0; nt<4; nt++){
      int a16 = (((nt*16+ln)*5 + lq)<<4);
      bh[nt].q = *(const uint4*)(sb + BH_OFF + a16);
      bl[nt].q = *(const uint4*)(sb + BL_OFF + a16);
    }
    #pragma unroll
    for (int mf=0; mf<4; mf++){
      U8 ah, al;
      int a16 = (((w*4+mf)*64 + lane)<<4);
      ah.q = *(const uint4*)(sb + AH_OFF + a16);
      al.q = *(const uint4*)(sb + AL_OFF + a16);
      #pragma unroll
      for (int nt=0; nt<4; nt++){
        acc2[mf][nt] = __builtin_amdgcn_mfma_f32_16x16x32_bf16(ah.v, bh[nt].v, acc2[mf][nt], 0,0,0);
        acc2[mf][nt] = __builtin_amdgcn_mfma_f32_16x16x32_bf16(ah.v, bl[nt].v, acc2[mf][nt], 0,0,0);
        acc2[mf][nt] = __builtin_amdgcn_mfma_f32_16x16x32_bf16(al.v, bh[nt].v, acc2[mf][nt], 0,0,0);
      }
    }
  }
  #pragma unroll
  for (int mf=0; mf<4; mf++){
    #pragma unroll
    for (int nt=0; nt<4; nt++){
      int n = n0 + nt*16 + ln;
      if (n < Nz){
        float* hp = hb + (size_t)n*Dz + w*64 + mf*16 + lq*4;
        float4 hv = *(const float4*)hp;
        hv.x += acc2[mf][nt][0];
        hv.y += acc2[mf][nt][1];
        hv.z += acc2[mf][nt][2];
        hv.w += acc2[mf][nt][3];
        *(float4*)hp = hv;
      }
    }
  }
}

__global__ __launch_bounds__(256) void k_wkv(const float* __restrict__ h,
    const float* __restrict__ Wwk, const float* __restrict__ Wwv,
    float* __restrict__ wkbuf, float* __restrict__ wvbuf){
  __shared__ float wtL[16*257];
  int t = threadIdx.x;
  int b = blockIdx.y, m0 = blockIdx.x*16;
  const float* hb = h + ((size_t)b*Nz + (Nz-64))*Dz;
  for (int i=t;i<16*Dz;i+=256){ int r=i>>8,c=i&255; wtL[r*257+c] = hb[(size_t)(m0+r)*Dz + c]; }
  __syncthreads();
  int r=t>>4, c0=t&15;
  float4 ak0=f4z(),ak1=f4z(),av0=f4z(),av1=f4z();
  for (int kk=0;kk<Dz;kk++){
    float hv = wtL[r*257+kk];
    const float4* wk4 = (const float4*)(Wwk + (size_t)kk*DCz);
    const float4* wv4 = (const float4*)(Wwv + (size_t)kk*DCz);
    fma4(ak0,hv,wk4[c0]); fma4(ak1,hv,wk4[c0+16]);
    fma4(av0,hv,wv4[c0]); fma4(av1,hv,wv4[c0+16]);
  }
  float4* ok = (float4*)(wkbuf + (size_t)(b*64 + m0+r)*DCz);
  float4* ov = (float4*)(wvbuf + (size_t)(b*64 + m0+r)*DCz);
  ok[c0]=ak0; ok[c0+16]=ak1; ov[c0]=av0; ov[c0+16]=av1;
}

__global__ __launch_bounds__(256) void k_cache_upd(float* __restrict__ cache,
    const float* __restrict__ wkbuf, const float* __restrict__ wvbuf,
    const float* __restrict__ Wwg, const float* __restrict__ bwg,
    int s0, int it, int pas){
  __shared__ float sqL[16*132];
  __shared__ float wkL[64*132];
  __shared__ float wat[16*68];
  __shared__ float ncL[16*132];
  __shared__ float wg[16];
  int t = threadIdx.x; int b = blockIdx.x;
  for (int i=t;i<16*DCz;i+=256){ int k2=i>>7,c=i&127; sqL[k2*132+c] = cache[((size_t)(b*NSLOTz)+s0+k2)*DSLOTz + c]; }
  for (int i=t;i<64*DCz;i+=256){ int m=i>>7,c=i&127; wkL[m*132+c] = wkbuf[(size_t)(b*64+m)*DCz+c]; }
  __syncthreads();
  {
    int k2 = t>>4;
    const float4* s4 = (const float4*)(sqL) + k2*33;
    for (int mm=0;mm<4;mm++){
      int m = (t&15) + 16*mm;
      const float4* k4 = (const float4*)(wkL) + m*33;
      float a=0.f;
      for (int d4=0;d4<32;d4++) a += dot4(s4[d4], k4[d4]);
      wat[k2*68+m] = a * 0.088388347648318447f;
    }
  }
  __syncthreads();
  if (t<16){
    float mx=-1e30f;
    for (int m=0;m<64;m++) mx = fmaxf(mx, wat[t*68+m]);
    float su=0.f;
    for (int m=0;m<64;m++){ float e=__expf(wat[t*68+m]-mx); wat[t*68+m]=e; su+=e; }
    float inv=1.f/su;
    for (int m=0;m<64;m++) wat[t*68+m]*=inv;
  }
  __syncthreads();
  {
    int k2=t>>4, c0=t&15;
    float4 a0=f4z(), a1=f4z();
    const float4* wvg = (const float4*)(wvbuf + (size_t)b*64*DCz);
    for (int m=0;m<64;m++){
      float a = wat[k2*68+m];
      fma4(a0,a,wvg[m*32+c0]); fma4(a1,a,wvg[m*32+c0+16]);
    }
    ((float4*)ncL)[k2*33+c0]=a0; ((float4*)ncL)[k2*33+16+c0]=a1;
  }
  __syncthreads();
  if (t<16){
    float a = bwg[0];
    for (int d2=0; d2<DCz; d2++) a += sqL[t*132+d2]*Wwg[d2] + ncL[t*132+d2]*Wwg[DCz+d2];
    wg[t] = sigm(a);
  }
  __syncthreads();
  for (int i=t;i<16*DCz;i+=256){
    int k2=i>>7,c=i&127;
    cache[((size_t)(b*NSLOTz)+s0+k2)*DSLOTz + c] = sqL[k2*132+c] + wg[k2]*ncL[k2*132+c];
  }
  if (t<16){
    float* cp = cache + ((size_t)(b*NSLOTz)+s0+t)*DSLOTz;
    cp[128] = wg[t];
    cp[137] = (it==0)?1.f:0.f; cp[138] = (it==1)?1.f:0.f; cp[139]=0.f; cp[140]=0.f;
    cp[141] = (pas==0)?1.f:0.f; cp[142] = (pas==1)?1.f:0.f; cp[143]=0.f; cp[144]=0.f;
  }
}

__global__ __launch_bounds__(256) void k_logits(const float* __restrict__ h,
    const float* __restrict__ Wout, const float* __restrict__ bout, float* __restrict__ out){
  __shared__ float hl[16*257];
  int t = threadIdx.x; int row0 = blockIdx.x*16;
  for (int i=t;i<16*Dz;i+=256){
    int rr=i>>8,c=i&255; int row=row0+rr; int b=row/Sz, s=row-b*Sz;
    hl[rr*257+c] = h[((size_t)b*Nz + TSz + s)*Dz + c];
  }
  __syncthreads();
  int rr = t>>4, v = t&15;
  float a = bout[v];
  for (int c=0;c<Dz;c++) a += hl[rr*257+c]*Wout[c*Vz + v];
  out[(size_t)(row0+rr)*Vz + v] = a;
}

__global__ __launch_bounds__(256) void k_feedback(float* __restrict__ h,
    const float* __restrict__ logits0, const float* __restrict__ pae,
    const float* __restrict__ Wfb, const float* __restrict__ bfb){
  __shared__ float trL[16*257];
  __shared__ float paeL[16*257];
  __shared__ int amL[16];
  int t = threadIdx.x; int b = blockIdx.y; int s0 = blockIdx.x*16;
  if (t<16){
    int s = s0+t; int am=0;
    if (s < Sz){
      const float* lg = logits0 + (size_t)(b*Sz+s)*Vz;
      float best = lg[0];
      for (int v=1;v<16;v++){ if (lg[v] > best){ best=lg[v]; am=v; } }
    }
    amL[t]=am;
  }
  for (int i=t;i<16*Dz;i+=256){
    int rr=i>>8,c=i&255; int s=s0+rr;
    trL[rr*257+c] = (s<Sz)? h[((size_t)b*Nz + TSz + s)*Dz + c] : 0.f;
  }
  __syncthreads();
  for (int i=t;i<16*Dz;i+=256){ int rr=i>>8,c=i&255; paeL[rr*257+c] = pae[(size_t)amL[rr]*Dz + c]; }
  __syncthreads();
  int r=t>>4, c0=t&15;
  float4 acc[4]; acc[0]=f4z(); acc[1]=f4z(); acc[2]=f4z(); acc[3]=f4z();
  for (int kk=0;kk<Dz;kk++){
    float xv = trL[r*257+kk];
    const float4* wr = (const float4*)(Wfb + (size_t)kk*Dz);
    fma4(acc[0],xv,wr[c0]); fma4(acc[1],xv,wr[c0+16]); fma4(acc[2],xv,wr[c0+32]); fma4(acc[3],xv,wr[c0+48]);
  }
  for (int kk=0;kk<Dz;kk++){
    float xv = paeL[r*257+kk];
    const float4* wr = (const float4*)(Wfb + (size_t)(Dz+kk)*Dz);
    fma4(acc[0],xv,wr[c0]); fma4(acc[1],xv,wr[c0+16]); fma4(acc[2],xv,wr[c0+32]); fma4(acc[3],xv,wr[c0+48]);
  }
  int s = s0+r;
  if (s < Sz){
    float* cp = h + ((size_t)b*Nz + TSz + s)*Dz;
    #pragma unroll
    for (int j=0;j<4;j++){
      float vals[4] = {acc[j].x, acc[j].y, acc[j].z, acc[j].w};
      #pragma unroll
      for (int q2=0;q2<4;q2++){
        int c = (c0+16*j)*4 + q2;
        float g = sigm(vals[q2] + bfb[c]);
        cp[c] = trL[r*257+c] + g*paeL[r*257+c];
      }
    }
  }
}

extern "C" void kernel_launch(void* const* d_in, const int* in_sizes, int n_in,
                              void* d_out, int out_size, void* d_ws, size_t ws_size,
                              hipStream_t stream){
  (void)in_sizes; (void)n_in;
  const int*   demo_in   = (const int*)d_in[0];
  const int*   demo_out  = (const int*)d_in[1];
  const int*   test_in   = (const int*)d_in[2];
  const float* token_emb = (const float*)d_in[3];
  const float* seg_emb   = (const float*)d_in[4];
  const float* slot_emb  = (const float*)d_in[5];
  const float* lid_emb   = (const float*)d_in[6];
  const float* Wq_read   = (const float*)d_in[7];
  const float* Wk_read   = (const float*)d_in[8];
  const float* Wv_read   = (const float*)d_in[9];
  const float* Wg_read   = (const float*)d_in[10];
  const float* bg_read   = (const float*)d_in[11];
  const float* Wqkv      = (const float*)d_in[12];
  const float* Wo        = (const float*)d_in[13];
  const float* Wwk       = (const float*)d_in[14];
  const float* Wwv       = (const float*)d_in[15];
  const float* Wwg       = (const float*)d_in[16];
  const float* bwg       = (const float*)d_in[17];
  const float* Wout      = (const float*)d_in[18];
  const float* bout      = (const float*)d_in[19];
  const float* pae       = (const float*)d_in[20];
  const float* Wfb       = (const float*)d_in[21];
  const float* bfb       = (const float*)d_in[22];

  char* wsb = (char*)d_ws;
  size_t off = 0;
  auto alloc = [&](size_t bytes)->char*{
    char* p = wsb + off;
    off += (bytes + 255) & ~(size_t)255;
    return p;
  };
  float* hbuf   = (float*)alloc((size_t)Bz*Nz*Dz*4);
  float* cache  = (float*)alloc((size_t)Bz*NSLOTz*DSLOTz*4);
  float* kvbuf  = (float*)alloc((size_t)Bz*Hz*4160*4);
  float* pmat   = (float*)alloc((size_t)Bz*Hz*64*256*4);
  float* wkbuf  = (float*)alloc((size_t)Bz*64*DCz*4);
  float* wvbuf  = (float*)alloc((size_t)Bz*64*DCz*4);
  float* logits0= (float*)alloc((size_t)Bz*Sz*Vz*4);
  float* cost   = (float*)alloc((size_t)Nz*32*4);
  float* sint   = (float*)alloc((size_t)Nz*32*4);
  u16*   wqth   = (u16*)alloc((size_t)3*65536*2);
  u16*   wqtl   = (u16*)alloc((size_t)3*65536*2);
  u16*   pth    = (u16*)alloc((size_t)16*65536*2);
  u16*   ptl    = (u16*)alloc((size_t)16*65536*2);
  u16*   wkvh   = (u16*)alloc((size_t)3*131072*2);
  u16*   wkvl   = (u16*)alloc((size_t)3*131072*2);
  u16*   wqrh   = (u16*)alloc((size_t)3*32768*2);
  u16*   wqrl   = (u16*)alloc((size_t)3*32768*2);
  u16*   krh    = (u16*)alloc((size_t)Bz*6144*2);
  u16*   krl    = (u16*)alloc((size_t)Bz*6144*2);
  u16*   vrh    = (u16*)alloc((size_t)Bz*16384*2);
  u16*   vrl    = (u16*)alloc((size_t)Bz*16384*2);

  if (off > ws_size){
    k_sentinel<<<(out_size+255)/256, 256, 0, stream>>>((float*)d_out, out_size);
    return;
  }

  k_rope<<<(Nz*32+255)/256, 256, 0, stream>>>(cost, sint);
  k_cache_init<<<(Bz*NSLOTz*DSLOTz+255)/256, 256, 0, stream>>>(slot_emb, lid_emb, cache);
  k_pack_w<<<768, 256, 0, stream>>>(Wqkv, wqth, wqtl);
  k_pack_wkv<<<1536, 256, 0, stream>>>(Wqkv, wkvh, wkvl);
  k_pack_wr<<<384, 256, 0, stream>>>(Wq_read, wqrh, wqrl);
  // zero vreadp once: pad rows s=48..63 must be 0 bf16 forever
  k_zero<<<512, 256, 0, stream>>>((float*)vrh, Bz*16384/2);
  k_zero<<<512, 256, 0, stream>>>((float*)vrl, Bz*16384/2);

  for (int pas=0; pas<2; pas++){
    k_embed<<<(Bz*Nz*64+255)/256, 256, 0, stream>>>(demo_in, demo_out, test_in, token_emb, seg_emb, hbuf);
    if (pas==1)
      k_feedback<<<dim3(57,Bz), 256, 0, stream>>>(hbuf, logits0, pae, Wfb, bfb);
    for (int l=0; l<3; l++){
      for (int it=0; it<2; it++){
        k_proj_cache<<<Bz*NSLOTz, 384, 0, stream>>>(cache,
            Wk_read + (size_t)l*DSLOTz*DCz, Wv_read + (size_t)l*DSLOTz*Dz,
            krh, krl, vrh, vrl);
        k_read_attn<<<dim3(GXA,Bz), 256, 0, stream>>>(hbuf,
            wqrh + (size_t)l*32768, wqrl + (size_t)l*32768,
            krh, krl, vrh, vrl,
            Wg_read + (size_t)l*Dz, bg_read + l, kvbuf);
        k_kv<<<dim3(GXA,Bz), 256, 0, stream>>>(hbuf,
            wkvh + (size_t)l*131072, wkvl + (size_t)l*131072, cost, sint, kvbuf);
        k_pmat<<<Bz*Hz, 256, 0, stream>>>(kvbuf, Wo + (size_t)l*Dz*Dz, pmat);
        k_pack_p<<<4096, 256, 0, stream>>>(pmat, pth, ptl);
        k_att<<<dim3(GXA,Bz), 256, 0, stream>>>(hbuf,
            wqth + (size_t)l*65536, wqtl + (size_t)l*65536, pth, ptl,
            kvbuf, cost, sint);
        k_wkv<<<dim3(4,Bz), 256, 0, stream>>>(hbuf,
            Wwk + (size_t)l*Dz*DCz, Wwv + (size_t)l*Dz*DCz, wkbuf, wvbuf);
        k_cache_upd<<<Bz, 256, 0, stream>>>(cache, wkbuf, wvbuf,
            Wwg + (size_t)l*2*DCz, bwg + l, l*16, it, pas);
      }
    }
    float* outp = (pas==0) ? logits0 : (float*)d_out;
    k_logits<<<900, 256, 0, stream>>>(hbuf, Wout, bout, outp);
  }
}

// Round 10
// 7901.509 us; speedup vs baseline: 1.0947x; 1.0332x over previous
//
#include <hip/hip_runtime.h>
#include <math.h>

#define Bz 16
#define Sz 900
#define Vz 16
#define Dz 256
#define DCz 128
#define Hz 4
#define Nz 6300
#define TSz 5400
#define DSLOTz 145
#define NSLOTz 48
#define GXA 99    // ceil(6300/64) row-blocks

typedef unsigned short u16;
typedef unsigned int u32;

typedef __bf16 bf16x8 __attribute__((ext_vector_type(8)));
typedef float floatx4 __attribute__((ext_vector_type(4)));
union U8 { bf16x8 v; uint4 q; };

static __device__ __forceinline__ float sigm(float x){ return 1.0f/(1.0f+__expf(-x)); }
static __device__ __forceinline__ void fma4(float4& a, float s, float4 b){ a.x+=s*b.x; a.y+=s*b.y; a.z+=s*b.z; a.w+=s*b.w; }
static __device__ __forceinline__ float dot4(float4 a, float4 b){ return a.x*b.x + a.y*b.y + a.z*b.z + a.w*b.w; }
static __device__ __forceinline__ float4 f4z(){ float4 z; z.x=0.f; z.y=0.f; z.z=0.f; z.w=0.f; return z; }
static __device__ __forceinline__ float elu1(float x){ return x>0.f ? x+1.f : __expf(x); }
static __device__ __forceinline__ float fcomp(float4 v, int i){ return (i==0)?v.x:(i==1)?v.y:(i==2)?v.z:v.w; }

// round-to-nearest-even bf16 (top 16 bits) of f32
static __device__ __forceinline__ uint hi16(float x){
  uint u = __float_as_uint(x);
  return (u + 0x7fffu + ((u>>16)&1u)) >> 16;
}

typedef const void GV __attribute__((address_space(1)));
typedef void LV __attribute__((address_space(3)));
static __device__ __forceinline__ void gl16(const float* g, float* l){
  __builtin_amdgcn_global_load_lds((GV*)g, (LV*)l, 16, 0, 0);
}
static __device__ __forceinline__ void gl16b(const void* g, void* l){
  __builtin_amdgcn_global_load_lds((GV*)g, (LV*)l, 16, 0, 0);
}

__global__ void k_sentinel(float* out, int nelem){
  int i = blockIdx.x*256 + threadIdx.x;
  if (i < nelem) out[i] = 12345.0f;
}

__global__ void k_zero(float* p, int n){
  int i = blockIdx.x*256 + threadIdx.x;
  if (i < n) p[i] = 0.f;
}

__global__ void k_rope(float* cost, float* sint){
  int i = blockIdx.x*256 + threadIdx.x;
  if (i >= Nz*32) return;
  int n = i>>5, f = i&31;
  double invd = pow(10000.0, -(double)f/32.0);
  double fr = (double)n * invd;
  cost[i] = (float)cos(fr);
  sint[i] = (float)sin(fr);
}

__global__ void k_embed(const int* __restrict__ di, const int* __restrict__ dq,
                        const int* __restrict__ ti, const float* __restrict__ temb,
                        const float* __restrict__ semb, float* __restrict__ h){
  int i = blockIdx.x*256 + threadIdx.x;   // over B*N*64 float4s
  if (i >= Bz*Nz*64) return;
  int dv = i & 63; int bn = i >> 6; int n = bn % Nz; int b = bn / Nz;
  int tok;
  if (n < TSz){
    int nd = n/1800; int r = n - nd*1800;
    tok = (r < Sz) ? di[(b*3+nd)*Sz + r] : dq[(b*3+nd)*Sz + (r-Sz)];
  } else {
    tok = ti[b*Sz + (n-TSz)];
  }
  const float4* e4 = (const float4*)(temb + (size_t)tok*Dz);
  const float4* s4 = (const float4*)semb;
  float4 v = e4[dv]; float4 s = s4[dv];
  v.x += s.x; v.y += s.y; v.z += s.z; v.w += s.w;
  ((float4*)h)[(size_t)bn*64 + dv] = v;
}

__global__ void k_cache_init(const float* __restrict__ slot_emb, const float* __restrict__ lid,
                             float* __restrict__ cache){
  int i = blockIdx.x*256 + threadIdx.x;
  if (i >= Bz*NSLOTz*DSLOTz) return;
  int c = i % DSLOTz; int sc = (i / DSLOTz) % NSLOTz; int l = sc >> 4;
  float v = 0.f;
  if (c < DCz) v = slot_emb[sc*DCz + c];
  else if (c >= 129 && c < 137) v = lid[l*8 + (c-129)];
  cache[i] = v;
}

// pack Wq^T (cols 0..256 of Wqkv) into MFMA A-fragment order, bf16 hi/lo.
__global__ void k_pack_w(const float* __restrict__ Wqkv,
                         u16* __restrict__ wh, u16* __restrict__ wl){
  int i = blockIdx.x*256 + threadIdx.x;
  if (i >= 3*65536) return;
  int l = i >> 16; int r = i & 65535;
  int ks = r >> 13; int ct = (r>>9)&15; int lane = (r>>3)&63; int e = r&7;
  int k = ks*32 + ((lane>>4)<<3) + e;
  int c = ct*16 + (lane&15);
  float x = Wqkv[(size_t)l*196608 + (size_t)k*768 + c];
  uint hb = hi16(x);
  uint lb = hi16(x - __uint_as_float(hb<<16));
  wh[i] = (u16)hb; wl[i] = (u16)lb;
}

// pack Wkv^T (cols 256..768 of Wqkv) into MFMA A-fragment order, bf16 hi/lo.
__global__ void k_pack_wkv(const float* __restrict__ Wqkv,
                           u16* __restrict__ wh, u16* __restrict__ wl){
  int i = blockIdx.x*256 + threadIdx.x;
  if (i >= 3*131072) return;
  int l = i / 131072; int r = i % 131072;
  int ks = r >> 14; int ct = (r>>9)&31; int lane = (r>>3)&63; int e = r&7;
  int k = ks*32 + ((lane>>4)<<3) + e;
  int c = ct*16 + (lane&15);
  float x = Wqkv[(size_t)l*196608 + (size_t)k*768 + 256 + c];
  uint hb = hi16(x);
  uint lb = hi16(x - __uint_as_float(hb<<16));
  wh[i] = (u16)hb; wl[i] = (u16)lb;
}

// pack Wq_read^T into MFMA A-fragment order, bf16 hi/lo.
__global__ void k_pack_wr(const float* __restrict__ Wqr,
                          u16* __restrict__ wh, u16* __restrict__ wl){
  int i = blockIdx.x*256 + threadIdx.x;
  if (i >= 3*32768) return;
  int l = i >> 15; int r = i & 32767;
  int ks = r >> 12; int ct = (r>>9)&7; int lane = (r>>3)&63; int e = r&7;
  int k = ks*32 + ((lane>>4)<<3) + e;
  int c = ct*16 + (lane&15);
  float x = Wqr[(size_t)l*32768 + (size_t)k*DCz + c];
  uint hb = hi16(x);
  uint lb = hi16(x - __uint_as_float(hb<<16));
  wh[i] = (u16)hb; wl[i] = (u16)lb;
}

// pack Pcat^T into MFMA A-fragment order, bf16 hi/lo (coalesced reads+writes).
__global__ void k_pack_p(const float* __restrict__ pmat,
                         u16* __restrict__ ph, u16* __restrict__ pl){
  int i = blockIdx.x*256 + threadIdx.x;
  if (i >= 16*65536) return;
  int b = i >> 16; int r = i & 65535;
  int ks2 = r >> 13; int ct = (r>>9)&15; int lane = (r>>3)&63; int e = r&7;
  int c = ks2*32 + ((lane>>4)<<3) + e;
  int oc = ct*16 + (lane&15);
  float x = pmat[(((size_t)(b*4 + (c>>6)))*64 + (c&63))*256 + oc];
  uint hb = hi16(x);
  uint lb = hi16(x - __uint_as_float(hb<<16));
  ph[i] = (u16)hb; pl[i] = (u16)lb;
}

// cache->kread/vread projections, emitted directly in bf16 hi/lo MFMA A-frag order.
__global__ __launch_bounds__(384) void k_proj_cache(const float* __restrict__ cache,
    const float* __restrict__ Wk, const float* __restrict__ Wv,
    u16* __restrict__ krh, u16* __restrict__ krl,
    u16* __restrict__ vrh, u16* __restrict__ vrl){
  __shared__ float crow[DSLOTz];
  int b = blockIdx.x / NSLOTz, sc = blockIdx.x % NSLOTz;
  int t = threadIdx.x;
  const float* cp = cache + (size_t)(b*NSLOTz+sc)*DSLOTz;
  if (t < DSLOTz) crow[t] = cp[t];
  __syncthreads();
  if (t < DCz){
    float a = 0.f;
    for (int r2=0;r2<DSLOTz;r2++) a += crow[r2]*Wk[r2*DCz + t];
    uint hb = hi16(a);
    uint lb = hi16(a - __uint_as_float(hb<<16));
    int ks = t>>5, st = sc>>4, lane = (sc&15) | (((t>>3)&3)<<4), e = t&7;
    size_t idx = (size_t)b*6144 + (size_t)(((ks*3+st)*64 + lane)*8 + e);
    krh[idx] = (u16)hb; krl[idx] = (u16)lb;
  } else {
    int d = t - DCz;
    float a = 0.f;
    for (int r2=0;r2<DSLOTz;r2++) a += crow[r2]*Wv[r2*Dz + d];
    uint hb = hi16(a);
    uint lb = hi16(a - __uint_as_float(hb<<16));
    int ot = d>>4, ks2 = sc>>5, lane = (d&15) | (((sc>>3)&3)<<4), e = sc&7;
    size_t idx = (size_t)b*16384 + (size_t)(((ks2*16+ot)*64 + lane)*8 + e);
    vrh[idx] = (u16)hb; vrl[idx] = (u16)lb;
  }
}

// ---------------- MFMA k_read_attn (also zeroes kvbuf for this iteration) ------
#define RA2_BH 0
#define RA2_BL 5120
#define RA2_QBH 10240
#define RA2_QBL 30720
#define RA2_ABH 10240
#define RA2_ABL 20480
#define RA2_G  51200
#define RA2_WG 51456
__global__ __launch_bounds__(256) void k_read_attn(
    float* __restrict__ h,
    const u16* __restrict__ wqh, const u16* __restrict__ wql,
    const u16* __restrict__ krh, const u16* __restrict__ krl,
    const u16* __restrict__ vrh, const u16* __restrict__ vrl,
    const float* __restrict__ Wg, const float* __restrict__ bg,
    float* __restrict__ kvbuf){
  __shared__ float smem[13120];
  char* sb = (char*)smem;
  const int t = threadIdx.x;
  const int b = blockIdx.y;
  const int n0 = blockIdx.x*64;
  const int w = t>>6, lane = t&63, ln = t&15, lq = (t>>4)&3;
  float* hb = h + (size_t)b*Nz*Dz;
  { // fold: zero kvbuf (stream order: previous k_att was the last reader)
    int gid = (b*GXA + blockIdx.x)*256 + t;
    if (gid < Bz*Hz*4160) kvbuf[gid] = 0.f;
  }
  ((float*)(sb+RA2_WG))[t] = Wg[t];
  floatx4 acc[2][4];
  #pragma unroll
  for (int i=0;i<2;i++)
    #pragma unroll
    for (int j=0;j<4;j++){ acc[i][j][0]=0.f; acc[i][j][1]=0.f; acc[i][j][2]=0.f; acc[i][j][3]=0.f; }
  for (int ks=0; ks<8; ks++){
    __syncthreads();
    {
      int n = n0 + (t>>2);
      const float* hp = hb + (size_t)n*Dz + ks*32 + (t&3)*8;
      float x[8];
      if (n < Nz){
        float4 v0 = *(const float4*)(hp);
        float4 v1 = *(const float4*)(hp+4);
        x[0]=v0.x; x[1]=v0.y; x[2]=v0.z; x[3]=v0.w;
        x[4]=v1.x; x[5]=v1.y; x[6]=v1.z; x[7]=v1.w;
      } else {
        #pragma unroll
        for (int e=0;e<8;e++) x[e]=0.f;
      }
      uint hw[4], lw[4];
      #pragma unroll
      for (int e=0;e<4;e++){
        uint h0=hi16(x[2*e]), h1=hi16(x[2*e+1]);
        uint l0=hi16(x[2*e]-__uint_as_float(h0<<16));
        uint l1=hi16(x[2*e+1]-__uint_as_float(h1<<16));
        hw[e]=h0|(h1<<16); lw[e]=l0|(l1<<16);
      }
      int a16 = (((t>>2)*5 + (t&3))<<4);
      *(uint4*)(sb + RA2_BH + a16) = make_uint4(hw[0],hw[1],hw[2],hw[3]);
      *(uint4*)(sb + RA2_BL + a16) = make_uint4(lw[0],lw[1],lw[2],lw[3]);
    }
    __syncthreads();
    U8 bh[4], bl[4];
    #pragma unroll
    for (int nt=0; nt<4; nt++){
      int a16 = (((nt*16+ln)*5 + lq)<<4);
      bh[nt].q = *(const uint4*)(sb + RA2_BH + a16);
      bl[nt].q = *(const uint4*)(sb + RA2_BL + a16);
    }
    #pragma unroll
    for (int mf=0; mf<2; mf++){
      U8 ah, al;
      size_t ai = ((size_t)(ks*8 + w*2 + mf))*512 + lane*8;
      ah.q = *(const uint4*)(wqh + ai);
      al.q = *(const uint4*)(wql + ai);
      #pragma unroll
      for (int nt=0; nt<4; nt++){
        acc[mf][nt] = __builtin_amdgcn_mfma_f32_16x16x32_bf16(ah.v, bh[nt].v, acc[mf][nt], 0,0,0);
        acc[mf][nt] = __builtin_amdgcn_mfma_f32_16x16x32_bf16(ah.v, bl[nt].v, acc[mf][nt], 0,0,0);
        acc[mf][nt] = __builtin_amdgcn_mfma_f32_16x16x32_bf16(al.v, bh[nt].v, acc[mf][nt], 0,0,0);
      }
    }
  }
  {
    int n = t>>2, kq = t&3;
    int nn = n0+n; int nc = (nn < Nz) ? nn : (Nz-1);
    const float* hp = hb + (size_t)nc*Dz + kq*64;
    const float* wgp = (const float*)(sb+RA2_WG) + kq*64;
    float a = 0.f;
    for (int k=0;k<64;k+=4){
      float4 hv = *(const float4*)(hp+k);
      float4 wv = *(const float4*)(wgp+k);
      a += dot4(hv,wv);
    }
    a += __shfl_xor(a,1,64);
    a += __shfl_xor(a,2,64);
    if (kq==0) ((float*)(sb+RA2_G))[n] = a;
  }
  {
    #pragma unroll
    for (int mf=0; mf<2; mf++){
      #pragma unroll
      for (int nt=0; nt<4; nt++){
        float v0 = acc[mf][nt][0], v1 = acc[mf][nt][1];
        float v2 = acc[mf][nt][2], v3 = acc[mf][nt][3];
        uint h0=hi16(v0), h1=hi16(v1), h2=hi16(v2), h3=hi16(v3);
        uint l0=hi16(v0-__uint_as_float(h0<<16));
        uint l1=hi16(v1-__uint_as_float(h1<<16));
        uint l2=hi16(v2-__uint_as_float(h2<<16));
        uint l3=hi16(v3-__uint_as_float(h3<<16));
        int a16 = (((nt*16+ln)*5 + (mf*2 + (lq>>1)))<<4) + ((lq&1)<<3);
        *(uint2*)(sb + RA2_QBH + w*5120 + a16) = make_uint2(h0|(h1<<16), h2|(h3<<16));
        *(uint2*)(sb + RA2_QBL + w*5120 + a16) = make_uint2(l0|(l1<<16), l2|(l3<<16));
      }
    }
  }
  __syncthreads();
  floatx4 sacc[3];
  #pragma unroll
  for (int st=0; st<3; st++){ sacc[st][0]=0.f; sacc[st][1]=0.f; sacc[st][2]=0.f; sacc[st][3]=0.f; }
  for (int ks=0; ks<4; ks++){
    U8 bh, bl;
    int a16 = (((w*16+ln)*5 + lq)<<4);
    bh.q = *(const uint4*)(sb + RA2_QBH + ks*5120 + a16);
    bl.q = *(const uint4*)(sb + RA2_QBL + ks*5120 + a16);
    #pragma unroll
    for (int st=0; st<3; st++){
      U8 ah, al;
      size_t ai = (size_t)b*6144 + ((size_t)(ks*3+st))*512 + lane*8;
      ah.q = *(const uint4*)(krh + ai);
      al.q = *(const uint4*)(krl + ai);
      sacc[st] = __builtin_amdgcn_mfma_f32_16x16x32_bf16(ah.v, bh.v, sacc[st], 0,0,0);
      sacc[st] = __builtin_amdgcn_mfma_f32_16x16x32_bf16(ah.v, bl.v, sacc[st], 0,0,0);
      sacc[st] = __builtin_amdgcn_mfma_f32_16x16x32_bf16(al.v, bh.v, sacc[st], 0,0,0);
    }
  }
  {
    const float scl = 0.088388347648318447f;
    float mx = -1e30f;
    #pragma unroll
    for (int st=0; st<3; st++)
      #pragma unroll
      for (int r=0;r<4;r++){ sacc[st][r] *= scl; mx = fmaxf(mx, sacc[st][r]); }
    mx = fmaxf(mx, __shfl_xor(mx, 16, 64));
    mx = fmaxf(mx, __shfl_xor(mx, 32, 64));
    float su = 0.f;
    #pragma unroll
    for (int st=0; st<3; st++)
      #pragma unroll
      for (int r=0;r<4;r++){ float e = __expf(sacc[st][r]-mx); sacc[st][r]=e; su+=e; }
    su += __shfl_xor(su, 16, 64);
    su += __shfl_xor(su, 32, 64);
    float inv = 1.f/su;
    #pragma unroll
    for (int st=0; st<3; st++)
      #pragma unroll
      for (int r=0;r<4;r++) sacc[st][r] *= inv;
  }
  __syncthreads();
  {
    uint2 ah2[3], al2[3];
    #pragma unroll
    for (int st=0; st<3; st++){
      float v0=sacc[st][0], v1=sacc[st][1], v2=sacc[st][2], v3=sacc[st][3];
      uint h0=hi16(v0), h1=hi16(v1), h2=hi16(v2), h3=hi16(v3);
      uint l0=hi16(v0-__uint_as_float(h0<<16));
      uint l1=hi16(v1-__uint_as_float(h1<<16));
      uint l2=hi16(v2-__uint_as_float(h2<<16));
      uint l3=hi16(v3-__uint_as_float(h3<<16));
      ah2[st] = make_uint2(h0|(h1<<16), h2|(h3<<16));
      al2[st] = make_uint2(l0|(l1<<16), l2|(l3<<16));
    }
    int rb = (w*16+ln)*5;
    int sub = (lq&1)<<3;
    #pragma unroll
    for (int st=0; st<2; st++){
      int a16 = ((rb + st*2 + (lq>>1))<<4) + sub;
      *(uint2*)(sb + RA2_ABH + a16) = ah2[st];
      *(uint2*)(sb + RA2_ABL + a16) = al2[st];
    }
    {
      int a16 = ((rb + (lq>>1))<<4) + sub;
      *(uint2*)(sb + RA2_ABH + 5120 + a16) = ah2[2];
      *(uint2*)(sb + RA2_ABL + 5120 + a16) = al2[2];
      int z16 = ((rb + 2 + (lq>>1))<<4) + sub;
      *(uint2*)(sb + RA2_ABH + 5120 + z16) = make_uint2(0,0);
      *(uint2*)(sb + RA2_ABL + 5120 + z16) = make_uint2(0,0);
    }
  }
  __syncthreads();
  floatx4 o[4][4];
  #pragma unroll
  for (int i=0;i<4;i++)
    #pragma unroll
    for (int j=0;j<4;j++){ o[i][j][0]=0.f; o[i][j][1]=0.f; o[i][j][2]=0.f; o[i][j][3]=0.f; }
  #pragma unroll
  for (int ks2=0; ks2<2; ks2++){
    U8 bh[4], bl[4];
    #pragma unroll
    for (int nt=0; nt<4; nt++){
      int a16 = (((nt*16+ln)*5 + lq)<<4);
      bh[nt].q = *(const uint4*)(sb + RA2_ABH + ks2*5120 + a16);
      bl[nt].q = *(const uint4*)(sb + RA2_ABL + ks2*5120 + a16);
    }
    #pragma unroll
    for (int mf=0; mf<4; mf++){
      U8 ah, al;
      size_t ai = (size_t)b*16384 + ((size_t)(ks2*16 + w*4 + mf))*512 + lane*8;
      ah.q = *(const uint4*)(vrh + ai);
      al.q = *(const uint4*)(vrl + ai);
      #pragma unroll
      for (int nt=0; nt<4; nt++){
        o[mf][nt] = __builtin_amdgcn_mfma_f32_16x16x32_bf16(ah.v, bh[nt].v, o[mf][nt], 0,0,0);
        o[mf][nt] = __builtin_amdgcn_mfma_f32_16x16x32_bf16(ah.v, bl[nt].v, o[mf][nt], 0,0,0);
        o[mf][nt] = __builtin_amdgcn_mfma_f32_16x16x32_bf16(al.v, bh[nt].v, o[mf][nt], 0,0,0);
      }
    }
  }
  float bg0 = bg[0];
  #pragma unroll
  for (int nt=0; nt<4; nt++){
    int n = n0 + nt*16 + ln;
    if (n < Nz){
      float gv = sigm(((const float*)(sb+RA2_G))[nt*16+ln] + bg0);
      #pragma unroll
      for (int mf=0; mf<4; mf++){
        float* hp = hb + (size_t)n*Dz + w*64 + mf*16 + lq*4;
        float4 hv = *(const float4*)hp;
        hv.x += gv*o[mf][nt][0];
        hv.y += gv*o[mf][nt][1];
        hv.z += gv*o[mf][nt][2];
        hv.w += gv*o[mf][nt][3];
        *(float4*)hp = hv;
      }
    }
  }
}

// ---------------- MFMA k_kv: A direct->reg, double-buffered B, 1 barrier/ks ----
// (R6 version — empirically best at ~283 µs.)
__global__ __launch_bounds__(256) void k_kv(
    const float* __restrict__ h,
    const u16* __restrict__ wh, const u16* __restrict__ wl,
    const float* __restrict__ cost, const float* __restrict__ sint,
    float* __restrict__ kvbuf){
  __shared__ float smem[8704];
  char* sb = (char*)smem;
  const int t = threadIdx.x;
  const int b = blockIdx.y;
  const int n0 = blockIdx.x*64;
  const int w = t>>6;
  const int lane = t&63;
  const int ln = t&15;
  const int lq = (t>>4)&3;
  const float* hb = h + (size_t)b*Nz*Dz;
  floatx4 acc[2][4][4];
  #pragma unroll
  for (int cp=0;cp<2;cp++)
    #pragma unroll
    for (int i=0;i<4;i++)
      #pragma unroll
      for (int j=0;j<4;j++){ acc[cp][i][j][0]=0.f; acc[cp][i][j][1]=0.f; acc[cp][i][j][2]=0.f; acc[cp][i][j][3]=0.f; }

  const int hrow = t>>2, hcol = t&3;
  const float* hbase = hb + (size_t)(n0+hrow)*Dz + hcol*8;
  const int hvalid = (n0+hrow) < Nz;
  const int a16w = ((hrow*5 + hcol)<<4);

  auto load_h = [&](int ks, float x[8]){
    if (hvalid){
      float4 v0 = *(const float4*)(hbase + ks*32);
      float4 v1 = *(const float4*)(hbase + ks*32 + 4);
      x[0]=v0.x; x[1]=v0.y; x[2]=v0.z; x[3]=v0.w;
      x[4]=v1.x; x[5]=v1.y; x[6]=v1.z; x[7]=v1.w;
    } else {
      #pragma unroll
      for (int e=0;e<8;e++) x[e]=0.f;
    }
  };
  auto cvt_write = [&](const float x[8], int buf){
    uint hw[4], lw[4];
    #pragma unroll
    for (int e=0;e<4;e++){
      uint h0=hi16(x[2*e]), h1=hi16(x[2*e+1]);
      uint l0=hi16(x[2*e]-__uint_as_float(h0<<16));
      uint l1=hi16(x[2*e+1]-__uint_as_float(h1<<16));
      hw[e]=h0|(h1<<16); lw[e]=l0|(l1<<16);
    }
    *(uint4*)(sb + buf*10240 + a16w) = make_uint4(hw[0],hw[1],hw[2],hw[3]);
    *(uint4*)(sb + buf*10240 + 5120 + a16w) = make_uint4(lw[0],lw[1],lw[2],lw[3]);
  };

  { float x0[8]; load_h(0, x0); cvt_write(x0, 0); }
  for (int ks=0; ks<8; ks++){
    __syncthreads();
    float xn[8];
    if (ks < 7) load_h(ks+1, xn);
    const int cb = ks&1;
    U8 bh[4], bl[4];
    #pragma unroll
    for (int nt=0; nt<4; nt++){
      int a16 = (((nt*16+ln)*5 + lq)<<4);
      bh[nt].q = *(const uint4*)(sb + cb*10240 + a16);
      bl[nt].q = *(const uint4*)(sb + cb*10240 + 5120 + a16);
    }
    #pragma unroll
    for (int cp=0; cp<2; cp++){
      #pragma unroll
      for (int mf=0; mf<4; mf++){
        U8 ah, al;
        size_t ai = ((size_t)(ks*32 + cp*16 + w*4 + mf))*512 + lane*8;
        ah.q = *(const uint4*)(wh + ai);
        al.q = *(const uint4*)(wl + ai);
        #pragma unroll
        for (int nt=0; nt<4; nt++){
          acc[cp][mf][nt] = __builtin_amdgcn_mfma_f32_16x16x32_bf16(ah.v, bh[nt].v, acc[cp][mf][nt], 0,0,0);
          acc[cp][mf][nt] = __builtin_amdgcn_mfma_f32_16x16x32_bf16(ah.v, bl[nt].v, acc[cp][mf][nt], 0,0,0);
          acc[cp][mf][nt] = __builtin_amdgcn_mfma_f32_16x16x32_bf16(al.v, bh[nt].v, acc[cp][mf][nt], 0,0,0);
        }
      }
    }
    if (ks < 7) cvt_write(xn, cb^1);
  }
  // epilogue: rope + elu on kf (cp0), zero invalid columns
  #pragma unroll
  for (int mf=0; mf<4; mf++){
    #pragma unroll
    for (int nt=0; nt<4; nt++){
      int n = n0 + nt*16 + ln;
      int valid = (n < Nz);
      int nc = valid ? n : (Nz-1);
      int pi = mf*8 + lq*2;
      float2 c2 = *(const float2*)(cost + (size_t)nc*32 + pi);
      float2 s2 = *(const float2*)(sint + (size_t)nc*32 + pi);
      float q0 = acc[0][mf][nt][0], q1 = acc[0][mf][nt][1];
      float q2 = acc[0][mf][nt][2], q3 = acc[0][mf][nt][3];
      float r0 = elu1(q0*c2.x - q1*s2.x);
      float r1 = elu1(q0*s2.x + q1*c2.x);
      float r2 = elu1(q2*c2.y - q3*s2.y);
      float r3 = elu1(q2*s2.y + q3*c2.y);
      acc[0][mf][nt][0] = valid ? r0 : 0.f;
      acc[0][mf][nt][1] = valid ? r1 : 0.f;
      acc[0][mf][nt][2] = valid ? r2 : 0.f;
      acc[0][mf][nt][3] = valid ? r3 : 0.f;
    }
  }
  // phase B: kv accumulation per head (atomic path)
  const int d = t&63, q4 = t>>6;
  float* kfL = smem;          // [n(64)][68]
  float* vL  = smem + 4352;   // [n(64)][68]
  for (int g=0; g<4; g++){
    __syncthreads();
    if (w == g){
      #pragma unroll
      for (int mf=0; mf<4; mf++){
        #pragma unroll
        for (int nt=0; nt<4; nt++){
          int n = nt*16 + ln;
          int cc = mf*16 + lq*4;
          *(float4*)(kfL + n*68 + cc) = make_float4(acc[0][mf][nt][0],acc[0][mf][nt][1],acc[0][mf][nt][2],acc[0][mf][nt][3]);
          *(float4*)(vL  + n*68 + cc) = make_float4(acc[1][mf][nt][0],acc[1][mf][nt][1],acc[1][mf][nt][2],acc[1][mf][nt][3]);
        }
      }
    }
    __syncthreads();
    float4 kvacc[4];
    #pragma unroll
    for (int u=0;u<4;u++) kvacc[u]=f4z();
    float ksl = 0.f;
    for (int row=0; row<64; row++){
      float kd = kfL[row*68 + d];
      ksl += kd;
      const float4* vp = (const float4*)(vL + row*68);
      #pragma unroll
      for (int u=0;u<4;u++) fma4(kvacc[u], kd, vp[q4*4+u]);
    }
    float* kq = kvbuf + ((size_t)(b*Hz + g))*4160;
    #pragma unroll
    for (int u=0;u<4;u++){
      int e = q4*16 + 4*u;
      atomicAdd(&kq[(e+0)*64+d], kvacc[u].x);
      atomicAdd(&kq[(e+1)*64+d], kvacc[u].y);
      atomicAdd(&kq[(e+2)*64+d], kvacc[u].z);
      atomicAdd(&kq[(e+3)*64+d], kvacc[u].w);
    }
    if (q4==0) atomicAdd(&kq[4096+d], ksl);
  }
}

// P[b][h] = kv_h @ Wo_h  (64 x 256, K=64). grid: Bz*Hz blocks. f32 output.
__global__ __launch_bounds__(256) void k_pmat(const float* __restrict__ kvbuf,
    const float* __restrict__ Wo, float* __restrict__ pmat){
  __shared__ float smem[8448];
  const int t = threadIdx.x;
  const int bh = blockIdx.x;
  const int hh = bh & 3;
  const int c0 = t&15, rr = t>>4;
  const float* kvp = kvbuf + (size_t)bh*4160;
  for (int id=t; id<4096; id+=256){
    int e=id>>6, d=id&63;
    smem[e*68+d] = kvp[id];
  }
  float4 acc[4][4];
  #pragma unroll
  for (int i=0;i<4;i++){
    #pragma unroll
    for (int j=0;j<4;j++) acc[i][j]=f4z();
  }
  for (int kt=0; kt<64; kt+=16){
    __syncthreads();
    for (int id=t; id<1024; id+=256){
      int wr=id>>6, cf=id&63;
      ((float4*)(smem+4352))[wr*64+cf] = ((const float4*)(Wo + (size_t)(hh*64+kt+wr)*256))[cf];
    }
    __syncthreads();
    for (int kk=0; kk<16; kk++){
      float4 a4 = *(const float4*)(smem + (kt+kk)*68 + 4*rr);
      const float4* wrow = (const float4*)(smem+4352) + kk*64;
      float4 w0=wrow[c0], w1=wrow[c0+16], w2=wrow[c0+32], w3=wrow[c0+48];
      #pragma unroll
      for (int i=0;i<4;i++){
        float ac = fcomp(a4,i);
        fma4(acc[i][0],ac,w0); fma4(acc[i][1],ac,w1); fma4(acc[i][2],ac,w2); fma4(acc[i][3],ac,w3);
      }
    }
  }
  float* Pp = pmat + (size_t)bh*16384;
  #pragma unroll
  for (int i=0;i<4;i++){
    #pragma unroll
    for (int j=0;j<4;j++) ((float4*)Pp)[(4*rr+i)*64 + c0 + 16*j] = acc[i][j];
  }
}

// ---------------- MFMA k_att: direct-A, double-buffered B, 1 barrier/step ------
// GEMM1: q^T[c][n] = Wq^T . h^T (256c x 64n, K=256); A direct global->VGPR
// (wave-private fragments), B = h tile double-buffered in LDS (R6 pattern).
// epilogue: rope+elu+z -> qz bf16 hi/lo in registers.
// GEMM2: O[oc][n] = P^T . qz (A direct from packed P^T); B = qz slices,
// double-buffered: owner wave writes slice ks2+1 while slice ks2 is consumed.
// LDS: dbuf [0,20480) = 2 x {BH 5120 | BL 5120}; KS [20480,21504).
#define KA_KS 20480
__global__ __launch_bounds__(256) void k_att(
    float* __restrict__ h,
    const u16* __restrict__ wqh, const u16* __restrict__ wql,
    const u16* __restrict__ pth, const u16* __restrict__ ptl,
    const float* __restrict__ kvbuf,
    const float* __restrict__ cost, const float* __restrict__ sint){
  __shared__ float smem[5376];
  char* sb = (char*)smem;
  const int t = threadIdx.x;
  const int b = blockIdx.y;
  const int n0 = blockIdx.x*64;
  const int w = t>>6;
  const int lane = t&63;
  const int ln = t&15;
  const int lq = (t>>4)&3;
  float* hb = h + (size_t)b*Nz*Dz;
  ((float*)(sb+KA_KS))[t] = kvbuf[(size_t)(b*Hz + w)*4160 + 4096 + lane];

  const int hrow = t>>2, hcol = t&3;
  const float* hbase = hb + (size_t)(n0+hrow)*Dz + hcol*8;
  const int hvalid = (n0+hrow) < Nz;
  const int a16w = ((hrow*5 + hcol)<<4);
  auto load_h = [&](int ks, float x[8]){
    if (hvalid){
      float4 v0 = *(const float4*)(hbase + ks*32);
      float4 v1 = *(const float4*)(hbase + ks*32 + 4);
      x[0]=v0.x; x[1]=v0.y; x[2]=v0.z; x[3]=v0.w;
      x[4]=v1.x; x[5]=v1.y; x[6]=v1.z; x[7]=v1.w;
    } else {
      #pragma unroll
      for (int e=0;e<8;e++) x[e]=0.f;
    }
  };
  auto cvt_write = [&](const float x[8], int buf){
    uint hw[4], lw[4];
    #pragma unroll
    for (int e=0;e<4;e++){
      uint h0=hi16(x[2*e]), h1=hi16(x[2*e+1]);
      uint l0=hi16(x[2*e]-__uint_as_float(h0<<16));
      uint l1=hi16(x[2*e+1]-__uint_as_float(h1<<16));
      hw[e]=h0|(h1<<16); lw[e]=l0|(l1<<16);
    }
    *(uint4*)(sb + buf*10240 + a16w) = make_uint4(hw[0],hw[1],hw[2],hw[3]);
    *(uint4*)(sb + buf*10240 + 5120 + a16w) = make_uint4(lw[0],lw[1],lw[2],lw[3]);
  };

  floatx4 acc[4][4];
  #pragma unroll
  for (int i=0;i<4;i++)
    #pragma unroll
    for (int j=0;j<4;j++){ acc[i][j][0]=0.f; acc[i][j][1]=0.f; acc[i][j][2]=0.f; acc[i][j][3]=0.f; }

  { float x0[8]; load_h(0, x0); cvt_write(x0, 0); }
  for (int ks=0; ks<8; ks++){
    __syncthreads();
    float xn[8];
    if (ks < 7) load_h(ks+1, xn);
    const int cb = ks&1;
    U8 bh[4], bl[4];
    #pragma unroll
    for (int nt=0; nt<4; nt++){
      int a16 = (((nt*16+ln)*5 + lq)<<4);
      bh[nt].q = *(const uint4*)(sb + cb*10240 + a16);
      bl[nt].q = *(const uint4*)(sb + cb*10240 + 5120 + a16);
    }
    #pragma unroll
    for (int mf=0; mf<4; mf++){
      U8 ah, al;
      size_t ai = ((size_t)(ks*16 + w*4 + mf))*512 + lane*8;
      ah.q = *(const uint4*)(wqh + ai);
      al.q = *(const uint4*)(wql + ai);
      #pragma unroll
      for (int nt=0; nt<4; nt++){
        acc[mf][nt] = __builtin_amdgcn_mfma_f32_16x16x32_bf16(ah.v, bh[nt].v, acc[mf][nt], 0,0,0);
        acc[mf][nt] = __builtin_amdgcn_mfma_f32_16x16x32_bf16(ah.v, bl[nt].v, acc[mf][nt], 0,0,0);
        acc[mf][nt] = __builtin_amdgcn_mfma_f32_16x16x32_bf16(al.v, bh[nt].v, acc[mf][nt], 0,0,0);
      }
    }
    if (ks < 7) cvt_write(xn, cb^1);
  }
  // epilogue: rope + elu + z, pack qz to bf16 hi/lo
  uint2 qzh[4][4], qzl[4][4];
  {
    float4 ks4[4];
    #pragma unroll
    for (int mf=0; mf<4; mf++)
      ks4[mf] = *(const float4*)(sb + KA_KS + ((w*64 + mf*16 + lq*4)<<2));
    float psum[4] = {0.f,0.f,0.f,0.f};
    #pragma unroll
    for (int mf=0; mf<4; mf++){
      #pragma unroll
      for (int nt=0; nt<4; nt++){
        int n = n0 + nt*16 + ln;
        int nc = (n < Nz) ? n : (Nz-1);
        int pi = mf*8 + lq*2;
        float2 c2 = *(const float2*)(cost + (size_t)nc*32 + pi);
        float2 s2 = *(const float2*)(sint + (size_t)nc*32 + pi);
        float q0 = acc[mf][nt][0], q1 = acc[mf][nt][1];
        float q2 = acc[mf][nt][2], q3 = acc[mf][nt][3];
        float r0 = elu1(q0*c2.x - q1*s2.x);
        float r1 = elu1(q0*s2.x + q1*c2.x);
        float r2 = elu1(q2*c2.y - q3*s2.y);
        float r3 = elu1(q2*s2.y + q3*c2.y);
        acc[mf][nt][0]=r0; acc[mf][nt][1]=r1; acc[mf][nt][2]=r2; acc[mf][nt][3]=r3;
        psum[nt] += r0*ks4[mf].x + r1*ks4[mf].y + r2*ks4[mf].z + r3*ks4[mf].w;
      }
    }
    float zt[4];
    #pragma unroll
    for (int nt=0; nt<4; nt++){
      float p = psum[nt];
      p += __shfl_xor(p, 16, 64);
      p += __shfl_xor(p, 32, 64);
      zt[nt] = 1.f/(p + 1e-6f);
    }
    #pragma unroll
    for (int mf=0; mf<4; mf++){
      #pragma unroll
      for (int nt=0; nt<4; nt++){
        float v0 = acc[mf][nt][0]*zt[nt];
        float v1 = acc[mf][nt][1]*zt[nt];
        float v2 = acc[mf][nt][2]*zt[nt];
        float v3 = acc[mf][nt][3]*zt[nt];
        uint h0=hi16(v0), h1=hi16(v1), h2=hi16(v2), h3=hi16(v3);
        qzh[mf][nt] = make_uint2(h0|(h1<<16), h2|(h3<<16));
        uint l0=hi16(v0-__uint_as_float(h0<<16));
        uint l1=hi16(v1-__uint_as_float(h1<<16));
        uint l2=hi16(v2-__uint_as_float(h2<<16));
        uint l3=hi16(v3-__uint_as_float(h3<<16));
        qzl[mf][nt] = make_uint2(l0|(l1<<16), l2|(l3<<16));
      }
    }
  }
  // GEMM2: qz slices double-buffered; owner of slice s is wave s>>1
  auto write_slice = [&](int s, int buf){
    #pragma unroll
    for (int mm=0; mm<2; mm++){
      int mf = ((s&1)<<1) + mm;
      int g = (mm<<1) + (lq>>1);
      int sub = (lq&1)*8;
      #pragma unroll
      for (int nt=0; nt<4; nt++){
        int a16 = (((nt*16+ln)*5 + g)<<4) + sub;
        *(uint2*)(sb + buf*10240 + a16) = qzh[mf][nt];
        *(uint2*)(sb + buf*10240 + 5120 + a16) = qzl[mf][nt];
      }
    }
  };
  floatx4 acc2[4][4];
  #pragma unroll
  for (int i=0;i<4;i++)
    #pragma unroll
    for (int j=0;j<4;j++){ acc2[i][j][0]=0.f; acc2[i][j][1]=0.f; acc2[i][j][2]=0.f; acc2[i][j][3]=0.f; }
  __syncthreads();           // drain GEMM1's dbuf reads before qz overwrite
  if (w == 0) write_slice(0, 0);
  for (int ks2=0; ks2<8; ks2++){
    __syncthreads();
    if (ks2 < 7 && w == ((ks2+1)>>1)) write_slice(ks2+1, (ks2+1)&1);
    const int cb = ks2&1;
    U8 bh[4], bl[4];
    #pragma unroll
    for (int nt=0; nt<4; nt++){
      int a16 = (((nt*16+ln)*5 + lq)<<4);
      bh[nt].q = *(const uint4*)(sb + cb*10240 + a16);
      bl[nt].q = *(const uint4*)(sb + cb*10240 + 5120 + a16);
    }
    #pragma unroll
    for (int mf=0; mf<4; mf++){
      U8 ah, al;
      size_t ai = ((size_t)((b*8 + ks2)*16 + w*4 + mf))*512 + lane*8;
      ah.q = *(const uint4*)(pth + ai);
      al.q = *(const uint4*)(ptl + ai);
      #pragma unroll
      for (int nt=0; nt<4; nt++){
        acc2[mf][nt] = __builtin_amdgcn_mfma_f32_16x16x32_bf16(ah.v, bh[nt].v, acc2[mf][nt], 0,0,0);
        acc2[mf][nt] = __builtin_amdgcn_mfma_f32_16x16x32_bf16(ah.v, bl[nt].v, acc2[mf][nt], 0,0,0);
        acc2[mf][nt] = __builtin_amdgcn_mfma_f32_16x16x32_bf16(al.v, bh[nt].v, acc2[mf][nt], 0,0,0);
      }
    }
  }
  // residual add
  #pragma unroll
  for (int mf=0; mf<4; mf++){
    #pragma unroll
    for (int nt=0; nt<4; nt++){
      int n = n0 + nt*16 + ln;
      if (n < Nz){
        float* hp = hb + (size_t)n*Dz + w*64 + mf*16 + lq*4;
        float4 hv = *(const float4*)hp;
        hv.x += acc2[mf][nt][0];
        hv.y += acc2[mf][nt][1];
        hv.z += acc2[mf][nt][2];
        hv.w += acc2[mf][nt][3];
        *(float4*)hp = hv;
      }
    }
  }
}

__global__ __launch_bounds__(256) void k_wkv(const float* __restrict__ h,
    const float* __restrict__ Wwk, const float* __restrict__ Wwv,
    float* __restrict__ wkbuf, float* __restrict__ wvbuf){
  __shared__ float wtL[16*257];
  int t = threadIdx.x;
  int b = blockIdx.y, m0 = blockIdx.x*16;
  const float* hb = h + ((size_t)b*Nz + (Nz-64))*Dz;
  for (int i=t;i<16*Dz;i+=256){ int r=i>>8,c=i&255; wtL[r*257+c] = hb[(size_t)(m0+r)*Dz + c]; }
  __syncthreads();
  int r=t>>4, c0=t&15;
  float4 ak0=f4z(),ak1=f4z(),av0=f4z(),av1=f4z();
  for (int kk=0;kk<Dz;kk++){
    float hv = wtL[r*257+kk];
    const float4* wk4 = (const float4*)(Wwk + (size_t)kk*DCz);
    const float4* wv4 = (const float4*)(Wwv + (size_t)kk*DCz);
    fma4(ak0,hv,wk4[c0]); fma4(ak1,hv,wk4[c0+16]);
    fma4(av0,hv,wv4[c0]); fma4(av1,hv,wv4[c0+16]);
  }
  float4* ok = (float4*)(wkbuf + (size_t)(b*64 + m0+r)*DCz);
  float4* ov = (float4*)(wvbuf + (size_t)(b*64 + m0+r)*DCz);
  ok[c0]=ak0; ok[c0+16]=ak1; ov[c0]=av0; ov[c0+16]=av1;
}

__global__ __launch_bounds__(256) void k_cache_upd(float* __restrict__ cache,
    const float* __restrict__ wkbuf, const float* __restrict__ wvbuf,
    const float* __restrict__ Wwg, const float* __restrict__ bwg,
    int s0, int it, int pas){
  __shared__ float sqL[16*132];
  __shared__ float wkL[64*132];
  __shared__ float wat[16*68];
  __shared__ float ncL[16*132];
  __shared__ float wg[16];
  int t = threadIdx.x; int b = blockIdx.x;
  for (int i=t;i<16*DCz;i+=256){ int k2=i>>7,c=i&127; sqL[k2*132+c] = cache[((size_t)(b*NSLOTz)+s0+k2)*DSLOTz + c]; }
  for (int i=t;i<64*DCz;i+=256){ int m=i>>7,c=i&127; wkL[m*132+c] = wkbuf[(size_t)(b*64+m)*DCz+c]; }
  __syncthreads();
  {
    int k2 = t>>4;
    const float4* s4 = (const float4*)(sqL) + k2*33;
    for (int mm=0;mm<4;mm++){
      int m = (t&15) + 16*mm;
      const float4* k4 = (const float4*)(wkL) + m*33;
      float a=0.f;
      for (int d4=0;d4<32;d4++) a += dot4(s4[d4], k4[d4]);
      wat[k2*68+m] = a * 0.088388347648318447f;
    }
  }
  __syncthreads();
  if (t<16){
    float mx=-1e30f;
    for (int m=0;m<64;m++) mx = fmaxf(mx, wat[t*68+m]);
    float su=0.f;
    for (int m=0;m<64;m++){ float e=__expf(wat[t*68+m]-mx); wat[t*68+m]=e; su+=e; }
    float inv=1.f/su;
    for (int m=0;m<64;m++) wat[t*68+m]*=inv;
  }
  __syncthreads();
  {
    int k2=t>>4, c0=t&15;
    float4 a0=f4z(), a1=f4z();
    const float4* wvg = (const float4*)(wvbuf + (size_t)b*64*DCz);
    for (int m=0;m<64;m++){
      float a = wat[k2*68+m];
      fma4(a0,a,wvg[m*32+c0]); fma4(a1,a,wvg[m*32+c0+16]);
    }
    ((float4*)ncL)[k2*33+c0]=a0; ((float4*)ncL)[k2*33+16+c0]=a1;
  }
  __syncthreads();
  if (t<16){
    float a = bwg[0];
    for (int d2=0; d2<DCz; d2++) a += sqL[t*132+d2]*Wwg[d2] + ncL[t*132+d2]*Wwg[DCz+d2];
    wg[t] = sigm(a);
  }
  __syncthreads();
  for (int i=t;i<16*DCz;i+=256){
    int k2=i>>7,c=i&127;
    cache[((size_t)(b*NSLOTz)+s0+k2)*DSLOTz + c] = sqL[k2*132+c] + wg[k2]*ncL[k2*132+c];
  }
  if (t<16){
    float* cp = cache + ((size_t)(b*NSLOTz)+s0+t)*DSLOTz;
    cp[128] = wg[t];
    cp[137] = (it==0)?1.f:0.f; cp[138] = (it==1)?1.f:0.f; cp[139]=0.f; cp[140]=0.f;
    cp[141] = (pas==0)?1.f:0.f; cp[142] = (pas==1)?1.f:0.f; cp[143]=0.f; cp[144]=0.f;
  }
}

__global__ __launch_bounds__(256) void k_logits(const float* __restrict__ h,
    const float* __restrict__ Wout, const float* __restrict__ bout, float* __restrict__ out){
  __shared__ float hl[16*257];
  int t = threadIdx.x; int row0 = blockIdx.x*16;
  for (int i=t;i<16*Dz;i+=256){
    int rr=i>>8,c=i&255; int row=row0+rr; int b=row/Sz, s=row-b*Sz;
    hl[rr*257+c] = h[((size_t)b*Nz + TSz + s)*Dz + c];
  }
  __syncthreads();
  int rr = t>>4, v = t&15;
  float a = bout[v];
  for (int c=0;c<Dz;c++) a += hl[rr*257+c]*Wout[c*Vz + v];
  out[(size_t)(row0+rr)*Vz + v] = a;
}

__global__ __launch_bounds__(256) void k_feedback(float* __restrict__ h,
    const float* __restrict__ logits0, const float* __restrict__ pae,
    const float* __restrict__ Wfb, const float* __restrict__ bfb){
  __shared__ float trL[16*257];
  __shared__ float paeL[16*257];
  __shared__ int amL[16];
  int t = threadIdx.x; int b = blockIdx.y; int s0 = blockIdx.x*16;
  if (t<16){
    int s = s0+t; int am=0;
    if (s < Sz){
      const float* lg = logits0 + (size_t)(b*Sz+s)*Vz;
      float best = lg[0];
      for (int v=1;v<16;v++){ if (lg[v] > best){ best=lg[v]; am=v; } }
    }
    amL[t]=am;
  }
  for (int i=t;i<16*Dz;i+=256){
    int rr=i>>8,c=i&255; int s=s0+rr;
    trL[rr*257+c] = (s<Sz)? h[((size_t)b*Nz + TSz + s)*Dz + c] : 0.f;
  }
  __syncthreads();
  for (int i=t;i<16*Dz;i+=256){ int rr=i>>8,c=i&255; paeL[rr*257+c] = pae[(size_t)amL[rr]*Dz + c]; }
  __syncthreads();
  int r=t>>4, c0=t&15;
  float4 acc[4]; acc[0]=f4z(); acc[1]=f4z(); acc[2]=f4z(); acc[3]=f4z();
  for (int kk=0;kk<Dz;kk++){
    float xv = trL[r*257+kk];
    const float4* wr = (const float4*)(Wfb + (size_t)kk*Dz);
    fma4(acc[0],xv,wr[c0]); fma4(acc[1],xv,wr[c0+16]); fma4(acc[2],xv,wr[c0+32]); fma4(acc[3],xv,wr[c0+48]);
  }
  for (int kk=0;kk<Dz;kk++){
    float xv = paeL[r*257+kk];
    const float4* wr = (const float4*)(Wfb + (size_t)(Dz+kk)*Dz);
    fma4(acc[0],xv,wr[c0]); fma4(acc[1],xv,wr[c0+16]); fma4(acc[2],xv,wr[c0+32]); fma4(acc[3],xv,wr[c0+48]);
  }
  int s = s0+r;
  if (s < Sz){
    float* cp = h + ((size_t)b*Nz + TSz + s)*Dz;
    #pragma unroll
    for (int j=0;j<4;j++){
      float vals[4] = {acc[j].x, acc[j].y, acc[j].z, acc[j].w};
      #pragma unroll
      for (int q2=0;q2<4;q2++){
        int c = (c0+16*j)*4 + q2;
        float g = sigm(vals[q2] + bfb[c]);
        cp[c] = trL[r*257+c] + g*paeL[r*257+c];
      }
    }
  }
}

extern "C" void kernel_launch(void* const* d_in, const int* in_sizes, int n_in,
                              void* d_out, int out_size, void* d_ws, size_t ws_size,
                              hipStream_t stream){
  (void)in_sizes; (void)n_in;
  const int*   demo_in   = (const int*)d_in[0];
  const int*   demo_out  = (const int*)d_in[1];
  const int*   test_in   = (const int*)d_in[2];
  const float* token_emb = (const float*)d_in[3];
  const float* seg_emb   = (const float*)d_in[4];
  const float* slot_emb  = (const float*)d_in[5];
  const float* lid_emb   = (const float*)d_in[6];
  const float* Wq_read   = (const float*)d_in[7];
  const float* Wk_read   = (const float*)d_in[8];
  const float* Wv_read   = (const float*)d_in[9];
  const float* Wg_read   = (const float*)d_in[10];
  const float* bg_read   = (const float*)d_in[11];
  const float* Wqkv      = (const float*)d_in[12];
  const float* Wo        = (const float*)d_in[13];
  const float* Wwk       = (const float*)d_in[14];
  const float* Wwv       = (const float*)d_in[15];
  const float* Wwg       = (const float*)d_in[16];
  const float* bwg       = (const float*)d_in[17];
  const float* Wout      = (const float*)d_in[18];
  const float* bout      = (const float*)d_in[19];
  const float* pae       = (const float*)d_in[20];
  const float* Wfb       = (const float*)d_in[21];
  const float* bfb       = (const float*)d_in[22];

  char* wsb = (char*)d_ws;
  size_t off = 0;
  auto alloc = [&](size_t bytes)->char*{
    char* p = wsb + off;
    off += (bytes + 255) & ~(size_t)255;
    return p;
  };
  float* hbuf   = (float*)alloc((size_t)Bz*Nz*Dz*4);
  float* cache  = (float*)alloc((size_t)Bz*NSLOTz*DSLOTz*4);
  float* kvbuf  = (float*)alloc((size_t)Bz*Hz*4160*4);
  float* pmat   = (float*)alloc((size_t)Bz*Hz*64*256*4);
  float* wkbuf  = (float*)alloc((size_t)Bz*64*DCz*4);
  float* wvbuf  = (float*)alloc((size_t)Bz*64*DCz*4);
  float* logits0= (float*)alloc((size_t)Bz*Sz*Vz*4);
  float* cost   = (float*)alloc((size_t)Nz*32*4);
  float* sint   = (float*)alloc((size_t)Nz*32*4);
  u16*   wqth   = (u16*)alloc((size_t)3*65536*2);
  u16*   wqtl   = (u16*)alloc((size_t)3*65536*2);
  u16*   pth    = (u16*)alloc((size_t)16*65536*2);
  u16*   ptl    = (u16*)alloc((size_t)16*65536*2);
  u16*   wkvh   = (u16*)alloc((size_t)3*131072*2);
  u16*   wkvl   = (u16*)alloc((size_t)3*131072*2);
  u16*   wqrh   = (u16*)alloc((size_t)3*32768*2);
  u16*   wqrl   = (u16*)alloc((size_t)3*32768*2);
  u16*   krh    = (u16*)alloc((size_t)Bz*6144*2);
  u16*   krl    = (u16*)alloc((size_t)Bz*6144*2);
  u16*   vrh    = (u16*)alloc((size_t)Bz*16384*2);
  u16*   vrl    = (u16*)alloc((size_t)Bz*16384*2);

  if (off > ws_size){
    k_sentinel<<<(out_size+255)/256, 256, 0, stream>>>((float*)d_out, out_size);
    return;
  }

  k_rope<<<(Nz*32+255)/256, 256, 0, stream>>>(cost, sint);
  k_cache_init<<<(Bz*NSLOTz*DSLOTz+255)/256, 256, 0, stream>>>(slot_emb, lid_emb, cache);
  k_pack_w<<<768, 256, 0, stream>>>(Wqkv, wqth, wqtl);
  k_pack_wkv<<<1536, 256, 0, stream>>>(Wqkv, wkvh, wkvl);
  k_pack_wr<<<384, 256, 0, stream>>>(Wq_read, wqrh, wqrl);
  // zero vreadp once: pad rows s=48..63 must be 0 bf16 forever
  k_zero<<<512, 256, 0, stream>>>((float*)vrh, Bz*16384/2);
  k_zero<<<512, 256, 0, stream>>>((float*)vrl, Bz*16384/2);

  for (int pas=0; pas<2; pas++){
    k_embed<<<(Bz*Nz*64+255)/256, 256, 0, stream>>>(demo_in, demo_out, test_in, token_emb, seg_emb, hbuf);
    if (pas==1)
      k_feedback<<<dim3(57,Bz), 256, 0, stream>>>(hbuf, logits0, pae, Wfb, bfb);
    for (int l=0; l<3; l++){
      for (int it=0; it<2; it++){
        k_proj_cache<<<Bz*NSLOTz, 384, 0, stream>>>(cache,
            Wk_read + (size_t)l*DSLOTz*DCz, Wv_read + (size_t)l*DSLOTz*Dz,
            krh, krl, vrh, vrl);
        k_read_attn<<<dim3(GXA,Bz), 256, 0, stream>>>(hbuf,
            wqrh + (size_t)l*32768, wqrl + (size_t)l*32768,
            krh, krl, vrh, vrl,
            Wg_read + (size_t)l*Dz, bg_read + l, kvbuf);
        k_kv<<<dim3(GXA,Bz), 256, 0, stream>>>(hbuf,
            wkvh + (size_t)l*131072, wkvl + (size_t)l*131072, cost, sint, kvbuf);
        k_pmat<<<Bz*Hz, 256, 0, stream>>>(kvbuf, Wo + (size_t)l*Dz*Dz, pmat);
        k_pack_p<<<4096, 256, 0, stream>>>(pmat, pth, ptl);
        k_att<<<dim3(GXA,Bz), 256, 0, stream>>>(hbuf,
            wqth + (size_t)l*65536, wqtl + (size_t)l*65536, pth, ptl,
            kvbuf, cost, sint);
        k_wkv<<<dim3(4,Bz), 256, 0, stream>>>(hbuf,
            Wwk + (size_t)l*Dz*DCz, Wwv + (size_t)l*Dz*DCz, wkbuf, wvbuf);
        k_cache_upd<<<Bz, 256, 0, stream>>>(cache, wkbuf, wvbuf,
            Wwg + (size_t)l*2*DCz, bwg + l, l*16, it, pas);
      }
    }
    float* outp = (pas==0) ? logits0 : (float*)d_out;
    k_logits<<<900, 256, 0, stream>>>(hbuf, Wout, bout, outp);
  }
}

// Round 11
// 7754.336 us; speedup vs baseline: 1.1155x; 1.0190x over previous
//
#include <hip/hip_runtime.h>
#include <math.h>

#define Bz 16
#define Sz 900
#define Vz 16
#define Dz 256
#define DCz 128
#define Hz 4
#define Nz 6300
#define TSz 5400
#define DSLOTz 145
#define NSLOTz 48
#define GXA 99    // ceil(6300/64) row-blocks

typedef unsigned short u16;
typedef unsigned int u32;

typedef __bf16 bf16x8 __attribute__((ext_vector_type(8)));
typedef float floatx4 __attribute__((ext_vector_type(4)));
union U8 { bf16x8 v; uint4 q; };

static __device__ __forceinline__ float sigm(float x){ return 1.0f/(1.0f+__expf(-x)); }
static __device__ __forceinline__ void fma4(float4& a, float s, float4 b){ a.x+=s*b.x; a.y+=s*b.y; a.z+=s*b.z; a.w+=s*b.w; }
static __device__ __forceinline__ float dot4(float4 a, float4 b){ return a.x*b.x + a.y*b.y + a.z*b.z + a.w*b.w; }
static __device__ __forceinline__ float4 f4z(){ float4 z; z.x=0.f; z.y=0.f; z.z=0.f; z.w=0.f; return z; }
static __device__ __forceinline__ float elu1(float x){ return x>0.f ? x+1.f : __expf(x); }
static __device__ __forceinline__ float fcomp(float4 v, int i){ return (i==0)?v.x:(i==1)?v.y:(i==2)?v.z:v.w; }

// round-to-nearest-even bf16 (top 16 bits) of f32
static __device__ __forceinline__ uint hi16(float x){
  uint u = __float_as_uint(x);
  return (u + 0x7fffu + ((u>>16)&1u)) >> 16;
}

typedef const void GV __attribute__((address_space(1)));
typedef void LV __attribute__((address_space(3)));
static __device__ __forceinline__ void gl16(const float* g, float* l){
  __builtin_amdgcn_global_load_lds((GV*)g, (LV*)l, 16, 0, 0);
}
static __device__ __forceinline__ void gl16b(const void* g, void* l){
  __builtin_amdgcn_global_load_lds((GV*)g, (LV*)l, 16, 0, 0);
}

__global__ void k_sentinel(float* out, int nelem){
  int i = blockIdx.x*256 + threadIdx.x;
  if (i < nelem) out[i] = 12345.0f;
}

__global__ void k_zero(float* p, int n){
  int i = blockIdx.x*256 + threadIdx.x;
  if (i < n) p[i] = 0.f;
}

__global__ void k_rope(float* cost, float* sint){
  int i = blockIdx.x*256 + threadIdx.x;
  if (i >= Nz*32) return;
  int n = i>>5, f = i&31;
  double invd = pow(10000.0, -(double)f/32.0);
  double fr = (double)n * invd;
  cost[i] = (float)cos(fr);
  sint[i] = (float)sin(fr);
}

__global__ void k_embed(const int* __restrict__ di, const int* __restrict__ dq,
                        const int* __restrict__ ti, const float* __restrict__ temb,
                        const float* __restrict__ semb, float* __restrict__ h){
  int i = blockIdx.x*256 + threadIdx.x;   // over B*N*64 float4s
  if (i >= Bz*Nz*64) return;
  int dv = i & 63; int bn = i >> 6; int n = bn % Nz; int b = bn / Nz;
  int tok;
  if (n < TSz){
    int nd = n/1800; int r = n - nd*1800;
    tok = (r < Sz) ? di[(b*3+nd)*Sz + r] : dq[(b*3+nd)*Sz + (r-Sz)];
  } else {
    tok = ti[b*Sz + (n-TSz)];
  }
  const float4* e4 = (const float4*)(temb + (size_t)tok*Dz);
  const float4* s4 = (const float4*)semb;
  float4 v = e4[dv]; float4 s = s4[dv];
  v.x += s.x; v.y += s.y; v.z += s.z; v.w += s.w;
  ((float4*)h)[(size_t)bn*64 + dv] = v;
}

__global__ void k_cache_init(const float* __restrict__ slot_emb, const float* __restrict__ lid,
                             float* __restrict__ cache){
  int i = blockIdx.x*256 + threadIdx.x;
  if (i >= Bz*NSLOTz*DSLOTz) return;
  int c = i % DSLOTz; int sc = (i / DSLOTz) % NSLOTz; int l = sc >> 4;
  float v = 0.f;
  if (c < DCz) v = slot_emb[sc*DCz + c];
  else if (c >= 129 && c < 137) v = lid[l*8 + (c-129)];
  cache[i] = v;
}

// pack Wq^T (cols 0..256 of Wqkv) into MFMA A-fragment order, bf16 hi/lo.
__global__ void k_pack_w(const float* __restrict__ Wqkv,
                         u16* __restrict__ wh, u16* __restrict__ wl){
  int i = blockIdx.x*256 + threadIdx.x;
  if (i >= 3*65536) return;
  int l = i >> 16; int r = i & 65535;
  int ks = r >> 13; int ct = (r>>9)&15; int lane = (r>>3)&63; int e = r&7;
  int k = ks*32 + ((lane>>4)<<3) + e;
  int c = ct*16 + (lane&15);
  float x = Wqkv[(size_t)l*196608 + (size_t)k*768 + c];
  uint hb = hi16(x);
  uint lb = hi16(x - __uint_as_float(hb<<16));
  wh[i] = (u16)hb; wl[i] = (u16)lb;
}

// pack Wkv^T (cols 256..768 of Wqkv) into MFMA A-fragment order, bf16 hi/lo.
__global__ void k_pack_wkv(const float* __restrict__ Wqkv,
                           u16* __restrict__ wh, u16* __restrict__ wl){
  int i = blockIdx.x*256 + threadIdx.x;
  if (i >= 3*131072) return;
  int l = i / 131072; int r = i % 131072;
  int ks = r >> 14; int ct = (r>>9)&31; int lane = (r>>3)&63; int e = r&7;
  int k = ks*32 + ((lane>>4)<<3) + e;
  int c = ct*16 + (lane&15);
  float x = Wqkv[(size_t)l*196608 + (size_t)k*768 + 256 + c];
  uint hb = hi16(x);
  uint lb = hi16(x - __uint_as_float(hb<<16));
  wh[i] = (u16)hb; wl[i] = (u16)lb;
}

// pack Wq_read^T into MFMA A-fragment order, bf16 hi/lo.
__global__ void k_pack_wr(const float* __restrict__ Wqr,
                          u16* __restrict__ wh, u16* __restrict__ wl){
  int i = blockIdx.x*256 + threadIdx.x;
  if (i >= 3*32768) return;
  int l = i >> 15; int r = i & 32767;
  int ks = r >> 12; int ct = (r>>9)&7; int lane = (r>>3)&63; int e = r&7;
  int k = ks*32 + ((lane>>4)<<3) + e;
  int c = ct*16 + (lane&15);
  float x = Wqr[(size_t)l*32768 + (size_t)k*DCz + c];
  uint hb = hi16(x);
  uint lb = hi16(x - __uint_as_float(hb<<16));
  wh[i] = (u16)hb; wl[i] = (u16)lb;
}

// pack Pcat^T into MFMA A-fragment order, bf16 hi/lo (coalesced reads+writes).
__global__ void k_pack_p(const float* __restrict__ pmat,
                         u16* __restrict__ ph, u16* __restrict__ pl){
  int i = blockIdx.x*256 + threadIdx.x;
  if (i >= 16*65536) return;
  int b = i >> 16; int r = i & 65535;
  int ks2 = r >> 13; int ct = (r>>9)&15; int lane = (r>>3)&63; int e = r&7;
  int c = ks2*32 + ((lane>>4)<<3) + e;
  int oc = ct*16 + (lane&15);
  float x = pmat[(((size_t)(b*4 + (c>>6)))*64 + (c&63))*256 + oc];
  uint hb = hi16(x);
  uint lb = hi16(x - __uint_as_float(hb<<16));
  ph[i] = (u16)hb; pl[i] = (u16)lb;
}

// cache->kread/vread projections, emitted directly in bf16 hi/lo MFMA A-frag order.
__global__ __launch_bounds__(384) void k_proj_cache(const float* __restrict__ cache,
    const float* __restrict__ Wk, const float* __restrict__ Wv,
    u16* __restrict__ krh, u16* __restrict__ krl,
    u16* __restrict__ vrh, u16* __restrict__ vrl){
  __shared__ float crow[DSLOTz];
  int b = blockIdx.x / NSLOTz, sc = blockIdx.x % NSLOTz;
  int t = threadIdx.x;
  const float* cp = cache + (size_t)(b*NSLOTz+sc)*DSLOTz;
  if (t < DSLOTz) crow[t] = cp[t];
  __syncthreads();
  if (t < DCz){
    float a = 0.f;
    for (int r2=0;r2<DSLOTz;r2++) a += crow[r2]*Wk[r2*DCz + t];
    uint hb = hi16(a);
    uint lb = hi16(a - __uint_as_float(hb<<16));
    int ks = t>>5, st = sc>>4, lane = (sc&15) | (((t>>3)&3)<<4), e = t&7;
    size_t idx = (size_t)b*6144 + (size_t)(((ks*3+st)*64 + lane)*8 + e);
    krh[idx] = (u16)hb; krl[idx] = (u16)lb;
  } else {
    int d = t - DCz;
    float a = 0.f;
    for (int r2=0;r2<DSLOTz;r2++) a += crow[r2]*Wv[r2*Dz + d];
    uint hb = hi16(a);
    uint lb = hi16(a - __uint_as_float(hb<<16));
    int ot = d>>4, ks2 = sc>>5, lane = (d&15) | (((sc>>3)&3)<<4), e = sc&7;
    size_t idx = (size_t)b*16384 + (size_t)(((ks2*16+ot)*64 + lane)*8 + e);
    vrh[idx] = (u16)hb; vrl[idx] = (u16)lb;
  }
}

// -------- MFMA k_read_attn: direct-A, dbuf everywhere, ~15 barriers, 21.8 KB LDS
// GEMM1: q^T[c][n] = Wq_read^T . h^T (128c x 64n, K=256); A direct; B = h tile
// dbuf (1 barrier/ks). gate fp32 from global h. QK^T: q K-slices dbuf (owner wave
// s writes slice s; deferred writes). softmax in registers. AV: attn slices
// written once into both buffers; A = vread direct. Also zeroes kvbuf.
// LDS: dbuf [0,20480) = 2 x {hi 5120 | lo 5120}; G [20480,20736); WG [20736,21760)
#define RB_G  20480
#define RB_WG 20736
__global__ __launch_bounds__(256) void k_read_attn(
    float* __restrict__ h,
    const u16* __restrict__ wqh, const u16* __restrict__ wql,
    const u16* __restrict__ krh, const u16* __restrict__ krl,
    const u16* __restrict__ vrh, const u16* __restrict__ vrl,
    const float* __restrict__ Wg, const float* __restrict__ bg,
    float* __restrict__ kvbuf){
  __shared__ float smem[5440];
  char* sb = (char*)smem;
  const int t = threadIdx.x;
  const int b = blockIdx.y;
  const int n0 = blockIdx.x*64;
  const int w = t>>6, lane = t&63, ln = t&15, lq = (t>>4)&3;
  float* hb = h + (size_t)b*Nz*Dz;
  { // fold: zero kvbuf (stream order: previous k_att was the last reader)
    int gid = (b*GXA + blockIdx.x)*256 + t;
    if (gid < Bz*Hz*4160) kvbuf[gid] = 0.f;
  }
  ((float*)(sb+RB_WG))[t] = Wg[t];

  const int hrow = t>>2, hcol = t&3;
  const float* hbase = hb + (size_t)(n0+hrow)*Dz + hcol*8;
  const int hvalid = (n0+hrow) < Nz;
  const int a16w = ((hrow*5 + hcol)<<4);
  auto load_h = [&](int ks, float x[8]){
    if (hvalid){
      float4 v0 = *(const float4*)(hbase + ks*32);
      float4 v1 = *(const float4*)(hbase + ks*32 + 4);
      x[0]=v0.x; x[1]=v0.y; x[2]=v0.z; x[3]=v0.w;
      x[4]=v1.x; x[5]=v1.y; x[6]=v1.z; x[7]=v1.w;
    } else {
      #pragma unroll
      for (int e=0;e<8;e++) x[e]=0.f;
    }
  };
  auto cvt_write = [&](const float x[8], int buf){
    uint hw[4], lw[4];
    #pragma unroll
    for (int e=0;e<4;e++){
      uint h0=hi16(x[2*e]), h1=hi16(x[2*e+1]);
      uint l0=hi16(x[2*e]-__uint_as_float(h0<<16));
      uint l1=hi16(x[2*e+1]-__uint_as_float(h1<<16));
      hw[e]=h0|(h1<<16); lw[e]=l0|(l1<<16);
    }
    *(uint4*)(sb + buf*10240 + a16w) = make_uint4(hw[0],hw[1],hw[2],hw[3]);
    *(uint4*)(sb + buf*10240 + 5120 + a16w) = make_uint4(lw[0],lw[1],lw[2],lw[3]);
  };

  // ---- GEMM1 (dbuf, 1 barrier/ks) ----
  floatx4 acc[2][4];
  #pragma unroll
  for (int i=0;i<2;i++)
    #pragma unroll
    for (int j=0;j<4;j++){ acc[i][j][0]=0.f; acc[i][j][1]=0.f; acc[i][j][2]=0.f; acc[i][j][3]=0.f; }
  { float x0[8]; load_h(0, x0); cvt_write(x0, 0); }
  for (int ks=0; ks<8; ks++){
    __syncthreads();
    float xn[8];
    if (ks < 7) load_h(ks+1, xn);
    const int cb = ks&1;
    U8 bh[4], bl[4];
    #pragma unroll
    for (int nt=0; nt<4; nt++){
      int a16 = (((nt*16+ln)*5 + lq)<<4);
      bh[nt].q = *(const uint4*)(sb + cb*10240 + a16);
      bl[nt].q = *(const uint4*)(sb + cb*10240 + 5120 + a16);
    }
    #pragma unroll
    for (int mf=0; mf<2; mf++){
      U8 ah, al;
      size_t ai = ((size_t)(ks*8 + w*2 + mf))*512 + lane*8;
      ah.q = *(const uint4*)(wqh + ai);
      al.q = *(const uint4*)(wql + ai);
      #pragma unroll
      for (int nt=0; nt<4; nt++){
        acc[mf][nt] = __builtin_amdgcn_mfma_f32_16x16x32_bf16(ah.v, bh[nt].v, acc[mf][nt], 0,0,0);
        acc[mf][nt] = __builtin_amdgcn_mfma_f32_16x16x32_bf16(ah.v, bl[nt].v, acc[mf][nt], 0,0,0);
        acc[mf][nt] = __builtin_amdgcn_mfma_f32_16x16x32_bf16(al.v, bh[nt].v, acc[mf][nt], 0,0,0);
      }
    }
    if (ks < 7) cvt_write(xn, cb^1);
  }
  // ---- gate (fp32, from global h) ----
  {
    int n = t>>2, kq = t&3;
    int nn = n0+n; int nc = (nn < Nz) ? nn : (Nz-1);
    const float* hp = hb + (size_t)nc*Dz + kq*64;
    const float* wgp = (const float*)(sb+RB_WG) + kq*64;
    float a = 0.f;
    for (int k=0;k<64;k+=4){
      float4 hv = *(const float4*)(hp+k);
      float4 wv = *(const float4*)(wgp+k);
      a += dot4(hv,wv);
    }
    a += __shfl_xor(a,1,64);
    a += __shfl_xor(a,2,64);
    if (kq==0) ((float*)(sb+RB_G))[n] = a;
  }
  // ---- pack q (this wave's c-slice) to registers ----
  uint2 qh[2][4], ql[2][4];
  #pragma unroll
  for (int mf=0; mf<2; mf++){
    #pragma unroll
    for (int nt=0; nt<4; nt++){
      float v0 = acc[mf][nt][0], v1 = acc[mf][nt][1];
      float v2 = acc[mf][nt][2], v3 = acc[mf][nt][3];
      uint h0=hi16(v0), h1=hi16(v1), h2=hi16(v2), h3=hi16(v3);
      uint l0=hi16(v0-__uint_as_float(h0<<16));
      uint l1=hi16(v1-__uint_as_float(h1<<16));
      uint l2=hi16(v2-__uint_as_float(h2<<16));
      uint l3=hi16(v3-__uint_as_float(h3<<16));
      qh[mf][nt] = make_uint2(h0|(h1<<16), h2|(h3<<16));
      ql[mf][nt] = make_uint2(l0|(l1<<16), l2|(l3<<16));
    }
  }
  // ---- QK^T: q K-slices dbuf; owner of slice s is wave s ----
  auto write_qslice = [&](int buf){
    #pragma unroll
    for (int mf=0; mf<2; mf++){
      int g = mf*2 + (lq>>1);
      int sub = (lq&1)<<3;
      #pragma unroll
      for (int nt=0; nt<4; nt++){
        int a16 = (((nt*16+ln)*5 + g)<<4) + sub;
        *(uint2*)(sb + buf*10240 + a16) = qh[mf][nt];
        *(uint2*)(sb + buf*10240 + 5120 + a16) = ql[mf][nt];
      }
    }
  };
  floatx4 sacc[3];
  #pragma unroll
  for (int st=0; st<3; st++){ sacc[st][0]=0.f; sacc[st][1]=0.f; sacc[st][2]=0.f; sacc[st][3]=0.f; }
  __syncthreads();            // drain GEMM1 dbuf reads before q overwrite
  if (w == 0) write_qslice(0);
  for (int ks=0; ks<4; ks++){
    __syncthreads();
    if (ks < 3 && w == ks+1) write_qslice((ks+1)&1);
    const int cb = ks&1;
    U8 bh, bl;
    int a16 = (((w*16+ln)*5 + lq)<<4);
    bh.q = *(const uint4*)(sb + cb*10240 + a16);
    bl.q = *(const uint4*)(sb + cb*10240 + 5120 + a16);
    #pragma unroll
    for (int st=0; st<3; st++){
      U8 ah, al;
      size_t ai = (size_t)b*6144 + ((size_t)(ks*3+st))*512 + lane*8;
      ah.q = *(const uint4*)(krh + ai);
      al.q = *(const uint4*)(krl + ai);
      sacc[st] = __builtin_amdgcn_mfma_f32_16x16x32_bf16(ah.v, bh.v, sacc[st], 0,0,0);
      sacc[st] = __builtin_amdgcn_mfma_f32_16x16x32_bf16(ah.v, bl.v, sacc[st], 0,0,0);
      sacc[st] = __builtin_amdgcn_mfma_f32_16x16x32_bf16(al.v, bh.v, sacc[st], 0,0,0);
    }
  }
  // ---- softmax over s=48 (per n = w*16+ln), in registers ----
  {
    const float scl = 0.088388347648318447f;
    float mx = -1e30f;
    #pragma unroll
    for (int st=0; st<3; st++)
      #pragma unroll
      for (int r=0;r<4;r++){ sacc[st][r] *= scl; mx = fmaxf(mx, sacc[st][r]); }
    mx = fmaxf(mx, __shfl_xor(mx, 16, 64));
    mx = fmaxf(mx, __shfl_xor(mx, 32, 64));
    float su = 0.f;
    #pragma unroll
    for (int st=0; st<3; st++)
      #pragma unroll
      for (int r=0;r<4;r++){ float e = __expf(sacc[st][r]-mx); sacc[st][r]=e; su+=e; }
    su += __shfl_xor(su, 16, 64);
    su += __shfl_xor(su, 32, 64);
    float inv = 1.f/su;
    #pragma unroll
    for (int st=0; st<3; st++)
      #pragma unroll
      for (int r=0;r<4;r++) sacc[st][r] *= inv;
  }
  // ---- write attn B: slice ks2 -> buf ks2 (both at once) ----
  __syncthreads();            // drain QK^T dbuf reads
  {
    uint2 ah2[3], al2[3];
    #pragma unroll
    for (int st=0; st<3; st++){
      float v0=sacc[st][0], v1=sacc[st][1], v2=sacc[st][2], v3=sacc[st][3];
      uint h0=hi16(v0), h1=hi16(v1), h2=hi16(v2), h3=hi16(v3);
      uint l0=hi16(v0-__uint_as_float(h0<<16));
      uint l1=hi16(v1-__uint_as_float(h1<<16));
      uint l2=hi16(v2-__uint_as_float(h2<<16));
      uint l3=hi16(v3-__uint_as_float(h3<<16));
      ah2[st] = make_uint2(h0|(h1<<16), h2|(h3<<16));
      al2[st] = make_uint2(l0|(l1<<16), l2|(l3<<16));
    }
    int rb = (w*16+ln)*5;
    int sub = (lq&1)<<3;
    #pragma unroll
    for (int st=0; st<2; st++){   // slice 0: s=0..31
      int a16 = ((rb + st*2 + (lq>>1))<<4) + sub;
      *(uint2*)(sb + a16) = ah2[st];
      *(uint2*)(sb + 5120 + a16) = al2[st];
    }
    { // slice 1: s=32..47 (st=2), pad s=48..63 zero
      int a16 = ((rb + (lq>>1))<<4) + sub;
      *(uint2*)(sb + 10240 + a16) = ah2[2];
      *(uint2*)(sb + 10240 + 5120 + a16) = al2[2];
      int z16 = ((rb + 2 + (lq>>1))<<4) + sub;
      *(uint2*)(sb + 10240 + z16) = make_uint2(0,0);
      *(uint2*)(sb + 10240 + 5120 + z16) = make_uint2(0,0);
    }
  }
  __syncthreads();
  // ---- AV: O[oc][n], A = vread direct ----
  floatx4 o[4][4];
  #pragma unroll
  for (int i=0;i<4;i++)
    #pragma unroll
    for (int j=0;j<4;j++){ o[i][j][0]=0.f; o[i][j][1]=0.f; o[i][j][2]=0.f; o[i][j][3]=0.f; }
  #pragma unroll
  for (int ks2=0; ks2<2; ks2++){
    U8 bh[4], bl[4];
    #pragma unroll
    for (int nt=0; nt<4; nt++){
      int a16 = (((nt*16+ln)*5 + lq)<<4);
      bh[nt].q = *(const uint4*)(sb + ks2*10240 + a16);
      bl[nt].q = *(const uint4*)(sb + ks2*10240 + 5120 + a16);
    }
    #pragma unroll
    for (int mf=0; mf<4; mf++){
      U8 ah, al;
      size_t ai = (size_t)b*16384 + ((size_t)(ks2*16 + w*4 + mf))*512 + lane*8;
      ah.q = *(const uint4*)(vrh + ai);
      al.q = *(const uint4*)(vrl + ai);
      #pragma unroll
      for (int nt=0; nt<4; nt++){
        o[mf][nt] = __builtin_amdgcn_mfma_f32_16x16x32_bf16(ah.v, bh[nt].v, o[mf][nt], 0,0,0);
        o[mf][nt] = __builtin_amdgcn_mfma_f32_16x16x32_bf16(ah.v, bl[nt].v, o[mf][nt], 0,0,0);
        o[mf][nt] = __builtin_amdgcn_mfma_f32_16x16x32_bf16(al.v, bh[nt].v, o[mf][nt], 0,0,0);
      }
    }
  }
  // ---- epilogue: h += sigm(gate)*read ----
  float bg0 = bg[0];
  #pragma unroll
  for (int nt=0; nt<4; nt++){
    int n = n0 + nt*16 + ln;
    if (n < Nz){
      float gv = sigm(((const float*)(sb+RB_G))[nt*16+ln] + bg0);
      #pragma unroll
      for (int mf=0; mf<4; mf++){
        float* hp = hb + (size_t)n*Dz + w*64 + mf*16 + lq*4;
        float4 hv = *(const float4*)hp;
        hv.x += gv*o[mf][nt][0];
        hv.y += gv*o[mf][nt][1];
        hv.z += gv*o[mf][nt][2];
        hv.w += gv*o[mf][nt][3];
        *(float4*)hp = hv;
      }
    }
  }
}

// ---------------- MFMA k_kv: A direct->reg, double-buffered B, 1 barrier/ks ----
// (R6 version — empirically best at ~285 µs.)
__global__ __launch_bounds__(256) void k_kv(
    const float* __restrict__ h,
    const u16* __restrict__ wh, const u16* __restrict__ wl,
    const float* __restrict__ cost, const float* __restrict__ sint,
    float* __restrict__ kvbuf){
  __shared__ float smem[8704];
  char* sb = (char*)smem;
  const int t = threadIdx.x;
  const int b = blockIdx.y;
  const int n0 = blockIdx.x*64;
  const int w = t>>6;
  const int lane = t&63;
  const int ln = t&15;
  const int lq = (t>>4)&3;
  const float* hb = h + (size_t)b*Nz*Dz;
  floatx4 acc[2][4][4];
  #pragma unroll
  for (int cp=0;cp<2;cp++)
    #pragma unroll
    for (int i=0;i<4;i++)
      #pragma unroll
      for (int j=0;j<4;j++){ acc[cp][i][j][0]=0.f; acc[cp][i][j][1]=0.f; acc[cp][i][j][2]=0.f; acc[cp][i][j][3]=0.f; }

  const int hrow = t>>2, hcol = t&3;
  const float* hbase = hb + (size_t)(n0+hrow)*Dz + hcol*8;
  const int hvalid = (n0+hrow) < Nz;
  const int a16w = ((hrow*5 + hcol)<<4);

  auto load_h = [&](int ks, float x[8]){
    if (hvalid){
      float4 v0 = *(const float4*)(hbase + ks*32);
      float4 v1 = *(const float4*)(hbase + ks*32 + 4);
      x[0]=v0.x; x[1]=v0.y; x[2]=v0.z; x[3]=v0.w;
      x[4]=v1.x; x[5]=v1.y; x[6]=v1.z; x[7]=v1.w;
    } else {
      #pragma unroll
      for (int e=0;e<8;e++) x[e]=0.f;
    }
  };
  auto cvt_write = [&](const float x[8], int buf){
    uint hw[4], lw[4];
    #pragma unroll
    for (int e=0;e<4;e++){
      uint h0=hi16(x[2*e]), h1=hi16(x[2*e+1]);
      uint l0=hi16(x[2*e]-__uint_as_float(h0<<16));
      uint l1=hi16(x[2*e+1]-__uint_as_float(h1<<16));
      hw[e]=h0|(h1<<16); lw[e]=l0|(l1<<16);
    }
    *(uint4*)(sb + buf*10240 + a16w) = make_uint4(hw[0],hw[1],hw[2],hw[3]);
    *(uint4*)(sb + buf*10240 + 5120 + a16w) = make_uint4(lw[0],lw[1],lw[2],lw[3]);
  };

  { float x0[8]; load_h(0, x0); cvt_write(x0, 0); }
  for (int ks=0; ks<8; ks++){
    __syncthreads();
    float xn[8];
    if (ks < 7) load_h(ks+1, xn);
    const int cb = ks&1;
    U8 bh[4], bl[4];
    #pragma unroll
    for (int nt=0; nt<4; nt++){
      int a16 = (((nt*16+ln)*5 + lq)<<4);
      bh[nt].q = *(const uint4*)(sb + cb*10240 + a16);
      bl[nt].q = *(const uint4*)(sb + cb*10240 + 5120 + a16);
    }
    #pragma unroll
    for (int cp=0; cp<2; cp++){
      #pragma unroll
      for (int mf=0; mf<4; mf++){
        U8 ah, al;
        size_t ai = ((size_t)(ks*32 + cp*16 + w*4 + mf))*512 + lane*8;
        ah.q = *(const uint4*)(wh + ai);
        al.q = *(const uint4*)(wl + ai);
        #pragma unroll
        for (int nt=0; nt<4; nt++){
          acc[cp][mf][nt] = __builtin_amdgcn_mfma_f32_16x16x32_bf16(ah.v, bh[nt].v, acc[cp][mf][nt], 0,0,0);
          acc[cp][mf][nt] = __builtin_amdgcn_mfma_f32_16x16x32_bf16(ah.v, bl[nt].v, acc[cp][mf][nt], 0,0,0);
          acc[cp][mf][nt] = __builtin_amdgcn_mfma_f32_16x16x32_bf16(al.v, bh[nt].v, acc[cp][mf][nt], 0,0,0);
        }
      }
    }
    if (ks < 7) cvt_write(xn, cb^1);
  }
  // epilogue: rope + elu on kf (cp0), zero invalid columns
  #pragma unroll
  for (int mf=0; mf<4; mf++){
    #pragma unroll
    for (int nt=0; nt<4; nt++){
      int n = n0 + nt*16 + ln;
      int valid = (n < Nz);
      int nc = valid ? n : (Nz-1);
      int pi = mf*8 + lq*2;
      float2 c2 = *(const float2*)(cost + (size_t)nc*32 + pi);
      float2 s2 = *(const float2*)(sint + (size_t)nc*32 + pi);
      float q0 = acc[0][mf][nt][0], q1 = acc[0][mf][nt][1];
      float q2 = acc[0][mf][nt][2], q3 = acc[0][mf][nt][3];
      float r0 = elu1(q0*c2.x - q1*s2.x);
      float r1 = elu1(q0*s2.x + q1*c2.x);
      float r2 = elu1(q2*c2.y - q3*s2.y);
      float r3 = elu1(q2*s2.y + q3*c2.y);
      acc[0][mf][nt][0] = valid ? r0 : 0.f;
      acc[0][mf][nt][1] = valid ? r1 : 0.f;
      acc[0][mf][nt][2] = valid ? r2 : 0.f;
      acc[0][mf][nt][3] = valid ? r3 : 0.f;
    }
  }
  // phase B: kv accumulation per head (atomic path)
  const int d = t&63, q4 = t>>6;
  float* kfL = smem;          // [n(64)][68]
  float* vL  = smem + 4352;   // [n(64)][68]
  for (int g=0; g<4; g++){
    __syncthreads();
    if (w == g){
      #pragma unroll
      for (int mf=0; mf<4; mf++){
        #pragma unroll
        for (int nt=0; nt<4; nt++){
          int n = nt*16 + ln;
          int cc = mf*16 + lq*4;
          *(float4*)(kfL + n*68 + cc) = make_float4(acc[0][mf][nt][0],acc[0][mf][nt][1],acc[0][mf][nt][2],acc[0][mf][nt][3]);
          *(float4*)(vL  + n*68 + cc) = make_float4(acc[1][mf][nt][0],acc[1][mf][nt][1],acc[1][mf][nt][2],acc[1][mf][nt][3]);
        }
      }
    }
    __syncthreads();
    float4 kvacc[4];
    #pragma unroll
    for (int u=0;u<4;u++) kvacc[u]=f4z();
    float ksl = 0.f;
    for (int row=0; row<64; row++){
      float kd = kfL[row*68 + d];
      ksl += kd;
      const float4* vp = (const float4*)(vL + row*68);
      #pragma unroll
      for (int u=0;u<4;u++) fma4(kvacc[u], kd, vp[q4*4+u]);
    }
    float* kq = kvbuf + ((size_t)(b*Hz + g))*4160;
    #pragma unroll
    for (int u=0;u<4;u++){
      int e = q4*16 + 4*u;
      atomicAdd(&kq[(e+0)*64+d], kvacc[u].x);
      atomicAdd(&kq[(e+1)*64+d], kvacc[u].y);
      atomicAdd(&kq[(e+2)*64+d], kvacc[u].z);
      atomicAdd(&kq[(e+3)*64+d], kvacc[u].w);
    }
    if (q4==0) atomicAdd(&kq[4096+d], ksl);
  }
}

// P[b][h] = kv_h @ Wo_h  (64 x 256, K=64). grid: Bz*Hz blocks. f32 output.
__global__ __launch_bounds__(256) void k_pmat(const float* __restrict__ kvbuf,
    const float* __restrict__ Wo, float* __restrict__ pmat){
  __shared__ float smem[8448];
  const int t = threadIdx.x;
  const int bh = blockIdx.x;
  const int hh = bh & 3;
  const int c0 = t&15, rr = t>>4;
  const float* kvp = kvbuf + (size_t)bh*4160;
  for (int id=t; id<4096; id+=256){
    int e=id>>6, d=id&63;
    smem[e*68+d] = kvp[id];
  }
  float4 acc[4][4];
  #pragma unroll
  for (int i=0;i<4;i++){
    #pragma unroll
    for (int j=0;j<4;j++) acc[i][j]=f4z();
  }
  for (int kt=0; kt<64; kt+=16){
    __syncthreads();
    for (int id=t; id<1024; id+=256){
      int wr=id>>6, cf=id&63;
      ((float4*)(smem+4352))[wr*64+cf] = ((const float4*)(Wo + (size_t)(hh*64+kt+wr)*256))[cf];
    }
    __syncthreads();
    for (int kk=0; kk<16; kk++){
      float4 a4 = *(const float4*)(smem + (kt+kk)*68 + 4*rr);
      const float4* wrow = (const float4*)(smem+4352) + kk*64;
      float4 w0=wrow[c0], w1=wrow[c0+16], w2=wrow[c0+32], w3=wrow[c0+48];
      #pragma unroll
      for (int i=0;i<4;i++){
        float ac = fcomp(a4,i);
        fma4(acc[i][0],ac,w0); fma4(acc[i][1],ac,w1); fma4(acc[i][2],ac,w2); fma4(acc[i][3],ac,w3);
      }
    }
  }
  float* Pp = pmat + (size_t)bh*16384;
  #pragma unroll
  for (int i=0;i<4;i++){
    #pragma unroll
    for (int j=0;j<4;j++) ((float4*)Pp)[(4*rr+i)*64 + c0 + 16*j] = acc[i][j];
  }
}

// ---------------- MFMA k_att: direct-A, double-buffered B, 1 barrier/step ------
#define KA_KS 20480
__global__ __launch_bounds__(256) void k_att(
    float* __restrict__ h,
    const u16* __restrict__ wqh, const u16* __restrict__ wql,
    const u16* __restrict__ pth, const u16* __restrict__ ptl,
    const float* __restrict__ kvbuf,
    const float* __restrict__ cost, const float* __restrict__ sint){
  __shared__ float smem[5376];
  char* sb = (char*)smem;
  const int t = threadIdx.x;
  const int b = blockIdx.y;
  const int n0 = blockIdx.x*64;
  const int w = t>>6;
  const int lane = t&63;
  const int ln = t&15;
  const int lq = (t>>4)&3;
  float* hb = h + (size_t)b*Nz*Dz;
  ((float*)(sb+KA_KS))[t] = kvbuf[(size_t)(b*Hz + w)*4160 + 4096 + lane];

  const int hrow = t>>2, hcol = t&3;
  const float* hbase = hb + (size_t)(n0+hrow)*Dz + hcol*8;
  const int hvalid = (n0+hrow) < Nz;
  const int a16w = ((hrow*5 + hcol)<<4);
  auto load_h = [&](int ks, float x[8]){
    if (hvalid){
      float4 v0 = *(const float4*)(hbase + ks*32);
      float4 v1 = *(const float4*)(hbase + ks*32 + 4);
      x[0]=v0.x; x[1]=v0.y; x[2]=v0.z; x[3]=v0.w;
      x[4]=v1.x; x[5]=v1.y; x[6]=v1.z; x[7]=v1.w;
    } else {
      #pragma unroll
      for (int e=0;e<8;e++) x[e]=0.f;
    }
  };
  auto cvt_write = [&](const float x[8], int buf){
    uint hw[4], lw[4];
    #pragma unroll
    for (int e=0;e<4;e++){
      uint h0=hi16(x[2*e]), h1=hi16(x[2*e+1]);
      uint l0=hi16(x[2*e]-__uint_as_float(h0<<16));
      uint l1=hi16(x[2*e+1]-__uint_as_float(h1<<16));
      hw[e]=h0|(h1<<16); lw[e]=l0|(l1<<16);
    }
    *(uint4*)(sb + buf*10240 + a16w) = make_uint4(hw[0],hw[1],hw[2],hw[3]);
    *(uint4*)(sb + buf*10240 + 5120 + a16w) = make_uint4(lw[0],lw[1],lw[2],lw[3]);
  };

  floatx4 acc[4][4];
  #pragma unroll
  for (int i=0;i<4;i++)
    #pragma unroll
    for (int j=0;j<4;j++){ acc[i][j][0]=0.f; acc[i][j][1]=0.f; acc[i][j][2]=0.f; acc[i][j][3]=0.f; }

  { float x0[8]; load_h(0, x0); cvt_write(x0, 0); }
  for (int ks=0; ks<8; ks++){
    __syncthreads();
    float xn[8];
    if (ks < 7) load_h(ks+1, xn);
    const int cb = ks&1;
    U8 bh[4], bl[4];
    #pragma unroll
    for (int nt=0; nt<4; nt++){
      int a16 = (((nt*16+ln)*5 + lq)<<4);
      bh[nt].q = *(const uint4*)(sb + cb*10240 + a16);
      bl[nt].q = *(const uint4*)(sb + cb*10240 + 5120 + a16);
    }
    #pragma unroll
    for (int mf=0; mf<4; mf++){
      U8 ah, al;
      size_t ai = ((size_t)(ks*16 + w*4 + mf))*512 + lane*8;
      ah.q = *(const uint4*)(wqh + ai);
      al.q = *(const uint4*)(wql + ai);
      #pragma unroll
      for (int nt=0; nt<4; nt++){
        acc[mf][nt] = __builtin_amdgcn_mfma_f32_16x16x32_bf16(ah.v, bh[nt].v, acc[mf][nt], 0,0,0);
        acc[mf][nt] = __builtin_amdgcn_mfma_f32_16x16x32_bf16(ah.v, bl[nt].v, acc[mf][nt], 0,0,0);
        acc[mf][nt] = __builtin_amdgcn_mfma_f32_16x16x32_bf16(al.v, bh[nt].v, acc[mf][nt], 0,0,0);
      }
    }
    if (ks < 7) cvt_write(xn, cb^1);
  }
  // epilogue: rope + elu + z, pack qz to bf16 hi/lo
  uint2 qzh[4][4], qzl[4][4];
  {
    float4 ks4[4];
    #pragma unroll
    for (int mf=0; mf<4; mf++)
      ks4[mf] = *(const float4*)(sb + KA_KS + ((w*64 + mf*16 + lq*4)<<2));
    float psum[4] = {0.f,0.f,0.f,0.f};
    #pragma unroll
    for (int mf=0; mf<4; mf++){
      #pragma unroll
      for (int nt=0; nt<4; nt++){
        int n = n0 + nt*16 + ln;
        int nc = (n < Nz) ? n : (Nz-1);
        int pi = mf*8 + lq*2;
        float2 c2 = *(const float2*)(cost + (size_t)nc*32 + pi);
        float2 s2 = *(const float2*)(sint + (size_t)nc*32 + pi);
        float q0 = acc[mf][nt][0], q1 = acc[mf][nt][1];
        float q2 = acc[mf][nt][2], q3 = acc[mf][nt][3];
        float r0 = elu1(q0*c2.x - q1*s2.x);
        float r1 = elu1(q0*s2.x + q1*c2.x);
        float r2 = elu1(q2*c2.y - q3*s2.y);
        float r3 = elu1(q2*s2.y + q3*c2.y);
        acc[mf][nt][0]=r0; acc[mf][nt][1]=r1; acc[mf][nt][2]=r2; acc[mf][nt][3]=r3;
        psum[nt] += r0*ks4[mf].x + r1*ks4[mf].y + r2*ks4[mf].z + r3*ks4[mf].w;
      }
    }
    float zt[4];
    #pragma unroll
    for (int nt=0; nt<4; nt++){
      float p = psum[nt];
      p += __shfl_xor(p, 16, 64);
      p += __shfl_xor(p, 32, 64);
      zt[nt] = 1.f/(p + 1e-6f);
    }
    #pragma unroll
    for (int mf=0; mf<4; mf++){
      #pragma unroll
      for (int nt=0; nt<4; nt++){
        float v0 = acc[mf][nt][0]*zt[nt];
        float v1 = acc[mf][nt][1]*zt[nt];
        float v2 = acc[mf][nt][2]*zt[nt];
        float v3 = acc[mf][nt][3]*zt[nt];
        uint h0=hi16(v0), h1=hi16(v1), h2=hi16(v2), h3=hi16(v3);
        qzh[mf][nt] = make_uint2(h0|(h1<<16), h2|(h3<<16));
        uint l0=hi16(v0-__uint_as_float(h0<<16));
        uint l1=hi16(v1-__uint_as_float(h1<<16));
        uint l2=hi16(v2-__uint_as_float(h2<<16));
        uint l3=hi16(v3-__uint_as_float(h3<<16));
        qzl[mf][nt] = make_uint2(l0|(l1<<16), l2|(l3<<16));
      }
    }
  }
  // GEMM2: qz slices double-buffered; owner of slice s is wave s>>1
  auto write_slice = [&](int s, int buf){
    #pragma unroll
    for (int mm=0; mm<2; mm++){
      int mf = ((s&1)<<1) + mm;
      int g = (mm<<1) + (lq>>1);
      int sub = (lq&1)*8;
      #pragma unroll
      for (int nt=0; nt<4; nt++){
        int a16 = (((nt*16+ln)*5 + g)<<4) + sub;
        *(uint2*)(sb + buf*10240 + a16) = qzh[mf][nt];
        *(uint2*)(sb + buf*10240 + 5120 + a16) = qzl[mf][nt];
      }
    }
  };
  floatx4 acc2[4][4];
  #pragma unroll
  for (int i=0;i<4;i++)
    #pragma unroll
    for (int j=0;j<4;j++){ acc2[i][j][0]=0.f; acc2[i][j][1]=0.f; acc2[i][j][2]=0.f; acc2[i][j][3]=0.f; }
  __syncthreads();           // drain GEMM1's dbuf reads before qz overwrite
  if (w == 0) write_slice(0, 0);
  for (int ks2=0; ks2<8; ks2++){
    __syncthreads();
    if (ks2 < 7 && w == ((ks2+1)>>1)) write_slice(ks2+1, (ks2+1)&1);
    const int cb = ks2&1;
    U8 bh[4], bl[4];
    #pragma unroll
    for (int nt=0; nt<4; nt++){
      int a16 = (((nt*16+ln)*5 + lq)<<4);
      bh[nt].q = *(const uint4*)(sb + cb*10240 + a16);
      bl[nt].q = *(const uint4*)(sb + cb*10240 + 5120 + a16);
    }
    #pragma unroll
    for (int mf=0; mf<4; mf++){
      U8 ah, al;
      size_t ai = ((size_t)((b*8 + ks2)*16 + w*4 + mf))*512 + lane*8;
      ah.q = *(const uint4*)(pth + ai);
      al.q = *(const uint4*)(ptl + ai);
      #pragma unroll
      for (int nt=0; nt<4; nt++){
        acc2[mf][nt] = __builtin_amdgcn_mfma_f32_16x16x32_bf16(ah.v, bh[nt].v, acc2[mf][nt], 0,0,0);
        acc2[mf][nt] = __builtin_amdgcn_mfma_f32_16x16x32_bf16(ah.v, bl[nt].v, acc2[mf][nt], 0,0,0);
        acc2[mf][nt] = __builtin_amdgcn_mfma_f32_16x16x32_bf16(al.v, bh[nt].v, acc2[mf][nt], 0,0,0);
      }
    }
  }
  // residual add
  #pragma unroll
  for (int mf=0; mf<4; mf++){
    #pragma unroll
    for (int nt=0; nt<4; nt++){
      int n = n0 + nt*16 + ln;
      if (n < Nz){
        float* hp = hb + (size_t)n*Dz + w*64 + mf*16 + lq*4;
        float4 hv = *(const float4*)hp;
        hv.x += acc2[mf][nt][0];
        hv.y += acc2[mf][nt][1];
        hv.z += acc2[mf][nt][2];
        hv.w += acc2[mf][nt][3];
        *(float4*)hp = hv;
      }
    }
  }
}

__global__ __launch_bounds__(256) void k_wkv(const float* __restrict__ h,
    const float* __restrict__ Wwk, const float* __restrict__ Wwv,
    float* __restrict__ wkbuf, float* __restrict__ wvbuf){
  __shared__ float wtL[16*257];
  int t = threadIdx.x;
  int b = blockIdx.y, m0 = blockIdx.x*16;
  const float* hb = h + ((size_t)b*Nz + (Nz-64))*Dz;
  for (int i=t;i<16*Dz;i+=256){ int r=i>>8,c=i&255; wtL[r*257+c] = hb[(size_t)(m0+r)*Dz + c]; }
  __syncthreads();
  int r=t>>4, c0=t&15;
  float4 ak0=f4z(),ak1=f4z(),av0=f4z(),av1=f4z();
  for (int kk=0;kk<Dz;kk++){
    float hv = wtL[r*257+kk];
    const float4* wk4 = (const float4*)(Wwk + (size_t)kk*DCz);
    const float4* wv4 = (const float4*)(Wwv + (size_t)kk*DCz);
    fma4(ak0,hv,wk4[c0]); fma4(ak1,hv,wk4[c0+16]);
    fma4(av0,hv,wv4[c0]); fma4(av1,hv,wv4[c0+16]);
  }
  float4* ok = (float4*)(wkbuf + (size_t)(b*64 + m0+r)*DCz);
  float4* ov = (float4*)(wvbuf + (size_t)(b*64 + m0+r)*DCz);
  ok[c0]=ak0; ok[c0+16]=ak1; ov[c0]=av0; ov[c0+16]=av1;
}

__global__ __launch_bounds__(256) void k_cache_upd(float* __restrict__ cache,
    const float* __restrict__ wkbuf, const float* __restrict__ wvbuf,
    const float* __restrict__ Wwg, const float* __restrict__ bwg,
    int s0, int it, int pas){
  __shared__ float sqL[16*132];
  __shared__ float wkL[64*132];
  __shared__ float wat[16*68];
  __shared__ float ncL[16*132];
  __shared__ float wg[16];
  int t = threadIdx.x; int b = blockIdx.x;
  for (int i=t;i<16*DCz;i+=256){ int k2=i>>7,c=i&127; sqL[k2*132+c] = cache[((size_t)(b*NSLOTz)+s0+k2)*DSLOTz + c]; }
  for (int i=t;i<64*DCz;i+=256){ int m=i>>7,c=i&127; wkL[m*132+c] = wkbuf[(size_t)(b*64+m)*DCz+c]; }
  __syncthreads();
  {
    int k2 = t>>4;
    const float4* s4 = (const float4*)(sqL) + k2*33;
    for (int mm=0;mm<4;mm++){
      int m = (t&15) + 16*mm;
      const float4* k4 = (const float4*)(wkL) + m*33;
      float a=0.f;
      for (int d4=0;d4<32;d4++) a += dot4(s4[d4], k4[d4]);
      wat[k2*68+m] = a * 0.088388347648318447f;
    }
  }
  __syncthreads();
  if (t<16){
    float mx=-1e30f;
    for (int m=0;m<64;m++) mx = fmaxf(mx, wat[t*68+m]);
    float su=0.f;
    for (int m=0;m<64;m++){ float e=__expf(wat[t*68+m]-mx); wat[t*68+m]=e; su+=e; }
    float inv=1.f/su;
    for (int m=0;m<64;m++) wat[t*68+m]*=inv;
  }
  __syncthreads();
  {
    int k2=t>>4, c0=t&15;
    float4 a0=f4z(), a1=f4z();
    const float4* wvg = (const float4*)(wvbuf + (size_t)b*64*DCz);
    for (int m=0;m<64;m++){
      float a = wat[k2*68+m];
      fma4(a0,a,wvg[m*32+c0]); fma4(a1,a,wvg[m*32+c0+16]);
    }
    ((float4*)ncL)[k2*33+c0]=a0; ((float4*)ncL)[k2*33+16+c0]=a1;
  }
  __syncthreads();
  if (t<16){
    float a = bwg[0];
    for (int d2=0; d2<DCz; d2++) a += sqL[t*132+d2]*Wwg[d2] + ncL[t*132+d2]*Wwg[DCz+d2];
    wg[t] = sigm(a);
  }
  __syncthreads();
  for (int i=t;i<16*DCz;i+=256){
    int k2=i>>7,c=i&127;
    cache[((size_t)(b*NSLOTz)+s0+k2)*DSLOTz + c] = sqL[k2*132+c] + wg[k2]*ncL[k2*132+c];
  }
  if (t<16){
    float* cp = cache + ((size_t)(b*NSLOTz)+s0+t)*DSLOTz;
    cp[128] = wg[t];
    cp[137] = (it==0)?1.f:0.f; cp[138] = (it==1)?1.f:0.f; cp[139]=0.f; cp[140]=0.f;
    cp[141] = (pas==0)?1.f:0.f; cp[142] = (pas==1)?1.f:0.f; cp[143]=0.f; cp[144]=0.f;
  }
}

__global__ __launch_bounds__(256) void k_logits(const float* __restrict__ h,
    const float* __restrict__ Wout, const float* __restrict__ bout, float* __restrict__ out){
  __shared__ float hl[16*257];
  int t = threadIdx.x; int row0 = blockIdx.x*16;
  for (int i=t;i<16*Dz;i+=256){
    int rr=i>>8,c=i&255; int row=row0+rr; int b=row/Sz, s=row-b*Sz;
    hl[rr*257+c] = h[((size_t)b*Nz + TSz + s)*Dz + c];
  }
  __syncthreads();
  int rr = t>>4, v = t&15;
  float a = bout[v];
  for (int c=0;c<Dz;c++) a += hl[rr*257+c]*Wout[c*Vz + v];
  out[(size_t)(row0+rr)*Vz + v] = a;
}

__global__ __launch_bounds__(256) void k_feedback(float* __restrict__ h,
    const float* __restrict__ logits0, const float* __restrict__ pae,
    const float* __restrict__ Wfb, const float* __restrict__ bfb){
  __shared__ float trL[16*257];
  __shared__ float paeL[16*257];
  __shared__ int amL[16];
  int t = threadIdx.x; int b = blockIdx.y; int s0 = blockIdx.x*16;
  if (t<16){
    int s = s0+t; int am=0;
    if (s < Sz){
      const float* lg = logits0 + (size_t)(b*Sz+s)*Vz;
      float best = lg[0];
      for (int v=1;v<16;v++){ if (lg[v] > best){ best=lg[v]; am=v; } }
    }
    amL[t]=am;
  }
  for (int i=t;i<16*Dz;i+=256){
    int rr=i>>8,c=i&255; int s=s0+rr;
    trL[rr*257+c] = (s<Sz)? h[((size_t)b*Nz + TSz + s)*Dz + c] : 0.f;
  }
  __syncthreads();
  for (int i=t;i<16*Dz;i+=256){ int rr=i>>8,c=i&255; paeL[rr*257+c] = pae[(size_t)amL[rr]*Dz + c]; }
  __syncthreads();
  int r=t>>4, c0=t&15;
  float4 acc[4]; acc[0]=f4z(); acc[1]=f4z(); acc[2]=f4z(); acc[3]=f4z();
  for (int kk=0;kk<Dz;kk++){
    float xv = trL[r*257+kk];
    const float4* wr = (const float4*)(Wfb + (size_t)kk*Dz);
    fma4(acc[0],xv,wr[c0]); fma4(acc[1],xv,wr[c0+16]); fma4(acc[2],xv,wr[c0+32]); fma4(acc[3],xv,wr[c0+48]);
  }
  for (int kk=0;kk<Dz;kk++){
    float xv = paeL[r*257+kk];
    const float4* wr = (const float4*)(Wfb + (size_t)(Dz+kk)*Dz);
    fma4(acc[0],xv,wr[c0]); fma4(acc[1],xv,wr[c0+16]); fma4(acc[2],xv,wr[c0+32]); fma4(acc[3],xv,wr[c0+48]);
  }
  int s = s0+r;
  if (s < Sz){
    float* cp = h + ((size_t)b*Nz + TSz + s)*Dz;
    #pragma unroll
    for (int j=0;j<4;j++){
      float vals[4] = {acc[j].x, acc[j].y, acc[j].z, acc[j].w};
      #pragma unroll
      for (int q2=0;q2<4;q2++){
        int c = (c0+16*j)*4 + q2;
        float g = sigm(vals[q2] + bfb[c]);
        cp[c] = trL[r*257+c] + g*paeL[r*257+c];
      }
    }
  }
}

extern "C" void kernel_launch(void* const* d_in, const int* in_sizes, int n_in,
                              void* d_out, int out_size, void* d_ws, size_t ws_size,
                              hipStream_t stream){
  (void)in_sizes; (void)n_in;
  const int*   demo_in   = (const int*)d_in[0];
  const int*   demo_out  = (const int*)d_in[1];
  const int*   test_in   = (const int*)d_in[2];
  const float* token_emb = (const float*)d_in[3];
  const float* seg_emb   = (const float*)d_in[4];
  const float* slot_emb  = (const float*)d_in[5];
  const float* lid_emb   = (const float*)d_in[6];
  const float* Wq_read   = (const float*)d_in[7];
  const float* Wk_read   = (const float*)d_in[8];
  const float* Wv_read   = (const float*)d_in[9];
  const float* Wg_read   = (const float*)d_in[10];
  const float* bg_read   = (const float*)d_in[11];
  const float* Wqkv      = (const float*)d_in[12];
  const float* Wo        = (const float*)d_in[13];
  const float* Wwk       = (const float*)d_in[14];
  const float* Wwv       = (const float*)d_in[15];
  const float* Wwg       = (const float*)d_in[16];
  const float* bwg       = (const float*)d_in[17];
  const float* Wout      = (const float*)d_in[18];
  const float* bout      = (const float*)d_in[19];
  const float* pae       = (const float*)d_in[20];
  const float* Wfb       = (const float*)d_in[21];
  const float* bfb       = (const float*)d_in[22];

  char* wsb = (char*)d_ws;
  size_t off = 0;
  auto alloc = [&](size_t bytes)->char*{
    char* p = wsb + off;
    off += (bytes + 255) & ~(size_t)255;
    return p;
  };
  float* hbuf   = (float*)alloc((size_t)Bz*Nz*Dz*4);
  float* cache  = (float*)alloc((size_t)Bz*NSLOTz*DSLOTz*4);
  float* kvbuf  = (float*)alloc((size_t)Bz*Hz*4160*4);
  float* pmat   = (float*)alloc((size_t)Bz*Hz*64*256*4);
  float* wkbuf  = (float*)alloc((size_t)Bz*64*DCz*4);
  float* wvbuf  = (float*)alloc((size_t)Bz*64*DCz*4);
  float* logits0= (float*)alloc((size_t)Bz*Sz*Vz*4);
  float* cost   = (float*)alloc((size_t)Nz*32*4);
  float* sint   = (float*)alloc((size_t)Nz*32*4);
  u16*   wqth   = (u16*)alloc((size_t)3*65536*2);
  u16*   wqtl   = (u16*)alloc((size_t)3*65536*2);
  u16*   pth    = (u16*)alloc((size_t)16*65536*2);
  u16*   ptl    = (u16*)alloc((size_t)16*65536*2);
  u16*   wkvh   = (u16*)alloc((size_t)3*131072*2);
  u16*   wkvl   = (u16*)alloc((size_t)3*131072*2);
  u16*   wqrh   = (u16*)alloc((size_t)3*32768*2);
  u16*   wqrl   = (u16*)alloc((size_t)3*32768*2);
  u16*   krh    = (u16*)alloc((size_t)Bz*6144*2);
  u16*   krl    = (u16*)alloc((size_t)Bz*6144*2);
  u16*   vrh    = (u16*)alloc((size_t)Bz*16384*2);
  u16*   vrl    = (u16*)alloc((size_t)Bz*16384*2);

  if (off > ws_size){
    k_sentinel<<<(out_size+255)/256, 256, 0, stream>>>((float*)d_out, out_size);
    return;
  }

  k_rope<<<(Nz*32+255)/256, 256, 0, stream>>>(cost, sint);
  k_cache_init<<<(Bz*NSLOTz*DSLOTz+255)/256, 256, 0, stream>>>(slot_emb, lid_emb, cache);
  k_pack_w<<<768, 256, 0, stream>>>(Wqkv, wqth, wqtl);
  k_pack_wkv<<<1536, 256, 0, stream>>>(Wqkv, wkvh, wkvl);
  k_pack_wr<<<384, 256, 0, stream>>>(Wq_read, wqrh, wqrl);
  // zero vreadp once: pad rows s=48..63 must be 0 bf16 forever
  k_zero<<<512, 256, 0, stream>>>((float*)vrh, Bz*16384/2);
  k_zero<<<512, 256, 0, stream>>>((float*)vrl, Bz*16384/2);

  for (int pas=0; pas<2; pas++){
    k_embed<<<(Bz*Nz*64+255)/256, 256, 0, stream>>>(demo_in, demo_out, test_in, token_emb, seg_emb, hbuf);
    if (pas==1)
      k_feedback<<<dim3(57,Bz), 256, 0, stream>>>(hbuf, logits0, pae, Wfb, bfb);
    for (int l=0; l<3; l++){
      for (int it=0; it<2; it++){
        k_proj_cache<<<Bz*NSLOTz, 384, 0, stream>>>(cache,
            Wk_read + (size_t)l*DSLOTz*DCz, Wv_read + (size_t)l*DSLOTz*Dz,
            krh, krl, vrh, vrl);
        k_read_attn<<<dim3(GXA,Bz), 256, 0, stream>>>(hbuf,
            wqrh + (size_t)l*32768, wqrl + (size_t)l*32768,
            krh, krl, vrh, vrl,
            Wg_read + (size_t)l*Dz, bg_read + l, kvbuf);
        k_kv<<<dim3(GXA,Bz), 256, 0, stream>>>(hbuf,
            wkvh + (size_t)l*131072, wkvl + (size_t)l*131072, cost, sint, kvbuf);
        k_pmat<<<Bz*Hz, 256, 0, stream>>>(kvbuf, Wo + (size_t)l*Dz*Dz, pmat);
        k_pack_p<<<4096, 256, 0, stream>>>(pmat, pth, ptl);
        k_att<<<dim3(GXA,Bz), 256, 0, stream>>>(hbuf,
            wqth + (size_t)l*65536, wqtl + (size_t)l*65536, pth, ptl,
            kvbuf, cost, sint);
        k_wkv<<<dim3(4,Bz), 256, 0, stream>>>(hbuf,
            Wwk + (size_t)l*Dz*DCz, Wwv + (size_t)l*Dz*DCz, wkbuf, wvbuf);
        k_cache_upd<<<Bz, 256, 0, stream>>>(cache, wkbuf, wvbuf,
            Wwg + (size_t)l*2*DCz, bwg + l, l*16, it, pas);
      }
    }
    float* outp = (pas==0) ? logits0 : (float*)d_out;
    k_logits<<<900, 256, 0, stream>>>(hbuf, Wout, bout, outp);
  }
}

// Round 12
// 7736.755 us; speedup vs baseline: 1.1180x; 1.0023x over previous
//
#include <hip/hip_runtime.h>
#include <math.h>

#define Bz 16
#define Sz 900
#define Vz 16
#define Dz 256
#define DCz 128
#define Hz 4
#define Nz 6300
#define TSz 5400
#define DSLOTz 145
#define NSLOTz 48
#define GXA 99    // ceil(6300/64) row-blocks

typedef unsigned short u16;
typedef unsigned int u32;

typedef __bf16 bf16x8 __attribute__((ext_vector_type(8)));
typedef float floatx4 __attribute__((ext_vector_type(4)));
union U8 { bf16x8 v; uint4 q; };

static __device__ __forceinline__ float sigm(float x){ return 1.0f/(1.0f+__expf(-x)); }
static __device__ __forceinline__ void fma4(float4& a, float s, float4 b){ a.x+=s*b.x; a.y+=s*b.y; a.z+=s*b.z; a.w+=s*b.w; }
static __device__ __forceinline__ float dot4(float4 a, float4 b){ return a.x*b.x + a.y*b.y + a.z*b.z + a.w*b.w; }
static __device__ __forceinline__ float4 f4z(){ float4 z; z.x=0.f; z.y=0.f; z.z=0.f; z.w=0.f; return z; }
static __device__ __forceinline__ float elu1(float x){ return x>0.f ? x+1.f : __expf(x); }
static __device__ __forceinline__ float fcomp(float4 v, int i){ return (i==0)?v.x:(i==1)?v.y:(i==2)?v.z:v.w; }

// round-to-nearest-even bf16 (top 16 bits) of f32
static __device__ __forceinline__ uint hi16(float x){
  uint u = __float_as_uint(x);
  return (u + 0x7fffu + ((u>>16)&1u)) >> 16;
}

typedef const void GV __attribute__((address_space(1)));
typedef void LV __attribute__((address_space(3)));
static __device__ __forceinline__ void gl16(const float* g, float* l){
  __builtin_amdgcn_global_load_lds((GV*)g, (LV*)l, 16, 0, 0);
}
static __device__ __forceinline__ void gl16b(const void* g, void* l){
  __builtin_amdgcn_global_load_lds((GV*)g, (LV*)l, 16, 0, 0);
}

__global__ void k_sentinel(float* out, int nelem){
  int i = blockIdx.x*256 + threadIdx.x;
  if (i < nelem) out[i] = 12345.0f;
}

__global__ void k_zero(float* p, int n){
  int i = blockIdx.x*256 + threadIdx.x;
  if (i < n) p[i] = 0.f;
}

__global__ void k_rope(float* cost, float* sint){
  int i = blockIdx.x*256 + threadIdx.x;
  if (i >= Nz*32) return;
  int n = i>>5, f = i&31;
  double invd = pow(10000.0, -(double)f/32.0);
  double fr = (double)n * invd;
  cost[i] = (float)cos(fr);
  sint[i] = (float)sin(fr);
}

__global__ void k_embed(const int* __restrict__ di, const int* __restrict__ dq,
                        const int* __restrict__ ti, const float* __restrict__ temb,
                        const float* __restrict__ semb, float* __restrict__ h){
  int i = blockIdx.x*256 + threadIdx.x;   // over B*N*64 float4s
  if (i >= Bz*Nz*64) return;
  int dv = i & 63; int bn = i >> 6; int n = bn % Nz; int b = bn / Nz;
  int tok;
  if (n < TSz){
    int nd = n/1800; int r = n - nd*1800;
    tok = (r < Sz) ? di[(b*3+nd)*Sz + r] : dq[(b*3+nd)*Sz + (r-Sz)];
  } else {
    tok = ti[b*Sz + (n-TSz)];
  }
  const float4* e4 = (const float4*)(temb + (size_t)tok*Dz);
  const float4* s4 = (const float4*)semb;
  float4 v = e4[dv]; float4 s = s4[dv];
  v.x += s.x; v.y += s.y; v.z += s.z; v.w += s.w;
  ((float4*)h)[(size_t)bn*64 + dv] = v;
}

__global__ void k_cache_init(const float* __restrict__ slot_emb, const float* __restrict__ lid,
                             float* __restrict__ cache){
  int i = blockIdx.x*256 + threadIdx.x;
  if (i >= Bz*NSLOTz*DSLOTz) return;
  int c = i % DSLOTz; int sc = (i / DSLOTz) % NSLOTz; int l = sc >> 4;
  float v = 0.f;
  if (c < DCz) v = slot_emb[sc*DCz + c];
  else if (c >= 129 && c < 137) v = lid[l*8 + (c-129)];
  cache[i] = v;
}

// pack Wq^T (cols 0..256 of Wqkv) into MFMA A-fragment order, bf16 hi/lo.
__global__ void k_pack_w(const float* __restrict__ Wqkv,
                         u16* __restrict__ wh, u16* __restrict__ wl){
  int i = blockIdx.x*256 + threadIdx.x;
  if (i >= 3*65536) return;
  int l = i >> 16; int r = i & 65535;
  int ks = r >> 13; int ct = (r>>9)&15; int lane = (r>>3)&63; int e = r&7;
  int k = ks*32 + ((lane>>4)<<3) + e;
  int c = ct*16 + (lane&15);
  float x = Wqkv[(size_t)l*196608 + (size_t)k*768 + c];
  uint hb = hi16(x);
  uint lb = hi16(x - __uint_as_float(hb<<16));
  wh[i] = (u16)hb; wl[i] = (u16)lb;
}

// pack Wkv^T (cols 256..768 of Wqkv) into MFMA A-fragment order, bf16 hi/lo.
__global__ void k_pack_wkv(const float* __restrict__ Wqkv,
                           u16* __restrict__ wh, u16* __restrict__ wl){
  int i = blockIdx.x*256 + threadIdx.x;
  if (i >= 3*131072) return;
  int l = i / 131072; int r = i % 131072;
  int ks = r >> 14; int ct = (r>>9)&31; int lane = (r>>3)&63; int e = r&7;
  int k = ks*32 + ((lane>>4)<<3) + e;
  int c = ct*16 + (lane&15);
  float x = Wqkv[(size_t)l*196608 + (size_t)k*768 + 256 + c];
  uint hb = hi16(x);
  uint lb = hi16(x - __uint_as_float(hb<<16));
  wh[i] = (u16)hb; wl[i] = (u16)lb;
}

// pack Wq_read^T into MFMA A-fragment order, bf16 hi/lo.
__global__ void k_pack_wr(const float* __restrict__ Wqr,
                          u16* __restrict__ wh, u16* __restrict__ wl){
  int i = blockIdx.x*256 + threadIdx.x;
  if (i >= 3*32768) return;
  int l = i >> 15; int r = i & 32767;
  int ks = r >> 12; int ct = (r>>9)&7; int lane = (r>>3)&63; int e = r&7;
  int k = ks*32 + ((lane>>4)<<3) + e;
  int c = ct*16 + (lane&15);
  float x = Wqr[(size_t)l*32768 + (size_t)k*DCz + c];
  uint hb = hi16(x);
  uint lb = hi16(x - __uint_as_float(hb<<16));
  wh[i] = (u16)hb; wl[i] = (u16)lb;
}

// cache->kread/vread projections, emitted directly in bf16 hi/lo MFMA A-frag order.
__global__ __launch_bounds__(384) void k_proj_cache(const float* __restrict__ cache,
    const float* __restrict__ Wk, const float* __restrict__ Wv,
    u16* __restrict__ krh, u16* __restrict__ krl,
    u16* __restrict__ vrh, u16* __restrict__ vrl){
  __shared__ float crow[DSLOTz];
  int b = blockIdx.x / NSLOTz, sc = blockIdx.x % NSLOTz;
  int t = threadIdx.x;
  const float* cp = cache + (size_t)(b*NSLOTz+sc)*DSLOTz;
  if (t < DSLOTz) crow[t] = cp[t];
  __syncthreads();
  if (t < DCz){
    float a = 0.f;
    for (int r2=0;r2<DSLOTz;r2++) a += crow[r2]*Wk[r2*DCz + t];
    uint hb = hi16(a);
    uint lb = hi16(a - __uint_as_float(hb<<16));
    int ks = t>>5, st = sc>>4, lane = (sc&15) | (((t>>3)&3)<<4), e = t&7;
    size_t idx = (size_t)b*6144 + (size_t)(((ks*3+st)*64 + lane)*8 + e);
    krh[idx] = (u16)hb; krl[idx] = (u16)lb;
  } else {
    int d = t - DCz;
    float a = 0.f;
    for (int r2=0;r2<DSLOTz;r2++) a += crow[r2]*Wv[r2*Dz + d];
    uint hb = hi16(a);
    uint lb = hi16(a - __uint_as_float(hb<<16));
    int ot = d>>4, ks2 = sc>>5, lane = (d&15) | (((sc>>3)&3)<<4), e = sc&7;
    size_t idx = (size_t)b*16384 + (size_t)(((ks2*16+ot)*64 + lane)*8 + e);
    vrh[idx] = (u16)hb; vrl[idx] = (u16)lb;
  }
}

// -------- MFMA k_read_attn: direct-A, dbuf everywhere, ~15 barriers, 21.8 KB LDS
#define RB_G  20480
#define RB_WG 20736
__global__ __launch_bounds__(256) void k_read_attn(
    float* __restrict__ h,
    const u16* __restrict__ wqh, const u16* __restrict__ wql,
    const u16* __restrict__ krh, const u16* __restrict__ krl,
    const u16* __restrict__ vrh, const u16* __restrict__ vrl,
    const float* __restrict__ Wg, const float* __restrict__ bg,
    float* __restrict__ kvbuf){
  __shared__ float smem[5440];
  char* sb = (char*)smem;
  const int t = threadIdx.x;
  const int b = blockIdx.y;
  const int n0 = blockIdx.x*64;
  const int w = t>>6, lane = t&63, ln = t&15, lq = (t>>4)&3;
  float* hb = h + (size_t)b*Nz*Dz;
  { // fold: zero kvbuf (stream order: previous k_att was the last reader)
    int gid = (b*GXA + blockIdx.x)*256 + t;
    if (gid < Bz*Hz*4160) kvbuf[gid] = 0.f;
  }
  ((float*)(sb+RB_WG))[t] = Wg[t];

  const int hrow = t>>2, hcol = t&3;
  const float* hbase = hb + (size_t)(n0+hrow)*Dz + hcol*8;
  const int hvalid = (n0+hrow) < Nz;
  const int a16w = ((hrow*5 + hcol)<<4);
  auto load_h = [&](int ks, float x[8]){
    if (hvalid){
      float4 v0 = *(const float4*)(hbase + ks*32);
      float4 v1 = *(const float4*)(hbase + ks*32 + 4);
      x[0]=v0.x; x[1]=v0.y; x[2]=v0.z; x[3]=v0.w;
      x[4]=v1.x; x[5]=v1.y; x[6]=v1.z; x[7]=v1.w;
    } else {
      #pragma unroll
      for (int e=0;e<8;e++) x[e]=0.f;
    }
  };
  auto cvt_write = [&](const float x[8], int buf){
    uint hw[4], lw[4];
    #pragma unroll
    for (int e=0;e<4;e++){
      uint h0=hi16(x[2*e]), h1=hi16(x[2*e+1]);
      uint l0=hi16(x[2*e]-__uint_as_float(h0<<16));
      uint l1=hi16(x[2*e+1]-__uint_as_float(h1<<16));
      hw[e]=h0|(h1<<16); lw[e]=l0|(l1<<16);
    }
    *(uint4*)(sb + buf*10240 + a16w) = make_uint4(hw[0],hw[1],hw[2],hw[3]);
    *(uint4*)(sb + buf*10240 + 5120 + a16w) = make_uint4(lw[0],lw[1],lw[2],lw[3]);
  };

  // ---- GEMM1 (dbuf, 1 barrier/ks) ----
  floatx4 acc[2][4];
  #pragma unroll
  for (int i=0;i<2;i++)
    #pragma unroll
    for (int j=0;j<4;j++){ acc[i][j][0]=0.f; acc[i][j][1]=0.f; acc[i][j][2]=0.f; acc[i][j][3]=0.f; }
  { float x0[8]; load_h(0, x0); cvt_write(x0, 0); }
  for (int ks=0; ks<8; ks++){
    __syncthreads();
    float xn[8];
    if (ks < 7) load_h(ks+1, xn);
    const int cb = ks&1;
    U8 bh[4], bl[4];
    #pragma unroll
    for (int nt=0; nt<4; nt++){
      int a16 = (((nt*16+ln)*5 + lq)<<4);
      bh[nt].q = *(const uint4*)(sb + cb*10240 + a16);
      bl[nt].q = *(const uint4*)(sb + cb*10240 + 5120 + a16);
    }
    #pragma unroll
    for (int mf=0; mf<2; mf++){
      U8 ah, al;
      size_t ai = ((size_t)(ks*8 + w*2 + mf))*512 + lane*8;
      ah.q = *(const uint4*)(wqh + ai);
      al.q = *(const uint4*)(wql + ai);
      #pragma unroll
      for (int nt=0; nt<4; nt++){
        acc[mf][nt] = __builtin_amdgcn_mfma_f32_16x16x32_bf16(ah.v, bh[nt].v, acc[mf][nt], 0,0,0);
        acc[mf][nt] = __builtin_amdgcn_mfma_f32_16x16x32_bf16(ah.v, bl[nt].v, acc[mf][nt], 0,0,0);
        acc[mf][nt] = __builtin_amdgcn_mfma_f32_16x16x32_bf16(al.v, bh[nt].v, acc[mf][nt], 0,0,0);
      }
    }
    if (ks < 7) cvt_write(xn, cb^1);
  }
  // ---- gate (fp32, from global h) ----
  {
    int n = t>>2, kq = t&3;
    int nn = n0+n; int nc = (nn < Nz) ? nn : (Nz-1);
    const float* hp = hb + (size_t)nc*Dz + kq*64;
    const float* wgp = (const float*)(sb+RB_WG) + kq*64;
    float a = 0.f;
    for (int k=0;k<64;k+=4){
      float4 hv = *(const float4*)(hp+k);
      float4 wv = *(const float4*)(wgp+k);
      a += dot4(hv,wv);
    }
    a += __shfl_xor(a,1,64);
    a += __shfl_xor(a,2,64);
    if (kq==0) ((float*)(sb+RB_G))[n] = a;
  }
  // ---- pack q (this wave's c-slice) to registers ----
  uint2 qh[2][4], ql[2][4];
  #pragma unroll
  for (int mf=0; mf<2; mf++){
    #pragma unroll
    for (int nt=0; nt<4; nt++){
      float v0 = acc[mf][nt][0], v1 = acc[mf][nt][1];
      float v2 = acc[mf][nt][2], v3 = acc[mf][nt][3];
      uint h0=hi16(v0), h1=hi16(v1), h2=hi16(v2), h3=hi16(v3);
      uint l0=hi16(v0-__uint_as_float(h0<<16));
      uint l1=hi16(v1-__uint_as_float(h1<<16));
      uint l2=hi16(v2-__uint_as_float(h2<<16));
      uint l3=hi16(v3-__uint_as_float(h3<<16));
      qh[mf][nt] = make_uint2(h0|(h1<<16), h2|(h3<<16));
      ql[mf][nt] = make_uint2(l0|(l1<<16), l2|(l3<<16));
    }
  }
  // ---- QK^T: q K-slices dbuf; owner of slice s is wave s ----
  auto write_qslice = [&](int buf){
    #pragma unroll
    for (int mf=0; mf<2; mf++){
      int g = mf*2 + (lq>>1);
      int sub = (lq&1)<<3;
      #pragma unroll
      for (int nt=0; nt<4; nt++){
        int a16 = (((nt*16+ln)*5 + g)<<4) + sub;
        *(uint2*)(sb + buf*10240 + a16) = qh[mf][nt];
        *(uint2*)(sb + buf*10240 + 5120 + a16) = ql[mf][nt];
      }
    }
  };
  floatx4 sacc[3];
  #pragma unroll
  for (int st=0; st<3; st++){ sacc[st][0]=0.f; sacc[st][1]=0.f; sacc[st][2]=0.f; sacc[st][3]=0.f; }
  __syncthreads();            // drain GEMM1 dbuf reads before q overwrite
  if (w == 0) write_qslice(0);
  for (int ks=0; ks<4; ks++){
    __syncthreads();
    if (ks < 3 && w == ks+1) write_qslice((ks+1)&1);
    const int cb = ks&1;
    U8 bh, bl;
    int a16 = (((w*16+ln)*5 + lq)<<4);
    bh.q = *(const uint4*)(sb + cb*10240 + a16);
    bl.q = *(const uint4*)(sb + cb*10240 + 5120 + a16);
    #pragma unroll
    for (int st=0; st<3; st++){
      U8 ah, al;
      size_t ai = (size_t)b*6144 + ((size_t)(ks*3+st))*512 + lane*8;
      ah.q = *(const uint4*)(krh + ai);
      al.q = *(const uint4*)(krl + ai);
      sacc[st] = __builtin_amdgcn_mfma_f32_16x16x32_bf16(ah.v, bh.v, sacc[st], 0,0,0);
      sacc[st] = __builtin_amdgcn_mfma_f32_16x16x32_bf16(ah.v, bl.v, sacc[st], 0,0,0);
      sacc[st] = __builtin_amdgcn_mfma_f32_16x16x32_bf16(al.v, bh.v, sacc[st], 0,0,0);
    }
  }
  // ---- softmax over s=48 (per n = w*16+ln), in registers ----
  {
    const float scl = 0.088388347648318447f;
    float mx = -1e30f;
    #pragma unroll
    for (int st=0; st<3; st++)
      #pragma unroll
      for (int r=0;r<4;r++){ sacc[st][r] *= scl; mx = fmaxf(mx, sacc[st][r]); }
    mx = fmaxf(mx, __shfl_xor(mx, 16, 64));
    mx = fmaxf(mx, __shfl_xor(mx, 32, 64));
    float su = 0.f;
    #pragma unroll
    for (int st=0; st<3; st++)
      #pragma unroll
      for (int r=0;r<4;r++){ float e = __expf(sacc[st][r]-mx); sacc[st][r]=e; su+=e; }
    su += __shfl_xor(su, 16, 64);
    su += __shfl_xor(su, 32, 64);
    float inv = 1.f/su;
    #pragma unroll
    for (int st=0; st<3; st++)
      #pragma unroll
      for (int r=0;r<4;r++) sacc[st][r] *= inv;
  }
  // ---- write attn B: slice ks2 -> buf ks2 (both at once) ----
  __syncthreads();            // drain QK^T dbuf reads
  {
    uint2 ah2[3], al2[3];
    #pragma unroll
    for (int st=0; st<3; st++){
      float v0=sacc[st][0], v1=sacc[st][1], v2=sacc[st][2], v3=sacc[st][3];
      uint h0=hi16(v0), h1=hi16(v1), h2=hi16(v2), h3=hi16(v3);
      uint l0=hi16(v0-__uint_as_float(h0<<16));
      uint l1=hi16(v1-__uint_as_float(h1<<16));
      uint l2=hi16(v2-__uint_as_float(h2<<16));
      uint l3=hi16(v3-__uint_as_float(h3<<16));
      ah2[st] = make_uint2(h0|(h1<<16), h2|(h3<<16));
      al2[st] = make_uint2(l0|(l1<<16), l2|(l3<<16));
    }
    int rb = (w*16+ln)*5;
    int sub = (lq&1)<<3;
    #pragma unroll
    for (int st=0; st<2; st++){   // slice 0: s=0..31
      int a16 = ((rb + st*2 + (lq>>1))<<4) + sub;
      *(uint2*)(sb + a16) = ah2[st];
      *(uint2*)(sb + 5120 + a16) = al2[st];
    }
    { // slice 1: s=32..47 (st=2), pad s=48..63 zero
      int a16 = ((rb + (lq>>1))<<4) + sub;
      *(uint2*)(sb + 10240 + a16) = ah2[2];
      *(uint2*)(sb + 10240 + 5120 + a16) = al2[2];
      int z16 = ((rb + 2 + (lq>>1))<<4) + sub;
      *(uint2*)(sb + 10240 + z16) = make_uint2(0,0);
      *(uint2*)(sb + 10240 + 5120 + z16) = make_uint2(0,0);
    }
  }
  __syncthreads();
  // ---- AV: O[oc][n], A = vread direct ----
  floatx4 o[4][4];
  #pragma unroll
  for (int i=0;i<4;i++)
    #pragma unroll
    for (int j=0;j<4;j++){ o[i][j][0]=0.f; o[i][j][1]=0.f; o[i][j][2]=0.f; o[i][j][3]=0.f; }
  #pragma unroll
  for (int ks2=0; ks2<2; ks2++){
    U8 bh[4], bl[4];
    #pragma unroll
    for (int nt=0; nt<4; nt++){
      int a16 = (((nt*16+ln)*5 + lq)<<4);
      bh[nt].q = *(const uint4*)(sb + ks2*10240 + a16);
      bl[nt].q = *(const uint4*)(sb + ks2*10240 + 5120 + a16);
    }
    #pragma unroll
    for (int mf=0; mf<4; mf++){
      U8 ah, al;
      size_t ai = (size_t)b*16384 + ((size_t)(ks2*16 + w*4 + mf))*512 + lane*8;
      ah.q = *(const uint4*)(vrh + ai);
      al.q = *(const uint4*)(vrl + ai);
      #pragma unroll
      for (int nt=0; nt<4; nt++){
        o[mf][nt] = __builtin_amdgcn_mfma_f32_16x16x32_bf16(ah.v, bh[nt].v, o[mf][nt], 0,0,0);
        o[mf][nt] = __builtin_amdgcn_mfma_f32_16x16x32_bf16(ah.v, bl[nt].v, o[mf][nt], 0,0,0);
        o[mf][nt] = __builtin_amdgcn_mfma_f32_16x16x32_bf16(al.v, bh[nt].v, o[mf][nt], 0,0,0);
      }
    }
  }
  // ---- epilogue: h += sigm(gate)*read ----
  float bg0 = bg[0];
  #pragma unroll
  for (int nt=0; nt<4; nt++){
    int n = n0 + nt*16 + ln;
    if (n < Nz){
      float gv = sigm(((const float*)(sb+RB_G))[nt*16+ln] + bg0);
      #pragma unroll
      for (int mf=0; mf<4; mf++){
        float* hp = hb + (size_t)n*Dz + w*64 + mf*16 + lq*4;
        float4 hv = *(const float4*)hp;
        hv.x += gv*o[mf][nt][0];
        hv.y += gv*o[mf][nt][1];
        hv.z += gv*o[mf][nt][2];
        hv.w += gv*o[mf][nt][3];
        *(float4*)hp = hv;
      }
    }
  }
}

// ---------------- MFMA k_kv: A direct->reg, double-buffered B, 1 barrier/ks ----
// (R6 version — empirically best at ~285 µs.)
__global__ __launch_bounds__(256) void k_kv(
    const float* __restrict__ h,
    const u16* __restrict__ wh, const u16* __restrict__ wl,
    const float* __restrict__ cost, const float* __restrict__ sint,
    float* __restrict__ kvbuf){
  __shared__ float smem[8704];
  char* sb = (char*)smem;
  const int t = threadIdx.x;
  const int b = blockIdx.y;
  const int n0 = blockIdx.x*64;
  const int w = t>>6;
  const int lane = t&63;
  const int ln = t&15;
  const int lq = (t>>4)&3;
  const float* hb = h + (size_t)b*Nz*Dz;
  floatx4 acc[2][4][4];
  #pragma unroll
  for (int cp=0;cp<2;cp++)
    #pragma unroll
    for (int i=0;i<4;i++)
      #pragma unroll
      for (int j=0;j<4;j++){ acc[cp][i][j][0]=0.f; acc[cp][i][j][1]=0.f; acc[cp][i][j][2]=0.f; acc[cp][i][j][3]=0.f; }

  const int hrow = t>>2, hcol = t&3;
  const float* hbase = hb + (size_t)(n0+hrow)*Dz + hcol*8;
  const int hvalid = (n0+hrow) < Nz;
  const int a16w = ((hrow*5 + hcol)<<4);

  auto load_h = [&](int ks, float x[8]){
    if (hvalid){
      float4 v0 = *(const float4*)(hbase + ks*32);
      float4 v1 = *(const float4*)(hbase + ks*32 + 4);
      x[0]=v0.x; x[1]=v0.y; x[2]=v0.z; x[3]=v0.w;
      x[4]=v1.x; x[5]=v1.y; x[6]=v1.z; x[7]=v1.w;
    } else {
      #pragma unroll
      for (int e=0;e<8;e++) x[e]=0.f;
    }
  };
  auto cvt_write = [&](const float x[8], int buf){
    uint hw[4], lw[4];
    #pragma unroll
    for (int e=0;e<4;e++){
      uint h0=hi16(x[2*e]), h1=hi16(x[2*e+1]);
      uint l0=hi16(x[2*e]-__uint_as_float(h0<<16));
      uint l1=hi16(x[2*e+1]-__uint_as_float(h1<<16));
      hw[e]=h0|(h1<<16); lw[e]=l0|(l1<<16);
    }
    *(uint4*)(sb + buf*10240 + a16w) = make_uint4(hw[0],hw[1],hw[2],hw[3]);
    *(uint4*)(sb + buf*10240 + 5120 + a16w) = make_uint4(lw[0],lw[1],lw[2],lw[3]);
  };

  { float x0[8]; load_h(0, x0); cvt_write(x0, 0); }
  for (int ks=0; ks<8; ks++){
    __syncthreads();
    float xn[8];
    if (ks < 7) load_h(ks+1, xn);
    const int cb = ks&1;
    U8 bh[4], bl[4];
    #pragma unroll
    for (int nt=0; nt<4; nt++){
      int a16 = (((nt*16+ln)*5 + lq)<<4);
      bh[nt].q = *(const uint4*)(sb + cb*10240 + a16);
      bl[nt].q = *(const uint4*)(sb + cb*10240 + 5120 + a16);
    }
    #pragma unroll
    for (int cp=0; cp<2; cp++){
      #pragma unroll
      for (int mf=0; mf<4; mf++){
        U8 ah, al;
        size_t ai = ((size_t)(ks*32 + cp*16 + w*4 + mf))*512 + lane*8;
        ah.q = *(const uint4*)(wh + ai);
        al.q = *(const uint4*)(wl + ai);
        #pragma unroll
        for (int nt=0; nt<4; nt++){
          acc[cp][mf][nt] = __builtin_amdgcn_mfma_f32_16x16x32_bf16(ah.v, bh[nt].v, acc[cp][mf][nt], 0,0,0);
          acc[cp][mf][nt] = __builtin_amdgcn_mfma_f32_16x16x32_bf16(ah.v, bl[nt].v, acc[cp][mf][nt], 0,0,0);
          acc[cp][mf][nt] = __builtin_amdgcn_mfma_f32_16x16x32_bf16(al.v, bh[nt].v, acc[cp][mf][nt], 0,0,0);
        }
      }
    }
    if (ks < 7) cvt_write(xn, cb^1);
  }
  // epilogue: rope + elu on kf (cp0), zero invalid columns
  #pragma unroll
  for (int mf=0; mf<4; mf++){
    #pragma unroll
    for (int nt=0; nt<4; nt++){
      int n = n0 + nt*16 + ln;
      int valid = (n < Nz);
      int nc = valid ? n : (Nz-1);
      int pi = mf*8 + lq*2;
      float2 c2 = *(const float2*)(cost + (size_t)nc*32 + pi);
      float2 s2 = *(const float2*)(sint + (size_t)nc*32 + pi);
      float q0 = acc[0][mf][nt][0], q1 = acc[0][mf][nt][1];
      float q2 = acc[0][mf][nt][2], q3 = acc[0][mf][nt][3];
      float r0 = elu1(q0*c2.x - q1*s2.x);
      float r1 = elu1(q0*s2.x + q1*c2.x);
      float r2 = elu1(q2*c2.y - q3*s2.y);
      float r3 = elu1(q2*s2.y + q3*c2.y);
      acc[0][mf][nt][0] = valid ? r0 : 0.f;
      acc[0][mf][nt][1] = valid ? r1 : 0.f;
      acc[0][mf][nt][2] = valid ? r2 : 0.f;
      acc[0][mf][nt][3] = valid ? r3 : 0.f;
    }
  }
  // phase B: kv accumulation per head (atomic path)
  const int d = t&63, q4 = t>>6;
  float* kfL = smem;          // [n(64)][68]
  float* vL  = smem + 4352;   // [n(64)][68]
  for (int g=0; g<4; g++){
    __syncthreads();
    if (w == g){
      #pragma unroll
      for (int mf=0; mf<4; mf++){
        #pragma unroll
        for (int nt=0; nt<4; nt++){
          int n = nt*16 + ln;
          int cc = mf*16 + lq*4;
          *(float4*)(kfL + n*68 + cc) = make_float4(acc[0][mf][nt][0],acc[0][mf][nt][1],acc[0][mf][nt][2],acc[0][mf][nt][3]);
          *(float4*)(vL  + n*68 + cc) = make_float4(acc[1][mf][nt][0],acc[1][mf][nt][1],acc[1][mf][nt][2],acc[1][mf][nt][3]);
        }
      }
    }
    __syncthreads();
    float4 kvacc[4];
    #pragma unroll
    for (int u=0;u<4;u++) kvacc[u]=f4z();
    float ksl = 0.f;
    for (int row=0; row<64; row++){
      float kd = kfL[row*68 + d];
      ksl += kd;
      const float4* vp = (const float4*)(vL + row*68);
      #pragma unroll
      for (int u=0;u<4;u++) fma4(kvacc[u], kd, vp[q4*4+u]);
    }
    float* kq = kvbuf + ((size_t)(b*Hz + g))*4160;
    #pragma unroll
    for (int u=0;u<4;u++){
      int e = q4*16 + 4*u;
      atomicAdd(&kq[(e+0)*64+d], kvacc[u].x);
      atomicAdd(&kq[(e+1)*64+d], kvacc[u].y);
      atomicAdd(&kq[(e+2)*64+d], kvacc[u].z);
      atomicAdd(&kq[(e+3)*64+d], kvacc[u].w);
    }
    if (q4==0) atomicAdd(&kq[4096+d], ksl);
  }
}

// P[b][h] = kv_h @ Wo_h (64 x 256, K=64), fused coalesced pack epilogue.
// Packed layout per b: [gs(8)][ct(16)][lane(64)][e(8)], element = Pcat[c][oc],
// c = gs*32+(lane>>4)*8+e, oc = ct*16+(lane&15). This block (hh) owns gs=2hh,2hh+1.
// Epilogue: stage 32-row half into LDS [32][260] f32, then 16B uint4 packed stores.
__global__ __launch_bounds__(256) void k_pmat(
    const float* __restrict__ kvbuf, const float* __restrict__ Wo,
    u16* __restrict__ ph, u16* __restrict__ pl){
  __shared__ float smem[8448];
  const int t = threadIdx.x;
  const int bh = blockIdx.x;
  const int hh = bh & 3;
  const int bb = bh >> 2;
  const int c0 = t&15, rr = t>>4;
  const float* kvp = kvbuf + (size_t)bh*4160;
  for (int id=t; id<4096; id+=256){
    int e=id>>6, d=id&63;
    smem[e*68+d] = kvp[id];
  }
  float4 acc[4][4];
  #pragma unroll
  for (int i=0;i<4;i++){
    #pragma unroll
    for (int j=0;j<4;j++) acc[i][j]=f4z();
  }
  for (int kt=0; kt<64; kt+=16){
    __syncthreads();
    for (int id=t; id<1024; id+=256){
      int wr=id>>6, cf=id&63;
      ((float4*)(smem+4352))[wr*64+cf] = ((const float4*)(Wo + (size_t)(hh*64+kt+wr)*256))[cf];
    }
    __syncthreads();
    for (int kk=0; kk<16; kk++){
      float4 a4 = *(const float4*)(smem + (kt+kk)*68 + 4*rr);
      const float4* wrow = (const float4*)(smem+4352) + kk*64;
      float4 w0=wrow[c0], w1=wrow[c0+16], w2=wrow[c0+32], w3=wrow[c0+48];
      #pragma unroll
      for (int i=0;i<4;i++){
        float ac = fcomp(a4,i);
        fma4(acc[i][0],ac,w0); fma4(acc[i][1],ac,w1); fma4(acc[i][2],ac,w2); fma4(acc[i][3],ac,w3);
      }
    }
  }
  // fused pack: two 32-row halves through LDS [32][260], coalesced 16B stores.
  // acc[i][j][q2] = P[hd=4rr+i][oc=4c0+64j+q2].
  #pragma unroll
  for (int m=0; m<2; m++){
    __syncthreads();
    if ((rr>>3) == m){
      int rbase = (rr - 8*m)*4;
      #pragma unroll
      for (int i=0;i<4;i++){
        #pragma unroll
        for (int j=0;j<4;j++){
          *(float4*)(smem + (size_t)(rbase+i)*260 + 4*c0 + 64*j) = acc[i][j];
        }
      }
    }
    __syncthreads();
    int gs = hh*2 + m;
    #pragma unroll
    for (int q=0; q<4; q++){
      int ch = t + 256*q;
      int ct = ch>>6, lane = ch&63;
      int lr0 = (lane>>4)*8;
      int col = ct*16 + (lane&15);
      uint hv[4], lv[4];
      #pragma unroll
      for (int p=0;p<4;p++){
        float x0 = smem[(lr0+2*p)*260 + col];
        float x1 = smem[(lr0+2*p+1)*260 + col];
        uint h0=hi16(x0), h1=hi16(x1);
        uint l0=hi16(x0-__uint_as_float(h0<<16));
        uint l1=hi16(x1-__uint_as_float(h1<<16));
        hv[p] = h0|(h1<<16); lv[p] = l0|(l1<<16);
      }
      size_t idx = (size_t)bb*65536 + (size_t)((gs*16+ct)*64 + lane)*8;
      *(uint4*)(ph + idx) = make_uint4(hv[0],hv[1],hv[2],hv[3]);
      *(uint4*)(pl + idx) = make_uint4(lv[0],lv[1],lv[2],lv[3]);
    }
  }
}

// ---------------- MFMA k_att: direct-A, double-buffered B, 1 barrier/step ------
#define KA_KS 20480
__global__ __launch_bounds__(256) void k_att(
    float* __restrict__ h,
    const u16* __restrict__ wqh, const u16* __restrict__ wql,
    const u16* __restrict__ pth, const u16* __restrict__ ptl,
    const float* __restrict__ kvbuf,
    const float* __restrict__ cost, const float* __restrict__ sint){
  __shared__ float smem[5376];
  char* sb = (char*)smem;
  const int t = threadIdx.x;
  const int b = blockIdx.y;
  const int n0 = blockIdx.x*64;
  const int w = t>>6;
  const int lane = t&63;
  const int ln = t&15;
  const int lq = (t>>4)&3;
  float* hb = h + (size_t)b*Nz*Dz;
  ((float*)(sb+KA_KS))[t] = kvbuf[(size_t)(b*Hz + w)*4160 + 4096 + lane];

  const int hrow = t>>2, hcol = t&3;
  const float* hbase = hb + (size_t)(n0+hrow)*Dz + hcol*8;
  const int hvalid = (n0+hrow) < Nz;
  const int a16w = ((hrow*5 + hcol)<<4);
  auto load_h = [&](int ks, float x[8]){
    if (hvalid){
      float4 v0 = *(const float4*)(hbase + ks*32);
      float4 v1 = *(const float4*)(hbase + ks*32 + 4);
      x[0]=v0.x; x[1]=v0.y; x[2]=v0.z; x[3]=v0.w;
      x[4]=v1.x; x[5]=v1.y; x[6]=v1.z; x[7]=v1.w;
    } else {
      #pragma unroll
      for (int e=0;e<8;e++) x[e]=0.f;
    }
  };
  auto cvt_write = [&](const float x[8], int buf){
    uint hw[4], lw[4];
    #pragma unroll
    for (int e=0;e<4;e++){
      uint h0=hi16(x[2*e]), h1=hi16(x[2*e+1]);
      uint l0=hi16(x[2*e]-__uint_as_float(h0<<16));
      uint l1=hi16(x[2*e+1]-__uint_as_float(h1<<16));
      hw[e]=h0|(h1<<16); lw[e]=l0|(l1<<16);
    }
    *(uint4*)(sb + buf*10240 + a16w) = make_uint4(hw[0],hw[1],hw[2],hw[3]);
    *(uint4*)(sb + buf*10240 + 5120 + a16w) = make_uint4(lw[0],lw[1],lw[2],lw[3]);
  };

  floatx4 acc[4][4];
  #pragma unroll
  for (int i=0;i<4;i++)
    #pragma unroll
    for (int j=0;j<4;j++){ acc[i][j][0]=0.f; acc[i][j][1]=0.f; acc[i][j][2]=0.f; acc[i][j][3]=0.f; }

  { float x0[8]; load_h(0, x0); cvt_write(x0, 0); }
  for (int ks=0; ks<8; ks++){
    __syncthreads();
    float xn[8];
    if (ks < 7) load_h(ks+1, xn);
    const int cb = ks&1;
    U8 bh[4], bl[4];
    #pragma unroll
    for (int nt=0; nt<4; nt++){
      int a16 = (((nt*16+ln)*5 + lq)<<4);
      bh[nt].q = *(const uint4*)(sb + cb*10240 + a16);
      bl[nt].q = *(const uint4*)(sb + cb*10240 + 5120 + a16);
    }
    #pragma unroll
    for (int mf=0; mf<4; mf++){
      U8 ah, al;
      size_t ai = ((size_t)(ks*16 + w*4 + mf))*512 + lane*8;
      ah.q = *(const uint4*)(wqh + ai);
      al.q = *(const uint4*)(wql + ai);
      #pragma unroll
      for (int nt=0; nt<4; nt++){
        acc[mf][nt] = __builtin_amdgcn_mfma_f32_16x16x32_bf16(ah.v, bh[nt].v, acc[mf][nt], 0,0,0);
        acc[mf][nt] = __builtin_amdgcn_mfma_f32_16x16x32_bf16(ah.v, bl[nt].v, acc[mf][nt], 0,0,0);
        acc[mf][nt] = __builtin_amdgcn_mfma_f32_16x16x32_bf16(al.v, bh[nt].v, acc[mf][nt], 0,0,0);
      }
    }
    if (ks < 7) cvt_write(xn, cb^1);
  }
  // epilogue: rope + elu + z, pack qz to bf16 hi/lo
  uint2 qzh[4][4], qzl[4][4];
  {
    float4 ks4[4];
    #pragma unroll
    for (int mf=0; mf<4; mf++)
      ks4[mf] = *(const float4*)(sb + KA_KS + ((w*64 + mf*16 + lq*4)<<2));
    float psum[4] = {0.f,0.f,0.f,0.f};
    #pragma unroll
    for (int mf=0; mf<4; mf++){
      #pragma unroll
      for (int nt=0; nt<4; nt++){
        int n = n0 + nt*16 + ln;
        int nc = (n < Nz) ? n : (Nz-1);
        int pi = mf*8 + lq*2;
        float2 c2 = *(const float2*)(cost + (size_t)nc*32 + pi);
        float2 s2 = *(const float2*)(sint + (size_t)nc*32 + pi);
        float q0 = acc[mf][nt][0], q1 = acc[mf][nt][1];
        float q2 = acc[mf][nt][2], q3 = acc[mf][nt][3];
        float r0 = elu1(q0*c2.x - q1*s2.x);
        float r1 = elu1(q0*s2.x + q1*c2.x);
        float r2 = elu1(q2*c2.y - q3*s2.y);
        float r3 = elu1(q2*s2.y + q3*c2.y);
        acc[mf][nt][0]=r0; acc[mf][nt][1]=r1; acc[mf][nt][2]=r2; acc[mf][nt][3]=r3;
        psum[nt] += r0*ks4[mf].x + r1*ks4[mf].y + r2*ks4[mf].z + r3*ks4[mf].w;
      }
    }
    float zt[4];
    #pragma unroll
    for (int nt=0; nt<4; nt++){
      float p = psum[nt];
      p += __shfl_xor(p, 16, 64);
      p += __shfl_xor(p, 32, 64);
      zt[nt] = 1.f/(p + 1e-6f);
    }
    #pragma unroll
    for (int mf=0; mf<4; mf++){
      #pragma unroll
      for (int nt=0; nt<4; nt++){
        float v0 = acc[mf][nt][0]*zt[nt];
        float v1 = acc[mf][nt][1]*zt[nt];
        float v2 = acc[mf][nt][2]*zt[nt];
        float v3 = acc[mf][nt][3]*zt[nt];
        uint h0=hi16(v0), h1=hi16(v1), h2=hi16(v2), h3=hi16(v3);
        qzh[mf][nt] = make_uint2(h0|(h1<<16), h2|(h3<<16));
        uint l0=hi16(v0-__uint_as_float(h0<<16));
        uint l1=hi16(v1-__uint_as_float(h1<<16));
        uint l2=hi16(v2-__uint_as_float(h2<<16));
        uint l3=hi16(v3-__uint_as_float(h3<<16));
        qzl[mf][nt] = make_uint2(l0|(l1<<16), l2|(l3<<16));
      }
    }
  }
  // GEMM2: qz slices double-buffered; owner of slice s is wave s>>1
  auto write_slice = [&](int s, int buf){
    #pragma unroll
    for (int mm=0; mm<2; mm++){
      int mf = ((s&1)<<1) + mm;
      int g = (mm<<1) + (lq>>1);
      int sub = (lq&1)*8;
      #pragma unroll
      for (int nt=0; nt<4; nt++){
        int a16 = (((nt*16+ln)*5 + g)<<4) + sub;
        *(uint2*)(sb + buf*10240 + a16) = qzh[mf][nt];
        *(uint2*)(sb + buf*10240 + 5120 + a16) = qzl[mf][nt];
      }
    }
  };
  floatx4 acc2[4][4];
  #pragma unroll
  for (int i=0;i<4;i++)
    #pragma unroll
    for (int j=0;j<4;j++){ acc2[i][j][0]=0.f; acc2[i][j][1]=0.f; acc2[i][j][2]=0.f; acc2[i][j][3]=0.f; }
  __syncthreads();           // drain GEMM1's dbuf reads before qz overwrite
  if (w == 0) write_slice(0, 0);
  for (int ks2=0; ks2<8; ks2++){
    __syncthreads();
    if (ks2 < 7 && w == ((ks2+1)>>1)) write_slice(ks2+1, (ks2+1)&1);
    const int cb = ks2&1;
    U8 bh[4], bl[4];
    #pragma unroll
    for (int nt=0; nt<4; nt++){
      int a16 = (((nt*16+ln)*5 + lq)<<4);
      bh[nt].q = *(const uint4*)(sb + cb*10240 + a16);
      bl[nt].q = *(const uint4*)(sb + cb*10240 + 5120 + a16);
    }
    #pragma unroll
    for (int mf=0; mf<4; mf++){
      U8 ah, al;
      size_t ai = ((size_t)((b*8 + ks2)*16 + w*4 + mf))*512 + lane*8;
      ah.q = *(const uint4*)(pth + ai);
      al.q = *(const uint4*)(ptl + ai);
      #pragma unroll
      for (int nt=0; nt<4; nt++){
        acc2[mf][nt] = __builtin_amdgcn_mfma_f32_16x16x32_bf16(ah.v, bh[nt].v, acc2[mf][nt], 0,0,0);
        acc2[mf][nt] = __builtin_amdgcn_mfma_f32_16x16x32_bf16(ah.v, bl[nt].v, acc2[mf][nt], 0,0,0);
        acc2[mf][nt] = __builtin_amdgcn_mfma_f32_16x16x32_bf16(al.v, bh[nt].v, acc2[mf][nt], 0,0,0);
      }
    }
  }
  // residual add
  #pragma unroll
  for (int mf=0; mf<4; mf++){
    #pragma unroll
    for (int nt=0; nt<4; nt++){
      int n = n0 + nt*16 + ln;
      if (n < Nz){
        float* hp = hb + (size_t)n*Dz + w*64 + mf*16 + lq*4;
        float4 hv = *(const float4*)hp;
        hv.x += acc2[mf][nt][0];
        hv.y += acc2[mf][nt][1];
        hv.z += acc2[mf][nt][2];
        hv.w += acc2[mf][nt][3];
        *(float4*)hp = hv;
      }
    }
  }
}

__global__ __launch_bounds__(256) void k_wkv(const float* __restrict__ h,
    const float* __restrict__ Wwk, const float* __restrict__ Wwv,
    float* __restrict__ wkbuf, float* __restrict__ wvbuf){
  __shared__ float wtL[16*257];
  int t = threadIdx.x;
  int b = blockIdx.y, m0 = blockIdx.x*16;
  const float* hb = h + ((size_t)b*Nz + (Nz-64))*Dz;
  for (int i=t;i<16*Dz;i+=256){ int r=i>>8,c=i&255; wtL[r*257+c] = hb[(size_t)(m0+r)*Dz + c]; }
  __syncthreads();
  int r=t>>4, c0=t&15;
  float4 ak0=f4z(),ak1=f4z(),av0=f4z(),av1=f4z();
  for (int kk=0;kk<Dz;kk++){
    float hv = wtL[r*257+kk];
    const float4* wk4 = (const float4*)(Wwk + (size_t)kk*DCz);
    const float4* wv4 = (const float4*)(Wwv + (size_t)kk*DCz);
    fma4(ak0,hv,wk4[c0]); fma4(ak1,hv,wk4[c0+16]);
    fma4(av0,hv,wv4[c0]); fma4(av1,hv,wv4[c0+16]);
  }
  float4* ok = (float4*)(wkbuf + (size_t)(b*64 + m0+r)*DCz);
  float4* ov = (float4*)(wvbuf + (size_t)(b*64 + m0+r)*DCz);
  ok[c0]=ak0; ok[c0+16]=ak1; ov[c0]=av0; ov[c0+16]=av1;
}

__global__ __launch_bounds__(256) void k_cache_upd(float* __restrict__ cache,
    const float* __restrict__ wkbuf, const float* __restrict__ wvbuf,
    const float* __restrict__ Wwg, const float* __restrict__ bwg,
    int s0, int it, int pas){
  __shared__ float sqL[16*132];
  __shared__ float wkL[64*132];
  __shared__ float wat[16*68];
  __shared__ float ncL[16*132];
  __shared__ float wg[16];
  int t = threadIdx.x; int b = blockIdx.x;
  for (int i=t;i<16*DCz;i+=256){ int k2=i>>7,c=i&127; sqL[k2*132+c] = cache[((size_t)(b*NSLOTz)+s0+k2)*DSLOTz + c]; }
  for (int i=t;i<64*DCz;i+=256){ int m=i>>7,c=i&127; wkL[m*132+c] = wkbuf[(size_t)(b*64+m)*DCz+c]; }
  __syncthreads();
  {
    int k2 = t>>4;
    const float4* s4 = (const float4*)(sqL) + k2*33;
    for (int mm=0;mm<4;mm++){
      int m = (t&15) + 16*mm;
      const float4* k4 = (const float4*)(wkL) + m*33;
      float a=0.f;
      for (int d4=0;d4<32;d4++) a += dot4(s4[d4], k4[d4]);
      wat[k2*68+m] = a * 0.088388347648318447f;
    }
  }
  __syncthreads();
  if (t<16){
    float mx=-1e30f;
    for (int m=0;m<64;m++) mx = fmaxf(mx, wat[t*68+m]);
    float su=0.f;
    for (int m=0;m<64;m++){ float e=__expf(wat[t*68+m]-mx); wat[t*68+m]=e; su+=e; }
    float inv=1.f/su;
    for (int m=0;m<64;m++) wat[t*68+m]*=inv;
  }
  __syncthreads();
  {
    int k2=t>>4, c0=t&15;
    float4 a0=f4z(), a1=f4z();
    const float4* wvg = (const float4*)(wvbuf + (size_t)b*64*DCz);
    for (int m=0;m<64;m++){
      float a = wat[k2*68+m];
      fma4(a0,a,wvg[m*32+c0]); fma4(a1,a,wvg[m*32+c0+16]);
    }
    ((float4*)ncL)[k2*33+c0]=a0; ((float4*)ncL)[k2*33+16+c0]=a1;
  }
  __syncthreads();
  if (t<16){
    float a = bwg[0];
    for (int d2=0; d2<DCz; d2++) a += sqL[t*132+d2]*Wwg[d2] + ncL[t*132+d2]*Wwg[DCz+d2];
    wg[t] = sigm(a);
  }
  __syncthreads();
  for (int i=t;i<16*DCz;i+=256){
    int k2=i>>7,c=i&127;
    cache[((size_t)(b*NSLOTz)+s0+k2)*DSLOTz + c] = sqL[k2*132+c] + wg[k2]*ncL[k2*132+c];
  }
  if (t<16){
    float* cp = cache + ((size_t)(b*NSLOTz)+s0+t)*DSLOTz;
    cp[128] = wg[t];
    cp[137] = (it==0)?1.f:0.f; cp[138] = (it==1)?1.f:0.f; cp[139]=0.f; cp[140]=0.f;
    cp[141] = (pas==0)?1.f:0.f; cp[142] = (pas==1)?1.f:0.f; cp[143]=0.f; cp[144]=0.f;
  }
}

__global__ __launch_bounds__(256) void k_logits(const float* __restrict__ h,
    const float* __restrict__ Wout, const float* __restrict__ bout, float* __restrict__ out){
  __shared__ float hl[16*257];
  int t = threadIdx.x; int row0 = blockIdx.x*16;
  for (int i=t;i<16*Dz;i+=256){
    int rr=i>>8,c=i&255; int row=row0+rr; int b=row/Sz, s=row-b*Sz;
    hl[rr*257+c] = h[((size_t)b*Nz + TSz + s)*Dz + c];
  }
  __syncthreads();
  int rr = t>>4, v = t&15;
  float a = bout[v];
  for (int c=0;c<Dz;c++) a += hl[rr*257+c]*Wout[c*Vz + v];
  out[(size_t)(row0+rr)*Vz + v] = a;
}

__global__ __launch_bounds__(256) void k_feedback(float* __restrict__ h,
    const float* __restrict__ logits0, const float* __restrict__ pae,
    const float* __restrict__ Wfb, const float* __restrict__ bfb){
  __shared__ float trL[16*257];
  __shared__ float paeL[16*257];
  __shared__ int amL[16];
  int t = threadIdx.x; int b = blockIdx.y; int s0 = blockIdx.x*16;
  if (t<16){
    int s = s0+t; int am=0;
    if (s < Sz){
      const float* lg = logits0 + (size_t)(b*Sz+s)*Vz;
      float best = lg[0];
      for (int v=1;v<16;v++){ if (lg[v] > best){ best=lg[v]; am=v; } }
    }
    amL[t]=am;
  }
  for (int i=t;i<16*Dz;i+=256){
    int rr=i>>8,c=i&255; int s=s0+rr;
    trL[rr*257+c] = (s<Sz)? h[((size_t)b*Nz + TSz + s)*Dz + c] : 0.f;
  }
  __syncthreads();
  for (int i=t;i<16*Dz;i+=256){ int rr=i>>8,c=i&255; paeL[rr*257+c] = pae[(size_t)amL[rr]*Dz + c]; }
  __syncthreads();
  int r=t>>4, c0=t&15;
  float4 acc[4]; acc[0]=f4z(); acc[1]=f4z(); acc[2]=f4z(); acc[3]=f4z();
  for (int kk=0;kk<Dz;kk++){
    float xv = trL[r*257+kk];
    const float4* wr = (const float4*)(Wfb + (size_t)kk*Dz);
    fma4(acc[0],xv,wr[c0]); fma4(acc[1],xv,wr[c0+16]); fma4(acc[2],xv,wr[c0+32]); fma4(acc[3],xv,wr[c0+48]);
  }
  for (int kk=0;kk<Dz;kk++){
    float xv = paeL[r*257+kk];
    const float4* wr = (const float4*)(Wfb + (size_t)(Dz+kk)*Dz);
    fma4(acc[0],xv,wr[c0]); fma4(acc[1],xv,wr[c0+16]); fma4(acc[2],xv,wr[c0+32]); fma4(acc[3],xv,wr[c0+48]);
  }
  int s = s0+r;
  if (s < Sz){
    float* cp = h + ((size_t)b*Nz + TSz + s)*Dz;
    #pragma unroll
    for (int j=0;j<4;j++){
      float vals[4] = {acc[j].x, acc[j].y, acc[j].z, acc[j].w};
      #pragma unroll
      for (int q2=0;q2<4;q2++){
        int c = (c0+16*j)*4 + q2;
        float g = sigm(vals[q2] + bfb[c]);
        cp[c] = trL[r*257+c] + g*paeL[r*257+c];
      }
    }
  }
}

extern "C" void kernel_launch(void* const* d_in, const int* in_sizes, int n_in,
                              void* d_out, int out_size, void* d_ws, size_t ws_size,
                              hipStream_t stream){
  (void)in_sizes; (void)n_in;
  const int*   demo_in   = (const int*)d_in[0];
  const int*   demo_out  = (const int*)d_in[1];
  const int*   test_in   = (const int*)d_in[2];
  const float* token_emb = (const float*)d_in[3];
  const float* seg_emb   = (const float*)d_in[4];
  const float* slot_emb  = (const float*)d_in[5];
  const float* lid_emb   = (const float*)d_in[6];
  const float* Wq_read   = (const float*)d_in[7];
  const float* Wk_read   = (const float*)d_in[8];
  const float* Wv_read   = (const float*)d_in[9];
  const float* Wg_read   = (const float*)d_in[10];
  const float* bg_read   = (const float*)d_in[11];
  const float* Wqkv      = (const float*)d_in[12];
  const float* Wo        = (const float*)d_in[13];
  const float* Wwk       = (const float*)d_in[14];
  const float* Wwv       = (const float*)d_in[15];
  const float* Wwg       = (const float*)d_in[16];
  const float* bwg       = (const float*)d_in[17];
  const float* Wout      = (const float*)d_in[18];
  const float* bout      = (const float*)d_in[19];
  const float* pae       = (const float*)d_in[20];
  const float* Wfb       = (const float*)d_in[21];
  const float* bfb       = (const float*)d_in[22];

  char* wsb = (char*)d_ws;
  size_t off = 0;
  auto alloc = [&](size_t bytes)->char*{
    char* p = wsb + off;
    off += (bytes + 255) & ~(size_t)255;
    return p;
  };
  float* hbuf   = (float*)alloc((size_t)Bz*Nz*Dz*4);
  float* cache  = (float*)alloc((size_t)Bz*NSLOTz*DSLOTz*4);
  float* kvbuf  = (float*)alloc((size_t)Bz*Hz*4160*4);
  float* wkbuf  = (float*)alloc((size_t)Bz*64*DCz*4);
  float* wvbuf  = (float*)alloc((size_t)Bz*64*DCz*4);
  float* logits0= (float*)alloc((size_t)Bz*Sz*Vz*4);
  float* cost   = (float*)alloc((size_t)Nz*32*4);
  float* sint   = (float*)alloc((size_t)Nz*32*4);
  u16*   wqth   = (u16*)alloc((size_t)3*65536*2);
  u16*   wqtl   = (u16*)alloc((size_t)3*65536*2);
  u16*   pth    = (u16*)alloc((size_t)16*65536*2);
  u16*   ptl    = (u16*)alloc((size_t)16*65536*2);
  u16*   wkvh   = (u16*)alloc((size_t)3*131072*2);
  u16*   wkvl   = (u16*)alloc((size_t)3*131072*2);
  u16*   wqrh   = (u16*)alloc((size_t)3*32768*2);
  u16*   wqrl   = (u16*)alloc((size_t)3*32768*2);
  u16*   krh    = (u16*)alloc((size_t)Bz*6144*2);
  u16*   krl    = (u16*)alloc((size_t)Bz*6144*2);
  u16*   vrh    = (u16*)alloc((size_t)Bz*16384*2);
  u16*   vrl    = (u16*)alloc((size_t)Bz*16384*2);

  if (off > ws_size){
    k_sentinel<<<(out_size+255)/256, 256, 0, stream>>>((float*)d_out, out_size);
    return;
  }

  k_rope<<<(Nz*32+255)/256, 256, 0, stream>>>(cost, sint);
  k_cache_init<<<(Bz*NSLOTz*DSLOTz+255)/256, 256, 0, stream>>>(slot_emb, lid_emb, cache);
  k_pack_w<<<768, 256, 0, stream>>>(Wqkv, wqth, wqtl);
  k_pack_wkv<<<1536, 256, 0, stream>>>(Wqkv, wkvh, wkvl);
  k_pack_wr<<<384, 256, 0, stream>>>(Wq_read, wqrh, wqrl);
  // zero vreadp once: pad rows s=48..63 must be 0 bf16 forever
  k_zero<<<512, 256, 0, stream>>>((float*)vrh, Bz*16384/2);
  k_zero<<<512, 256, 0, stream>>>((float*)vrl, Bz*16384/2);

  for (int pas=0; pas<2; pas++){
    k_embed<<<(Bz*Nz*64+255)/256, 256, 0, stream>>>(demo_in, demo_out, test_in, token_emb, seg_emb, hbuf);
    if (pas==1)
      k_feedback<<<dim3(57,Bz), 256, 0, stream>>>(hbuf, logits0, pae, Wfb, bfb);
    for (int l=0; l<3; l++){
      for (int it=0; it<2; it++){
        k_proj_cache<<<Bz*NSLOTz, 384, 0, stream>>>(cache,
            Wk_read + (size_t)l*DSLOTz*DCz, Wv_read + (size_t)l*DSLOTz*Dz,
            krh, krl, vrh, vrl);
        k_read_attn<<<dim3(GXA,Bz), 256, 0, stream>>>(hbuf,
            wqrh + (size_t)l*32768, wqrl + (size_t)l*32768,
            krh, krl, vrh, vrl,
            Wg_read + (size_t)l*Dz, bg_read + l, kvbuf);
        k_kv<<<dim3(GXA,Bz), 256, 0, stream>>>(hbuf,
            wkvh + (size_t)l*131072, wkvl + (size_t)l*131072, cost, sint, kvbuf);
        k_pmat<<<Bz*Hz, 256, 0, stream>>>(kvbuf, Wo + (size_t)l*Dz*Dz, pth, ptl);
        k_att<<<dim3(GXA,Bz), 256, 0, stream>>>(hbuf,
            wqth + (size_t)l*65536, wqtl + (size_t)l*65536, pth, ptl,
            kvbuf, cost, sint);
        k_wkv<<<dim3(4,Bz), 256, 0, stream>>>(hbuf,
            Wwk + (size_t)l*Dz*DCz, Wwv + (size_t)l*Dz*DCz, wkbuf, wvbuf);
        k_cache_upd<<<Bz, 256, 0, stream>>>(cache, wkbuf, wvbuf,
            Wwg + (size_t)l*2*DCz, bwg + l, l*16, it, pas);
      }
    }
    float* outp = (pas==0) ? logits0 : (float*)d_out;
    k_logits<<<900, 256, 0, stream>>>(hbuf, Wout, bout, outp);
  }
}